// Round 1
// baseline (350.756 us; speedup 1.0000x reference)
//
#include <hip/hip_runtime.h>
#include <hip/hip_bf16.h>

#define BB 512
#define NN 714
#define EE 4096
#define ED2 62
#define CH 32

typedef unsigned int u32;

__device__ __forceinline__ u32 f2bf(float f) {
  u32 u = __float_as_uint(f);
  return (u + 0x7fffu + ((u >> 16) & 1u)) >> 16;
}
__device__ __forceinline__ u32 pack2(float a, float b) {
  return f2bf(a) | (f2bf(b) << 16);
}
__device__ __forceinline__ float bf_lo(u32 u) { return __uint_as_float(u << 16); }
__device__ __forceinline__ float bf_hi(u32 u) { return __uint_as_float(u & 0xffff0000u); }

// ---------------- Kernel A: degree, dinv, CSR (sorted-by-col row list) ----------------
__global__ __launch_bounds__(256) void k_prep(const int* __restrict__ edges,
    float* __restrict__ dinv, int* __restrict__ csr_off, int* __restrict__ csr_rows)
{
  const int b = blockIdx.x;
  const int tid = threadIdx.x;
  const int* __restrict__ er = edges + (size_t)b * 2 * EE;       // e[0] = source (row)
  const int* __restrict__ ec = er + EE;                          // e[1] = target (col)
  __shared__ int s_cnt[NN];
  __shared__ int s_a[1024];
  __shared__ int s_b[1024];
  for (int i = tid; i < NN; i += 256) s_cnt[i] = 0;
  __syncthreads();
  for (int e = tid; e < EE; e += 256) atomicAdd(&s_cnt[ec[e]], 1);
  __syncthreads();
  for (int i = tid; i < 1024; i += 256) s_a[i] = (i < NN) ? s_cnt[i] : 0;
  for (int i = tid; i < NN; i += 256)
    dinv[(size_t)b * NN + i] = rsqrtf((float)(s_cnt[i] + 1));    // +1 self loop
  __syncthreads();
  int* src = s_a; int* dst = s_b;
  for (int d = 1; d < 1024; d <<= 1) {
    for (int i = tid; i < 1024; i += 256) {
      int v = src[i];
      if (i >= d) v += src[i - d];
      dst[i] = v;
    }
    __syncthreads();
    int* t = src; src = dst; dst = t;
  }
  // src = inclusive scan of counts
  int* og = csr_off + (size_t)b * (NN + 1);
  for (int i = tid; i <= NN; i += 256) og[i] = (i == 0) ? 0 : src[i - 1];
  for (int i = tid; i < NN; i += 256) s_cnt[i] = 0;  // reuse as fill cursors
  __syncthreads();
  int* rg = csr_rows + (size_t)b * EE;
  for (int e = tid; e < EE; e += 256) {
    int c = ec[e];
    int p = atomicAdd(&s_cnt[c], 1);
    int base = (c == 0) ? 0 : src[c - 1];
    rg[base + p] = er[e];
  }
}

// ---------------- Kernel B: y1 = dinv * (x @ W1), x = [emb(id0),emb(id1),cont] ----------------
__global__ __launch_bounds__(256) void k_gcn1(
    const int* __restrict__ ids, const float* __restrict__ cont,
    const float* __restrict__ emb, const float* __restrict__ W1,
    const float* __restrict__ dinv, u32* __restrict__ y1)
{
  const int idx = blockIdx.x * 256 + threadIdx.x;   // BB*NN = 1428*256 exactly
  float acc[CH];
#pragma unroll
  for (int j = 0; j < CH; ++j) acc[j] = 0.f;
  const int2 id2 = ((const int2*)ids)[idx];
  const float2* __restrict__ p0 = (const float2*)(emb + (size_t)id2.x * ED2);
  const float2* __restrict__ p1 = (const float2*)(emb + (size_t)id2.y * ED2);
#pragma unroll 4
  for (int q = 0; q < 31; ++q) {
    float2 x2 = p0[q];
    const float* __restrict__ w = W1 + (2 * q) * CH;
#pragma unroll
    for (int j = 0; j < CH; ++j) acc[j] = fmaf(x2.x, w[j], acc[j]);
#pragma unroll
    for (int j = 0; j < CH; ++j) acc[j] = fmaf(x2.y, w[CH + j], acc[j]);
  }
#pragma unroll 4
  for (int q = 0; q < 31; ++q) {
    float2 x2 = p1[q];
    const float* __restrict__ w = W1 + (ED2 + 2 * q) * CH;
#pragma unroll
    for (int j = 0; j < CH; ++j) acc[j] = fmaf(x2.x, w[j], acc[j]);
#pragma unroll
    for (int j = 0; j < CH; ++j) acc[j] = fmaf(x2.y, w[CH + j], acc[j]);
  }
  const float* __restrict__ c3 = cont + (size_t)idx * 3;
#pragma unroll
  for (int k = 0; k < 3; ++k) {
    float xv = c3[k];
    const float* __restrict__ w = W1 + (124 + k) * CH;
#pragma unroll
    for (int j = 0; j < CH; ++j) acc[j] = fmaf(xv, w[j], acc[j]);
  }
  float dv = dinv[idx];
  u32* o = y1 + (size_t)idx * (CH / 2);
#pragma unroll
  for (int q = 0; q < CH / 2; ++q) o[q] = pack2(acc[2 * q] * dv, acc[2 * q + 1] * dv);
}

// ---------------- Kernels C/D/E: aggregate + bias + act + fused next matmul ----------------
// ACT 0: h = lrelu(t);  ACT 1: h = lrelu(t) + t.
// OUTC 32: yout_b[i,:] = dinv_i * (h @ Wn) packed bf16;  OUTC 1: yout_f[i] = dinv_i * (h @ Wn).
template<int ACT, int OUTC>
__global__ __launch_bounds__(256) void k_layer(
    const u32* __restrict__ yin, const float* __restrict__ dinv,
    const int* __restrict__ csr_off, const int* __restrict__ csr_rows,
    const float* __restrict__ bias, const float* __restrict__ Wn,
    u32* __restrict__ yout_b, float* __restrict__ yout_f)
{
  const int b = blockIdx.x, tid = threadIdx.x;
  __shared__ u32 s_y[NN * 16];
  __shared__ float s_dv[NN];
  __shared__ int s_off[NN + 1];
  const uint4* __restrict__ ysrc = (const uint4*)(yin + (size_t)b * NN * 16);
  uint4* sy4 = (uint4*)s_y;
  for (int s = tid; s < NN * 4; s += 256) {       // XOR-swizzled store (bank spread)
    int row = s >> 2, q = s & 3;
    sy4[(row << 2) | (q ^ (row & 3))] = ysrc[s];
  }
  for (int i = tid; i < NN; i += 256) s_dv[i] = dinv[(size_t)b * NN + i];
  for (int i = tid; i <= NN; i += 256) s_off[i] = csr_off[(size_t)b * (NN + 1) + i];
  __syncthreads();
  const int* __restrict__ rows = csr_rows + (size_t)b * EE;
  for (int i = tid; i < NN; i += 256) {
    float z[CH];
    {
      const uint4* rp = sy4 + (i << 2);
      int sw = i & 3;
#pragma unroll
      for (int q = 0; q < 4; ++q) {
        uint4 u = rp[q ^ sw];
        z[8 * q + 0] = bf_lo(u.x); z[8 * q + 1] = bf_hi(u.x);
        z[8 * q + 2] = bf_lo(u.y); z[8 * q + 3] = bf_hi(u.y);
        z[8 * q + 4] = bf_lo(u.z); z[8 * q + 5] = bf_hi(u.z);
        z[8 * q + 6] = bf_lo(u.w); z[8 * q + 7] = bf_hi(u.w);
      }
    }
    int o0 = s_off[i], o1 = s_off[i + 1];
    for (int k = o0; k < o1; ++k) {
      int r = rows[k];
      const uint4* rp = sy4 + (r << 2);
      int sw = r & 3;
#pragma unroll
      for (int q = 0; q < 4; ++q) {
        uint4 u = rp[q ^ sw];
        z[8 * q + 0] += bf_lo(u.x); z[8 * q + 1] += bf_hi(u.x);
        z[8 * q + 2] += bf_lo(u.y); z[8 * q + 3] += bf_hi(u.y);
        z[8 * q + 4] += bf_lo(u.z); z[8 * q + 5] += bf_hi(u.z);
        z[8 * q + 6] += bf_lo(u.w); z[8 * q + 7] += bf_hi(u.w);
      }
    }
    float dv = s_dv[i];
#pragma unroll
    for (int c = 0; c < CH; ++c) {
      float t = fmaf(dv, z[c], bias[c]);
      float l = (t > 0.f) ? t : 0.01f * t;
      z[c] = (ACT == 0) ? l : (l + t);
    }
    if (OUTC == CH) {
      float acc2[CH];
#pragma unroll
      for (int j = 0; j < CH; ++j) acc2[j] = 0.f;
#pragma unroll
      for (int c = 0; c < CH; ++c) {
        float hc = z[c];
        const float* __restrict__ wr = Wn + c * CH;
#pragma unroll
        for (int j = 0; j < CH; ++j) acc2[j] = fmaf(hc, wr[j], acc2[j]);
      }
      u32* o = yout_b + ((size_t)b * NN + i) * 16;
#pragma unroll
      for (int q = 0; q < 16; ++q) o[q] = pack2(acc2[2 * q] * dv, acc2[2 * q + 1] * dv);
    } else {
      float a = 0.f;
#pragma unroll
      for (int c = 0; c < CH; ++c) a = fmaf(z[c], Wn[c], a);
      yout_f[(size_t)b * NN + i] = a * dv;
    }
  }
}

// ---------------- Kernel F: 1-ch aggregate + lrelu, then FC1+relu, FC2+relu ----------------
__global__ __launch_bounds__(256) void k_tail(
    const float* __restrict__ y4, const float* __restrict__ dinv,
    const int* __restrict__ csr_off, const int* __restrict__ csr_rows,
    const float* __restrict__ b4, const float* __restrict__ Wf1,
    const float* __restrict__ bf1, const float* __restrict__ Wf2,
    const float* __restrict__ bf2, float* __restrict__ out)
{
  const int b = blockIdx.x, tid = threadIdx.x;
  __shared__ float s_y[NN];
  __shared__ float s_h[NN];
  __shared__ int s_off[NN + 1];
  __shared__ float s_red[256];
  __shared__ float s_u[128];
  for (int i = tid; i < NN; i += 256) s_y[i] = y4[(size_t)b * NN + i];
  for (int i = tid; i <= NN; i += 256) s_off[i] = csr_off[(size_t)b * (NN + 1) + i];
  __syncthreads();
  const int* __restrict__ rows = csr_rows + (size_t)b * EE;
  const float bb4 = b4[0];
  for (int i = tid; i < NN; i += 256) {
    float z = s_y[i];
    int o0 = s_off[i], o1 = s_off[i + 1];
    for (int k = o0; k < o1; ++k) z += s_y[rows[k]];
    float t = fmaf(dinv[(size_t)b * NN + i], z, bb4);
    s_h[i] = (t > 0.f) ? t : 0.01f * t;
  }
  __syncthreads();
  // FC1: 714 -> 128, split n-range over two half-warps-of-threads
  const int j = tid & 127, half = tid >> 7;
  float a = 0.f;
  const int n0 = half * 357, n1 = n0 + 357;
  for (int n = n0; n < n1; ++n) a = fmaf(s_h[n], Wf1[n * 128 + j], a);
  s_red[tid] = a;
  __syncthreads();
  if (tid < 128) {
    float v = s_red[tid] + s_red[tid + 128] + bf1[tid];
    s_u[tid] = fmaxf(v, 0.f);
  }
  __syncthreads();
  if (tid < 128) {
    float a2 = bf2[tid];
#pragma unroll 4
    for (int k = 0; k < 128; ++k) a2 = fmaf(s_u[k], Wf2[k * 128 + tid], a2);
    out[(size_t)b * 128 + tid] = fmaxf(a2, 0.f);
  }
}

extern "C" void kernel_launch(void* const* d_in, const int* in_sizes, int n_in,
                              void* d_out, int out_size, void* d_ws, size_t ws_size,
                              hipStream_t stream)
{
  (void)in_sizes; (void)n_in; (void)out_size; (void)ws_size;
  const int*   ids  = (const int*)d_in[0];
  const float* cont = (const float*)d_in[1];
  const int*   edges= (const int*)d_in[2];
  const float* emb  = (const float*)d_in[3];
  const float* W1   = (const float*)d_in[4];
  const float* b1   = (const float*)d_in[5];
  const float* W2   = (const float*)d_in[6];
  const float* b2   = (const float*)d_in[7];
  const float* W3   = (const float*)d_in[8];
  const float* b3   = (const float*)d_in[9];
  const float* W4   = (const float*)d_in[10];
  const float* b4   = (const float*)d_in[11];
  const float* Wf1  = (const float*)d_in[12];
  const float* bf1  = (const float*)d_in[13];
  const float* Wf2  = (const float*)d_in[14];
  const float* bf2  = (const float*)d_in[15];
  float* out = (float*)d_out;

  char* ws = (char*)d_ws;
  size_t off = 0;
  auto alloc = [&](size_t bytes) -> void* {
    void* p = ws + off;
    off = (off + bytes + 255) & ~(size_t)255;
    return p;
  };
  float* dinv     = (float*)alloc((size_t)BB * NN * 4);
  int*   csr_off  = (int*)  alloc((size_t)BB * (NN + 1) * 4);
  int*   csr_rows = (int*)  alloc((size_t)BB * EE * 4);
  u32*   yA       = (u32*)  alloc((size_t)BB * NN * 16 * 4);
  u32*   yB       = (u32*)  alloc((size_t)BB * NN * 16 * 4);
  float* y4       = (float*)alloc((size_t)BB * NN * 4);

  hipLaunchKernelGGL(k_prep, dim3(BB), dim3(256), 0, stream, edges, dinv, csr_off, csr_rows);
  hipLaunchKernelGGL(k_gcn1, dim3((BB * NN) / 256), dim3(256), 0, stream,
                     ids, cont, emb, W1, dinv, yA);
  hipLaunchKernelGGL((k_layer<0, 32>), dim3(BB), dim3(256), 0, stream,
                     yA, dinv, csr_off, csr_rows, b1, W2, yB, (float*)nullptr);
  hipLaunchKernelGGL((k_layer<1, 32>), dim3(BB), dim3(256), 0, stream,
                     yB, dinv, csr_off, csr_rows, b2, W3, yA, (float*)nullptr);
  hipLaunchKernelGGL((k_layer<1, 1>),  dim3(BB), dim3(256), 0, stream,
                     yA, dinv, csr_off, csr_rows, b3, W4, (u32*)nullptr, y4);
  hipLaunchKernelGGL(k_tail, dim3(BB), dim3(256), 0, stream,
                     y4, dinv, csr_off, csr_rows, b4, Wf1, bf1, Wf2, bf2, out);
}

// Round 2
// 243.408 us; speedup vs baseline: 1.4410x; 1.4410x over previous
//
#include <hip/hip_runtime.h>
#include <hip/hip_bf16.h>

#define BB 512
#define NN 714
#define EE 4096
#define ED2 62
#define CH 32

typedef unsigned int u32;
typedef short short8 __attribute__((ext_vector_type(8)));
typedef float float4v __attribute__((ext_vector_type(4)));

__device__ __forceinline__ u32 f2bf(float f) {
  u32 u = __float_as_uint(f);
  return (u + 0x7fffu + ((u >> 16) & 1u)) >> 16;
}
__device__ __forceinline__ u32 pack2(float a, float b) {
  return f2bf(a) | (f2bf(b) << 16);
}
__device__ __forceinline__ float bf_lo(u32 u) { return __uint_as_float(u << 16); }
__device__ __forceinline__ float bf_hi(u32 u) { return __uint_as_float(u & 0xffff0000u); }

// ---------------- Kernel A: degree, dinv, CSR (sorted-by-col row list) ----------------
__global__ __launch_bounds__(256) void k_prep(const int* __restrict__ edges,
    float* __restrict__ dinv, int* __restrict__ csr_off, int* __restrict__ csr_rows)
{
  const int b = blockIdx.x;
  const int tid = threadIdx.x;
  const int* __restrict__ er = edges + (size_t)b * 2 * EE;       // e[0] = source (row)
  const int* __restrict__ ec = er + EE;                          // e[1] = target (col)
  __shared__ int s_cnt[NN];
  __shared__ int s_a[1024];
  __shared__ int s_b[1024];
  for (int i = tid; i < NN; i += 256) s_cnt[i] = 0;
  __syncthreads();
  for (int e = tid; e < EE; e += 256) atomicAdd(&s_cnt[ec[e]], 1);
  __syncthreads();
  for (int i = tid; i < 1024; i += 256) s_a[i] = (i < NN) ? s_cnt[i] : 0;
  for (int i = tid; i < NN; i += 256)
    dinv[(size_t)b * NN + i] = rsqrtf((float)(s_cnt[i] + 1));    // +1 self loop
  __syncthreads();
  int* src = s_a; int* dst = s_b;
  for (int d = 1; d < 1024; d <<= 1) {
    for (int i = tid; i < 1024; i += 256) {
      int v = src[i];
      if (i >= d) v += src[i - d];
      dst[i] = v;
    }
    __syncthreads();
    int* t = src; src = dst; dst = t;
  }
  // src = inclusive scan of counts
  int* og = csr_off + (size_t)b * (NN + 1);
  for (int i = tid; i <= NN; i += 256) og[i] = (i == 0) ? 0 : src[i - 1];
  for (int i = tid; i < NN; i += 256) s_cnt[i] = 0;  // reuse as fill cursors
  __syncthreads();
  int* rg = csr_rows + (size_t)b * EE;
  for (int e = tid; e < EE; e += 256) {
    int c = ec[e];
    int p = atomicAdd(&s_cnt[c], 1);
    int base = (c == 0) ? 0 : src[c - 1];
    rg[base + p] = er[e];
  }
}

// ---------------- Kernel B: y1 = dinv * (x @ W1), x = [emb(id0),emb(id1),cont] ----------------
__global__ __launch_bounds__(256) void k_gcn1(
    const int* __restrict__ ids, const float* __restrict__ cont,
    const float* __restrict__ emb, const float* __restrict__ W1,
    const float* __restrict__ dinv, u32* __restrict__ y1)
{
  const int idx = blockIdx.x * 256 + threadIdx.x;   // BB*NN = 1428*256 exactly
  float acc[CH];
#pragma unroll
  for (int j = 0; j < CH; ++j) acc[j] = 0.f;
  const int2 id2 = ((const int2*)ids)[idx];
  const float2* __restrict__ p0 = (const float2*)(emb + (size_t)id2.x * ED2);
  const float2* __restrict__ p1 = (const float2*)(emb + (size_t)id2.y * ED2);
#pragma unroll 4
  for (int q = 0; q < 31; ++q) {
    float2 x2 = p0[q];
    const float* __restrict__ w = W1 + (2 * q) * CH;
#pragma unroll
    for (int j = 0; j < CH; ++j) acc[j] = fmaf(x2.x, w[j], acc[j]);
#pragma unroll
    for (int j = 0; j < CH; ++j) acc[j] = fmaf(x2.y, w[CH + j], acc[j]);
  }
#pragma unroll 4
  for (int q = 0; q < 31; ++q) {
    float2 x2 = p1[q];
    const float* __restrict__ w = W1 + (ED2 + 2 * q) * CH;
#pragma unroll
    for (int j = 0; j < CH; ++j) acc[j] = fmaf(x2.x, w[j], acc[j]);
#pragma unroll
    for (int j = 0; j < CH; ++j) acc[j] = fmaf(x2.y, w[CH + j], acc[j]);
  }
  const float* __restrict__ c3 = cont + (size_t)idx * 3;
#pragma unroll
  for (int k = 0; k < 3; ++k) {
    float xv = c3[k];
    const float* __restrict__ w = W1 + (124 + k) * CH;
#pragma unroll
    for (int j = 0; j < CH; ++j) acc[j] = fmaf(xv, w[j], acc[j]);
  }
  float dv = dinv[idx];
  u32* o = y1 + (size_t)idx * (CH / 2);
#pragma unroll
  for (int q = 0; q < CH / 2; ++q) o[q] = pack2(acc[2 * q] * dv, acc[2 * q + 1] * dv);
}

// ---------------- Kernels C/D/E: 4-lane/node aggregate + act + MFMA next matmul ----------------
// node = lane&15, channel-group kg = lane>>4 (8 ch each). Agg register layout IS the
// B-fragment of mfma_f32_16x16x32_bf16 computing D[ch_out][node] = sum_k W[k][ch_out]*h[node][k].
// ACT 0: h = lrelu(t);  ACT 1: h = lrelu(t) + t.
template<int ACT, int OUTC>
__global__ __launch_bounds__(512, 6) void k_layer2(
    const u32* __restrict__ yin, const float* __restrict__ dinv,
    const int* __restrict__ csr_off, const int* __restrict__ csr_rows,
    const float* __restrict__ bias, const float* __restrict__ Wn,
    u32* __restrict__ yout_b, float* __restrict__ yout_f)
{
  const int bid = blockIdx.x;
  const int b = bid >> 1, chunk = bid & 1;
  const int tid = threadIdx.x;
  const int lane = tid & 63;
  const int wv = tid >> 6;          // wave 0..7
  const int col = lane & 15;        // node-in-tile
  const int kg = lane >> 4;         // channel group 0..3

  __shared__ u32 s_y[NN * 16];
  __shared__ float s_dv[NN];
  __shared__ int s_off[NN + 1];

  const uint4* __restrict__ ysrc = (const uint4*)(yin + (size_t)b * NN * 16);
  uint4* sy4 = (uint4*)s_y;
  for (int s = tid; s < NN * 4; s += 512) sy4[s] = ysrc[s];
  for (int i = tid; i < NN; i += 512) s_dv[i] = dinv[(size_t)b * NN + i];
  for (int i = tid; i <= NN; i += 512) s_off[i] = csr_off[(size_t)b * (NN + 1) + i];

  // hoist per-lane W fragments / bias (loop-invariant)
  union { u32 u[4]; short8 v; } ua0, ua1;
  float w4r[8];
  if (OUTC == CH) {
#pragma unroll
    for (int jj = 0; jj < 4; ++jj) {
      float wa = Wn[(kg * 8 + 2 * jj) * CH + col];
      float wb = Wn[(kg * 8 + 2 * jj + 1) * CH + col];
      ua0.u[jj] = pack2(wa, wb);
      float wc = Wn[(kg * 8 + 2 * jj) * CH + 16 + col];
      float wd = Wn[(kg * 8 + 2 * jj + 1) * CH + 16 + col];
      ua1.u[jj] = pack2(wc, wd);
    }
  } else {
#pragma unroll
    for (int j = 0; j < 8; ++j) w4r[j] = Wn[kg * 8 + j];
  }
  float bias8[8];
#pragma unroll
  for (int j = 0; j < 8; ++j) bias8[j] = bias[kg * 8 + j];
  __syncthreads();

  const int* __restrict__ rows = csr_rows + (size_t)b * EE;
  const int base0 = chunk * 357;
  const int nend = base0 + 357;

#pragma unroll 1
  for (int p = 0; p < 3; ++p) {
    const int node = base0 + (p * 8 + wv) * 16 + col;
    const bool valid = node < nend;
    float zx[8];
#pragma unroll
    for (int j = 0; j < 8; ++j) zx[j] = 0.f;
    if (valid) {
      uint4 u = sy4[node * 4 + kg];
      zx[0] += bf_lo(u.x); zx[1] += bf_hi(u.x);
      zx[2] += bf_lo(u.y); zx[3] += bf_hi(u.y);
      zx[4] += bf_lo(u.z); zx[5] += bf_hi(u.z);
      zx[6] += bf_lo(u.w); zx[7] += bf_hi(u.w);
      const int o0 = s_off[node], o1 = s_off[node + 1];
      for (int k = o0; k < o1; ++k) {
        uint4 n = sy4[rows[k] * 4 + kg];
        zx[0] += bf_lo(n.x); zx[1] += bf_hi(n.x);
        zx[2] += bf_lo(n.y); zx[3] += bf_hi(n.y);
        zx[4] += bf_lo(n.z); zx[5] += bf_hi(n.z);
        zx[6] += bf_lo(n.w); zx[7] += bf_hi(n.w);
      }
    }
    const float dv = valid ? s_dv[node] : 0.f;
    float h[8];
#pragma unroll
    for (int j = 0; j < 8; ++j) {
      float t = fmaf(dv, zx[j], bias8[j]);
      float l = (t > 0.f) ? t : 0.01f * t;
      h[j] = (ACT == 0) ? l : (l + t);
    }
    if (OUTC == CH) {
      union { u32 u[4]; short8 v; } ub;
#pragma unroll
      for (int jj = 0; jj < 4; ++jj) ub.u[jj] = pack2(h[2 * jj], h[2 * jj + 1]);
      float4v z4 = {0.f, 0.f, 0.f, 0.f};
      float4v d0 = __builtin_amdgcn_mfma_f32_16x16x32_bf16(ua0.v, ub.v, z4, 0, 0, 0);
      float4v d1 = __builtin_amdgcn_mfma_f32_16x16x32_bf16(ua1.v, ub.v, z4, 0, 0, 0);
      if (valid) {
        u32* op = yout_b + ((size_t)b * NN + node) * 16;
        uint2 s0 = { pack2(d0[0] * dv, d0[1] * dv), pack2(d0[2] * dv, d0[3] * dv) };
        uint2 s1 = { pack2(d1[0] * dv, d1[1] * dv), pack2(d1[2] * dv, d1[3] * dv) };
        *(uint2*)(op + 2 * kg) = s0;
        *(uint2*)(op + 8 + 2 * kg) = s1;
      }
    } else {
      float part = 0.f;
#pragma unroll
      for (int j = 0; j < 8; ++j) part = fmaf(h[j], w4r[j], part);
      part += __shfl_xor(part, 16, 64);
      part += __shfl_xor(part, 32, 64);
      if (valid && kg == 0) yout_f[(size_t)b * NN + node] = part * dv;
    }
  }
}

// ---------------- Kernel F: 1-ch aggregate + lrelu, then FC1+relu, FC2+relu ----------------
__global__ __launch_bounds__(256) void k_tail(
    const float* __restrict__ y4, const float* __restrict__ dinv,
    const int* __restrict__ csr_off, const int* __restrict__ csr_rows,
    const float* __restrict__ b4, const float* __restrict__ Wf1,
    const float* __restrict__ bf1, const float* __restrict__ Wf2,
    const float* __restrict__ bf2, float* __restrict__ out)
{
  const int b = blockIdx.x, tid = threadIdx.x;
  __shared__ float s_y[NN];
  __shared__ float s_h[NN];
  __shared__ int s_off[NN + 1];
  __shared__ float s_red[256];
  __shared__ float s_u[128];
  for (int i = tid; i < NN; i += 256) s_y[i] = y4[(size_t)b * NN + i];
  for (int i = tid; i <= NN; i += 256) s_off[i] = csr_off[(size_t)b * (NN + 1) + i];
  __syncthreads();
  const int* __restrict__ rows = csr_rows + (size_t)b * EE;
  const float bb4 = b4[0];
  for (int i = tid; i < NN; i += 256) {
    float z = s_y[i];
    int o0 = s_off[i], o1 = s_off[i + 1];
    for (int k = o0; k < o1; ++k) z += s_y[rows[k]];
    float t = fmaf(dinv[(size_t)b * NN + i], z, bb4);
    s_h[i] = (t > 0.f) ? t : 0.01f * t;
  }
  __syncthreads();
  // FC1: 714 -> 128
  const int j = tid & 127, half = tid >> 7;
  float a = 0.f;
  const int n0 = half * 357, n1 = n0 + 357;
  for (int n = n0; n < n1; ++n) a = fmaf(s_h[n], Wf1[n * 128 + j], a);
  s_red[tid] = a;
  __syncthreads();
  if (tid < 128) {
    float v = s_red[tid] + s_red[tid + 128] + bf1[tid];
    s_u[tid] = fmaxf(v, 0.f);
  }
  __syncthreads();
  if (tid < 128) {
    float a2 = bf2[tid];
#pragma unroll 4
    for (int k = 0; k < 128; ++k) a2 = fmaf(s_u[k], Wf2[k * 128 + tid], a2);
    out[(size_t)b * 128 + tid] = fmaxf(a2, 0.f);
  }
}

extern "C" void kernel_launch(void* const* d_in, const int* in_sizes, int n_in,
                              void* d_out, int out_size, void* d_ws, size_t ws_size,
                              hipStream_t stream)
{
  (void)in_sizes; (void)n_in; (void)out_size; (void)ws_size;
  const int*   ids  = (const int*)d_in[0];
  const float* cont = (const float*)d_in[1];
  const int*   edges= (const int*)d_in[2];
  const float* emb  = (const float*)d_in[3];
  const float* W1   = (const float*)d_in[4];
  const float* b1   = (const float*)d_in[5];
  const float* W2   = (const float*)d_in[6];
  const float* b2   = (const float*)d_in[7];
  const float* W3   = (const float*)d_in[8];
  const float* b3   = (const float*)d_in[9];
  const float* W4   = (const float*)d_in[10];
  const float* b4   = (const float*)d_in[11];
  const float* Wf1  = (const float*)d_in[12];
  const float* bf1  = (const float*)d_in[13];
  const float* Wf2  = (const float*)d_in[14];
  const float* bf2  = (const float*)d_in[15];
  float* out = (float*)d_out;

  char* ws = (char*)d_ws;
  size_t off = 0;
  auto alloc = [&](size_t bytes) -> void* {
    void* p = ws + off;
    off = (off + bytes + 255) & ~(size_t)255;
    return p;
  };
  float* dinv     = (float*)alloc((size_t)BB * NN * 4);
  int*   csr_off  = (int*)  alloc((size_t)BB * (NN + 1) * 4);
  int*   csr_rows = (int*)  alloc((size_t)BB * EE * 4);
  u32*   yA       = (u32*)  alloc((size_t)BB * NN * 16 * 4);
  u32*   yB       = (u32*)  alloc((size_t)BB * NN * 16 * 4);
  float* y4       = (float*)alloc((size_t)BB * NN * 4);

  hipLaunchKernelGGL(k_prep, dim3(BB), dim3(256), 0, stream, edges, dinv, csr_off, csr_rows);
  hipLaunchKernelGGL(k_gcn1, dim3((BB * NN) / 256), dim3(256), 0, stream,
                     ids, cont, emb, W1, dinv, yA);
  hipLaunchKernelGGL((k_layer2<0, 32>), dim3(BB * 2), dim3(512), 0, stream,
                     yA, dinv, csr_off, csr_rows, b1, W2, yB, (float*)nullptr);
  hipLaunchKernelGGL((k_layer2<1, 32>), dim3(BB * 2), dim3(512), 0, stream,
                     yB, dinv, csr_off, csr_rows, b2, W3, yA, (float*)nullptr);
  hipLaunchKernelGGL((k_layer2<1, 1>),  dim3(BB * 2), dim3(512), 0, stream,
                     yA, dinv, csr_off, csr_rows, b3, W4, (u32*)nullptr, y4);
  hipLaunchKernelGGL(k_tail, dim3(BB), dim3(256), 0, stream,
                     y4, dinv, csr_off, csr_rows, b4, Wf1, bf1, Wf2, bf2, out);
}

// Round 3
// 236.908 us; speedup vs baseline: 1.4806x; 1.0274x over previous
//
#include <hip/hip_runtime.h>
#include <hip/hip_bf16.h>

#define BB 512
#define NN 714
#define EE 4096
#define ED2 62
#define CH 32

typedef unsigned int u32;
typedef short short8 __attribute__((ext_vector_type(8)));
typedef float float4v __attribute__((ext_vector_type(4)));

__device__ __forceinline__ u32 f2bf(float f) {
  u32 u = __float_as_uint(f);
  return (u + 0x7fffu + ((u >> 16) & 1u)) >> 16;
}
__device__ __forceinline__ u32 pack2(float a, float b) {
  return f2bf(a) | (f2bf(b) << 16);
}
__device__ __forceinline__ float bf_lo(u32 u) { return __uint_as_float(u << 16); }
__device__ __forceinline__ float bf_hi(u32 u) { return __uint_as_float(u & 0xffff0000u); }

// ---------------- Kernel A: degree, dinv, CSR (sorted-by-col row list) ----------------
__global__ __launch_bounds__(256) void k_prep(const int* __restrict__ edges,
    float* __restrict__ dinv, int* __restrict__ csr_off, int* __restrict__ csr_rows)
{
  const int b = blockIdx.x;
  const int tid = threadIdx.x;
  const int* __restrict__ er = edges + (size_t)b * 2 * EE;       // e[0] = source (row)
  const int* __restrict__ ec = er + EE;                          // e[1] = target (col)
  __shared__ int s_cnt[NN];
  __shared__ int s_a[1024];
  __shared__ int s_b[1024];
  for (int i = tid; i < NN; i += 256) s_cnt[i] = 0;
  __syncthreads();
  for (int e = tid; e < EE; e += 256) atomicAdd(&s_cnt[ec[e]], 1);
  __syncthreads();
  for (int i = tid; i < 1024; i += 256) s_a[i] = (i < NN) ? s_cnt[i] : 0;
  for (int i = tid; i < NN; i += 256)
    dinv[(size_t)b * NN + i] = rsqrtf((float)(s_cnt[i] + 1));    // +1 self loop
  __syncthreads();
  int* src = s_a; int* dst = s_b;
  for (int d = 1; d < 1024; d <<= 1) {
    for (int i = tid; i < 1024; i += 256) {
      int v = src[i];
      if (i >= d) v += src[i - d];
      dst[i] = v;
    }
    __syncthreads();
    int* t = src; src = dst; dst = t;
  }
  // src = inclusive scan of counts
  int* og = csr_off + (size_t)b * (NN + 1);
  for (int i = tid; i <= NN; i += 256) og[i] = (i == 0) ? 0 : src[i - 1];
  for (int i = tid; i < NN; i += 256) s_cnt[i] = 0;  // reuse as fill cursors
  __syncthreads();
  int* rg = csr_rows + (size_t)b * EE;
  for (int e = tid; e < EE; e += 256) {
    int c = ec[e];
    int p = atomicAdd(&s_cnt[c], 1);
    int base = (c == 0) ? 0 : src[c - 1];
    rg[base + p] = er[e];
  }
}

// ---------------- Kernel B: cooperative-staged MFMA GCN1 ----------------
// Block = 128 nodes (256 emb rows). Wave-coalesced row loads -> bf16 LDS tile
// X[128][128] (cols 0..123 = emb pair, 124..127 = 0, XOR-swizzled). MFMA computes
// D[ch][node] = sum_k W1[k][ch] * X[node][k]; cont (3 ch) added in f32.
__global__ __launch_bounds__(256) void k_gcn1m(
    const int* __restrict__ ids, const float* __restrict__ cont,
    const float* __restrict__ emb, const float* __restrict__ W1,
    const float* __restrict__ dinv, u32* __restrict__ y1)
{
  const int bid = blockIdx.x;
  const int b = bid / 6, blk = bid - b * 6;
  const int base = blk * 128;
  const int nnodes = (NN - base < 128) ? (NN - base) : 128;
  const int nrows = nnodes * 2;
  const int tid = threadIdx.x, lane = tid & 63, wv = tid >> 6;
  const int col = lane & 15, kg = lane >> 4;

  __shared__ __align__(16) unsigned short sX[128 * 128];
  __shared__ float sC[128][4];

  for (int t = tid; t < nnodes * 3; t += 256)
    sC[t / 3][t % 3] = cont[((size_t)b * NN + base) * 3 + t];

  const int rowbase = wv * 64;
  int myid = 0;
  if (rowbase + lane < nrows)
    myid = ids[((size_t)b * NN + base) * 2 + rowbase + lane];

#pragma unroll 4
  for (int i = 0; i < 64; ++i) {
    const int r = rowbase + i;
    const bool rv = (r < nrows);
    const int id = __shfl(myid, i);
    float v = 0.f;
    if (rv && lane < ED2) v = emb[(size_t)id * ED2 + lane];
    if (rv) {
      const int node = r >> 1, slot = r & 1;
      const int c = slot ? (ED2 + lane) : (lane < ED2 ? lane : 64 + lane);
      const int idx = (node * 128 + c) ^ ((node & 7) << 3);
      sX[idx] = (unsigned short)f2bf(v);
    }
  }

  // hoist W1 MFMA fragments (bf16) and cont-channel weights (f32)
  union { u32 u[4]; short8 v; } A[4][2];
#pragma unroll
  for (int kc = 0; kc < 4; ++kc)
#pragma unroll
    for (int hh = 0; hh < 2; ++hh)
#pragma unroll
      for (int jj = 0; jj < 4; ++jj) {
        const int k0 = kc * 32 + kg * 8 + 2 * jj;
        const float wa = (k0 < 124) ? W1[k0 * CH + hh * 16 + col] : 0.f;
        const float wb = (k0 + 1 < 124) ? W1[(k0 + 1) * CH + hh * 16 + col] : 0.f;
        A[kc][hh].u[jj] = pack2(wa, wb);
      }
  float Wc0[3][4], Wc1[3][4];
#pragma unroll
  for (int j = 0; j < 3; ++j)
#pragma unroll
    for (int reg = 0; reg < 4; ++reg) {
      Wc0[j][reg] = W1[(124 + j) * CH + 4 * kg + reg];
      Wc1[j][reg] = W1[(124 + j) * CH + 16 + 4 * kg + reg];
    }
  __syncthreads();

  const int ntiles = (nnodes + 15) >> 4;
  for (int t = wv; t < ntiles; t += 4) {
    const int ln = t * 16 + col;
    float4v a0 = {0.f, 0.f, 0.f, 0.f}, a1 = {0.f, 0.f, 0.f, 0.f};
#pragma unroll
    for (int kc = 0; kc < 4; ++kc) {
      const int idx16 = (ln * 16 + kc * 4 + kg) ^ (ln & 7);
      short8 bf = *(const short8*)(sX + idx16 * 8);
      a0 = __builtin_amdgcn_mfma_f32_16x16x32_bf16(A[kc][0].v, bf, a0, 0, 0, 0);
      a1 = __builtin_amdgcn_mfma_f32_16x16x32_bf16(A[kc][1].v, bf, a1, 0, 0, 0);
    }
#pragma unroll
    for (int j = 0; j < 3; ++j) {
      const float cv = sC[ln][j];
#pragma unroll
      for (int reg = 0; reg < 4; ++reg) {
        a0[reg] = fmaf(cv, Wc0[j][reg], a0[reg]);
        a1[reg] = fmaf(cv, Wc1[j][reg], a1[reg]);
      }
    }
    if (ln < nnodes) {
      const int gnode = base + ln;
      const float dv = dinv[(size_t)b * NN + gnode];
      u32* op = y1 + ((size_t)b * NN + gnode) * 16;
      uint2 s0 = { pack2(a0[0] * dv, a0[1] * dv), pack2(a0[2] * dv, a0[3] * dv) };
      uint2 s1 = { pack2(a1[0] * dv, a1[1] * dv), pack2(a1[2] * dv, a1[3] * dv) };
      *(uint2*)(op + 2 * kg) = s0;
      *(uint2*)(op + 8 + 2 * kg) = s1;
    }
  }
}

// ---------------- Kernels C/D/E: 4-lane/node aggregate + act + MFMA next matmul ----------------
template<int ACT, int OUTC>
__global__ __launch_bounds__(512, 6) void k_layer2(
    const u32* __restrict__ yin, const float* __restrict__ dinv,
    const int* __restrict__ csr_off, const int* __restrict__ csr_rows,
    const float* __restrict__ bias, const float* __restrict__ Wn,
    u32* __restrict__ yout_b, float* __restrict__ yout_f)
{
  const int bid = blockIdx.x;
  const int b = bid >> 1, chunk = bid & 1;
  const int tid = threadIdx.x;
  const int lane = tid & 63;
  const int wv = tid >> 6;          // wave 0..7
  const int col = lane & 15;        // node-in-tile
  const int kg = lane >> 4;         // channel group 0..3

  __shared__ u32 s_y[NN * 16];
  __shared__ float s_dv[NN];
  __shared__ int s_off[NN + 1];

  const uint4* __restrict__ ysrc = (const uint4*)(yin + (size_t)b * NN * 16);
  uint4* sy4 = (uint4*)s_y;
  for (int s = tid; s < NN * 4; s += 512) sy4[s] = ysrc[s];
  for (int i = tid; i < NN; i += 512) s_dv[i] = dinv[(size_t)b * NN + i];
  for (int i = tid; i <= NN; i += 512) s_off[i] = csr_off[(size_t)b * (NN + 1) + i];

  // hoist per-lane W fragments / bias (loop-invariant)
  union { u32 u[4]; short8 v; } ua0, ua1;
  float w4r[8];
  if (OUTC == CH) {
#pragma unroll
    for (int jj = 0; jj < 4; ++jj) {
      float wa = Wn[(kg * 8 + 2 * jj) * CH + col];
      float wb = Wn[(kg * 8 + 2 * jj + 1) * CH + col];
      ua0.u[jj] = pack2(wa, wb);
      float wc = Wn[(kg * 8 + 2 * jj) * CH + 16 + col];
      float wd = Wn[(kg * 8 + 2 * jj + 1) * CH + 16 + col];
      ua1.u[jj] = pack2(wc, wd);
    }
  } else {
#pragma unroll
    for (int j = 0; j < 8; ++j) w4r[j] = Wn[kg * 8 + j];
  }
  float bias8[8];
#pragma unroll
  for (int j = 0; j < 8; ++j) bias8[j] = bias[kg * 8 + j];
  __syncthreads();

  const int* __restrict__ rows = csr_rows + (size_t)b * EE;
  const int base0 = chunk * 357;
  const int nend = base0 + 357;

#pragma unroll 1
  for (int p = 0; p < 3; ++p) {
    const int node = base0 + (p * 8 + wv) * 16 + col;
    const bool valid = node < nend;
    float zx[8];
#pragma unroll
    for (int j = 0; j < 8; ++j) zx[j] = 0.f;
    if (valid) {
      uint4 u = sy4[node * 4 + kg];
      zx[0] += bf_lo(u.x); zx[1] += bf_hi(u.x);
      zx[2] += bf_lo(u.y); zx[3] += bf_hi(u.y);
      zx[4] += bf_lo(u.z); zx[5] += bf_hi(u.z);
      zx[6] += bf_lo(u.w); zx[7] += bf_hi(u.w);
      const int o0 = s_off[node], o1 = s_off[node + 1];
      for (int k = o0; k < o1; ++k) {
        uint4 n = sy4[rows[k] * 4 + kg];
        zx[0] += bf_lo(n.x); zx[1] += bf_hi(n.x);
        zx[2] += bf_lo(n.y); zx[3] += bf_hi(n.y);
        zx[4] += bf_lo(n.z); zx[5] += bf_hi(n.z);
        zx[6] += bf_lo(n.w); zx[7] += bf_hi(n.w);
      }
    }
    const float dv = valid ? s_dv[node] : 0.f;
    float h[8];
#pragma unroll
    for (int j = 0; j < 8; ++j) {
      float t = fmaf(dv, zx[j], bias8[j]);
      float l = (t > 0.f) ? t : 0.01f * t;
      h[j] = (ACT == 0) ? l : (l + t);
    }
    if (OUTC == CH) {
      union { u32 u[4]; short8 v; } ub;
#pragma unroll
      for (int jj = 0; jj < 4; ++jj) ub.u[jj] = pack2(h[2 * jj], h[2 * jj + 1]);
      float4v z4 = {0.f, 0.f, 0.f, 0.f};
      float4v d0 = __builtin_amdgcn_mfma_f32_16x16x32_bf16(ua0.v, ub.v, z4, 0, 0, 0);
      float4v d1 = __builtin_amdgcn_mfma_f32_16x16x32_bf16(ua1.v, ub.v, z4, 0, 0, 0);
      if (valid) {
        u32* op = yout_b + ((size_t)b * NN + node) * 16;
        uint2 s0 = { pack2(d0[0] * dv, d0[1] * dv), pack2(d0[2] * dv, d0[3] * dv) };
        uint2 s1 = { pack2(d1[0] * dv, d1[1] * dv), pack2(d1[2] * dv, d1[3] * dv) };
        *(uint2*)(op + 2 * kg) = s0;
        *(uint2*)(op + 8 + 2 * kg) = s1;
      }
    } else {
      float part = 0.f;
#pragma unroll
      for (int j = 0; j < 8; ++j) part = fmaf(h[j], w4r[j], part);
      part += __shfl_xor(part, 16, 64);
      part += __shfl_xor(part, 32, 64);
      if (valid && kg == 0) yout_f[(size_t)b * NN + node] = part * dv;
    }
  }
}

// ---------------- Kernel F: 1-ch aggregate + lrelu, then FC1+relu, FC2+relu ----------------
__global__ __launch_bounds__(256) void k_tail(
    const float* __restrict__ y4, const float* __restrict__ dinv,
    const int* __restrict__ csr_off, const int* __restrict__ csr_rows,
    const float* __restrict__ b4, const float* __restrict__ Wf1,
    const float* __restrict__ bf1, const float* __restrict__ Wf2,
    const float* __restrict__ bf2, float* __restrict__ out)
{
  const int b = blockIdx.x, tid = threadIdx.x;
  __shared__ float s_y[NN];
  __shared__ float s_h[NN];
  __shared__ int s_off[NN + 1];
  __shared__ float s_red[256];
  __shared__ float s_u[128];
  for (int i = tid; i < NN; i += 256) s_y[i] = y4[(size_t)b * NN + i];
  for (int i = tid; i <= NN; i += 256) s_off[i] = csr_off[(size_t)b * (NN + 1) + i];
  __syncthreads();
  const int* __restrict__ rows = csr_rows + (size_t)b * EE;
  const float bb4 = b4[0];
  for (int i = tid; i < NN; i += 256) {
    float z = s_y[i];
    int o0 = s_off[i], o1 = s_off[i + 1];
    for (int k = o0; k < o1; ++k) z += s_y[rows[k]];
    float t = fmaf(dinv[(size_t)b * NN + i], z, bb4);
    s_h[i] = (t > 0.f) ? t : 0.01f * t;
  }
  __syncthreads();
  // FC1: 714 -> 128
  const int j = tid & 127, half = tid >> 7;
  float a = 0.f;
  const int n0 = half * 357, n1 = n0 + 357;
  for (int n = n0; n < n1; ++n) a = fmaf(s_h[n], Wf1[n * 128 + j], a);
  s_red[tid] = a;
  __syncthreads();
  if (tid < 128) {
    float v = s_red[tid] + s_red[tid + 128] + bf1[tid];
    s_u[tid] = fmaxf(v, 0.f);
  }
  __syncthreads();
  if (tid < 128) {
    float a2 = bf2[tid];
#pragma unroll 4
    for (int k = 0; k < 128; ++k) a2 = fmaf(s_u[k], Wf2[k * 128 + tid], a2);
    out[(size_t)b * 128 + tid] = fmaxf(a2, 0.f);
  }
}

extern "C" void kernel_launch(void* const* d_in, const int* in_sizes, int n_in,
                              void* d_out, int out_size, void* d_ws, size_t ws_size,
                              hipStream_t stream)
{
  (void)in_sizes; (void)n_in; (void)out_size; (void)ws_size;
  const int*   ids  = (const int*)d_in[0];
  const float* cont = (const float*)d_in[1];
  const int*   edges= (const int*)d_in[2];
  const float* emb  = (const float*)d_in[3];
  const float* W1   = (const float*)d_in[4];
  const float* b1   = (const float*)d_in[5];
  const float* W2   = (const float*)d_in[6];
  const float* b2   = (const float*)d_in[7];
  const float* W3   = (const float*)d_in[8];
  const float* b3   = (const float*)d_in[9];
  const float* W4   = (const float*)d_in[10];
  const float* b4   = (const float*)d_in[11];
  const float* Wf1  = (const float*)d_in[12];
  const float* bf1  = (const float*)d_in[13];
  const float* Wf2  = (const float*)d_in[14];
  const float* bf2  = (const float*)d_in[15];
  float* out = (float*)d_out;

  char* ws = (char*)d_ws;
  size_t off = 0;
  auto alloc = [&](size_t bytes) -> void* {
    void* p = ws + off;
    off = (off + bytes + 255) & ~(size_t)255;
    return p;
  };
  float* dinv     = (float*)alloc((size_t)BB * NN * 4);
  int*   csr_off  = (int*)  alloc((size_t)BB * (NN + 1) * 4);
  int*   csr_rows = (int*)  alloc((size_t)BB * EE * 4);
  u32*   yA       = (u32*)  alloc((size_t)BB * NN * 16 * 4);
  u32*   yB       = (u32*)  alloc((size_t)BB * NN * 16 * 4);
  float* y4       = (float*)alloc((size_t)BB * NN * 4);

  hipLaunchKernelGGL(k_prep, dim3(BB), dim3(256), 0, stream, edges, dinv, csr_off, csr_rows);
  hipLaunchKernelGGL(k_gcn1m, dim3(BB * 6), dim3(256), 0, stream,
                     ids, cont, emb, W1, dinv, yA);
  hipLaunchKernelGGL((k_layer2<0, 32>), dim3(BB * 2), dim3(512), 0, stream,
                     yA, dinv, csr_off, csr_rows, b1, W2, yB, (float*)nullptr);
  hipLaunchKernelGGL((k_layer2<1, 32>), dim3(BB * 2), dim3(512), 0, stream,
                     yB, dinv, csr_off, csr_rows, b2, W3, yA, (float*)nullptr);
  hipLaunchKernelGGL((k_layer2<1, 1>),  dim3(BB * 2), dim3(512), 0, stream,
                     yA, dinv, csr_off, csr_rows, b3, W4, (u32*)nullptr, y4);
  hipLaunchKernelGGL(k_tail, dim3(BB), dim3(256), 0, stream,
                     y4, dinv, csr_off, csr_rows, b4, Wf1, bf1, Wf2, bf2, out);
}

// Round 4
// 192.285 us; speedup vs baseline: 1.8241x; 1.2321x over previous
//
#include <hip/hip_runtime.h>
#include <hip/hip_bf16.h>

#define BB 512
#define NN 714
#define EE 4096
#define ED2 62
#define CH 32

typedef unsigned int u32;
typedef short short8 __attribute__((ext_vector_type(8)));
typedef float float4v __attribute__((ext_vector_type(4)));

__device__ __forceinline__ u32 f2bf(float f) {
  u32 u = __float_as_uint(f);
  return (u + 0x7fffu + ((u >> 16) & 1u)) >> 16;
}
__device__ __forceinline__ u32 pack2(float a, float b) {
  return f2bf(a) | (f2bf(b) << 16);
}
__device__ __forceinline__ float bf_lo(u32 u) { return __uint_as_float(u << 16); }
__device__ __forceinline__ float bf_hi(u32 u) { return __uint_as_float(u & 0xffff0000u); }

// ---------------- Kernel A: degree, dinv, CSR (sorted-by-col row list) ----------------
__global__ __launch_bounds__(256) void k_prep(const int* __restrict__ edges,
    float* __restrict__ dinv, int* __restrict__ csr_off, int* __restrict__ csr_rows)
{
  const int b = blockIdx.x;
  const int tid = threadIdx.x;
  const int* __restrict__ er = edges + (size_t)b * 2 * EE;       // e[0] = source (row)
  const int* __restrict__ ec = er + EE;                          // e[1] = target (col)
  __shared__ int s_cnt[NN];
  __shared__ int s_a[1024];
  __shared__ int s_b[1024];
  for (int i = tid; i < NN; i += 256) s_cnt[i] = 0;
  __syncthreads();
  for (int e = tid; e < EE; e += 256) atomicAdd(&s_cnt[ec[e]], 1);
  __syncthreads();
  for (int i = tid; i < 1024; i += 256) s_a[i] = (i < NN) ? s_cnt[i] : 0;
  for (int i = tid; i < NN; i += 256)
    dinv[(size_t)b * NN + i] = rsqrtf((float)(s_cnt[i] + 1));    // +1 self loop
  __syncthreads();
  int* src = s_a; int* dst = s_b;
  for (int d = 1; d < 1024; d <<= 1) {
    for (int i = tid; i < 1024; i += 256) {
      int v = src[i];
      if (i >= d) v += src[i - d];
      dst[i] = v;
    }
    __syncthreads();
    int* t = src; src = dst; dst = t;
  }
  // src = inclusive scan of counts
  int* og = csr_off + (size_t)b * (NN + 1);
  for (int i = tid; i <= NN; i += 256) og[i] = (i == 0) ? 0 : src[i - 1];
  for (int i = tid; i < NN; i += 256) s_cnt[i] = 0;  // reuse as fill cursors
  __syncthreads();
  int* rg = csr_rows + (size_t)b * EE;
  for (int e = tid; e < EE; e += 256) {
    int c = ec[e];
    int p = atomicAdd(&s_cnt[c], 1);
    int base = (c == 0) ? 0 : src[c - 1];
    rg[base + p] = er[e];
  }
}

// ---------------- Kernel B: cooperative-staged MFMA GCN1 ----------------
// Block = 128 nodes (256 emb rows). Item-parallel staging: 2048 (row,chunk8) items,
// 8 per thread, 2 batches x 4 rows x 4 independent float2 loads -> 16 outstanding.
// LDS X[node][slot*64+e] bf16, 16B-chunk XOR swizzle; cols 62,63,126,127 = 0 and the
// W1 A-fragment is remapped (k<62->k; 62,63->0; 64..125->k-2; 126,127->0).
// MFMA D[ch][node] = sum_k W1'[k][ch] * X[node][k]; cont (3 ch) added in f32.
__global__ __launch_bounds__(256) void k_gcn1m(
    const int* __restrict__ ids, const float* __restrict__ cont,
    const float* __restrict__ emb, const float* __restrict__ W1,
    const float* __restrict__ dinv, u32* __restrict__ y1)
{
  const int bid = blockIdx.x;
  const int b = bid / 6, blk = bid - b * 6;
  const int base = blk * 128;
  const int nnodes = (NN - base < 128) ? (NN - base) : 128;
  const int nrows = nnodes * 2;
  const int tid = threadIdx.x, lane = tid & 63, wv = tid >> 6;
  const int col = lane & 15, kg = lane >> 4;

  __shared__ __align__(16) unsigned short sX[128 * 128];
  __shared__ float sC[128][4];
  __shared__ int s_ids[256];

  for (int t = tid; t < nnodes * 3; t += 256)
    sC[t / 3][t % 3] = cont[((size_t)b * NN + base) * 3 + t];
  s_ids[tid] = (tid < nrows) ? ids[((size_t)b * NN + base) * 2 + tid] : -1;
  __syncthreads();

  const int ck = tid & 7;           // 8-float chunk within row
  const int rbase = tid >> 3;       // 0..31
#pragma unroll
  for (int half = 0; half < 2; ++half) {
    float2 vv[4][4];
    int ids4[4];
#pragma unroll
    for (int q = 0; q < 4; ++q) ids4[q] = s_ids[(half * 4 + q) * 32 + rbase];
#pragma unroll
    for (int q = 0; q < 4; ++q) {
      const int id = ids4[q];
      if (id >= 0) {
        const float2* __restrict__ p = (const float2*)(emb + (size_t)id * ED2 + ck * 8);
        vv[q][0] = p[0]; vv[q][1] = p[1]; vv[q][2] = p[2];
        if (ck != 7) vv[q][3] = p[3];
        else { vv[q][3].x = 0.f; vv[q][3].y = 0.f; }
      } else {
        vv[q][0].x = vv[q][0].y = vv[q][1].x = vv[q][1].y = 0.f;
        vv[q][2].x = vv[q][2].y = vv[q][3].x = vv[q][3].y = 0.f;
      }
    }
#pragma unroll
    for (int q = 0; q < 4; ++q) {
      const int r = (half * 4 + q) * 32 + rbase;
      const int node = r >> 1, slot = r & 1;
      const int c16 = (node * 16 + slot * 8 + ck) ^ (node & 7);
      uint4 w = { pack2(vv[q][0].x, vv[q][0].y), pack2(vv[q][1].x, vv[q][1].y),
                  pack2(vv[q][2].x, vv[q][2].y), pack2(vv[q][3].x, vv[q][3].y) };
      ((uint4*)sX)[c16] = w;
    }
  }

  // hoist W1 MFMA fragments (bf16, remapped k) and cont-channel weights (f32)
  union { u32 u[4]; short8 v; } A[4][2];
#pragma unroll
  for (int kc = 0; kc < 4; ++kc)
#pragma unroll
    for (int hh = 0; hh < 2; ++hh)
#pragma unroll
      for (int jj = 0; jj < 4; ++jj) {
        const int k0 = kc * 32 + kg * 8 + 2 * jj;
        const int k1 = k0 + 1;
        const int m0 = (k0 < 62) ? k0 : ((k0 >= 64 && k0 < 126) ? k0 - 2 : -1);
        const int m1 = (k1 < 62) ? k1 : ((k1 >= 64 && k1 < 126) ? k1 - 2 : -1);
        const float wa = (m0 >= 0) ? W1[m0 * CH + hh * 16 + col] : 0.f;
        const float wb = (m1 >= 0) ? W1[m1 * CH + hh * 16 + col] : 0.f;
        A[kc][hh].u[jj] = pack2(wa, wb);
      }
  float Wc0[3][4], Wc1[3][4];
#pragma unroll
  for (int j = 0; j < 3; ++j)
#pragma unroll
    for (int reg = 0; reg < 4; ++reg) {
      Wc0[j][reg] = W1[(124 + j) * CH + 4 * kg + reg];
      Wc1[j][reg] = W1[(124 + j) * CH + 16 + 4 * kg + reg];
    }
  __syncthreads();

  const int ntiles = (nnodes + 15) >> 4;
  for (int t = wv; t < ntiles; t += 4) {
    const int ln = t * 16 + col;
    float4v a0 = {0.f, 0.f, 0.f, 0.f}, a1 = {0.f, 0.f, 0.f, 0.f};
#pragma unroll
    for (int kc = 0; kc < 4; ++kc) {
      const int idx16 = (ln * 16 + kc * 4 + kg) ^ (ln & 7);
      short8 bf = *(const short8*)(sX + idx16 * 8);
      a0 = __builtin_amdgcn_mfma_f32_16x16x32_bf16(A[kc][0].v, bf, a0, 0, 0, 0);
      a1 = __builtin_amdgcn_mfma_f32_16x16x32_bf16(A[kc][1].v, bf, a1, 0, 0, 0);
    }
#pragma unroll
    for (int j = 0; j < 3; ++j) {
      const float cv = sC[ln][j];
#pragma unroll
      for (int reg = 0; reg < 4; ++reg) {
        a0[reg] = fmaf(cv, Wc0[j][reg], a0[reg]);
        a1[reg] = fmaf(cv, Wc1[j][reg], a1[reg]);
      }
    }
    if (ln < nnodes) {
      const int gnode = base + ln;
      const float dv = dinv[(size_t)b * NN + gnode];
      u32* op = y1 + ((size_t)b * NN + gnode) * 16;
      uint2 s0 = { pack2(a0[0] * dv, a0[1] * dv), pack2(a0[2] * dv, a0[3] * dv) };
      uint2 s1 = { pack2(a1[0] * dv, a1[1] * dv), pack2(a1[2] * dv, a1[3] * dv) };
      *(uint2*)(op + 2 * kg) = s0;
      *(uint2*)(op + 8 + 2 * kg) = s1;
    }
  }
}

// ---------------- Kernels C/D/E: 4-lane/node aggregate + act + MFMA next matmul ----------------
template<int ACT, int OUTC>
__global__ __launch_bounds__(512, 6) void k_layer2(
    const u32* __restrict__ yin, const float* __restrict__ dinv,
    const int* __restrict__ csr_off, const int* __restrict__ csr_rows,
    const float* __restrict__ bias, const float* __restrict__ Wn,
    u32* __restrict__ yout_b, float* __restrict__ yout_f)
{
  const int bid = blockIdx.x;
  const int b = bid >> 1, chunk = bid & 1;
  const int tid = threadIdx.x;
  const int lane = tid & 63;
  const int wv = tid >> 6;          // wave 0..7
  const int col = lane & 15;        // node-in-tile
  const int kg = lane >> 4;         // channel group 0..3

  __shared__ u32 s_y[NN * 16];
  __shared__ float s_dv[NN];
  __shared__ int s_off[NN + 1];

  const uint4* __restrict__ ysrc = (const uint4*)(yin + (size_t)b * NN * 16);
  uint4* sy4 = (uint4*)s_y;
  for (int s = tid; s < NN * 4; s += 512) sy4[s] = ysrc[s];
  for (int i = tid; i < NN; i += 512) s_dv[i] = dinv[(size_t)b * NN + i];
  for (int i = tid; i <= NN; i += 512) s_off[i] = csr_off[(size_t)b * (NN + 1) + i];

  // hoist per-lane W fragments / bias (loop-invariant)
  union { u32 u[4]; short8 v; } ua0, ua1;
  float w4r[8];
  if (OUTC == CH) {
#pragma unroll
    for (int jj = 0; jj < 4; ++jj) {
      float wa = Wn[(kg * 8 + 2 * jj) * CH + col];
      float wb = Wn[(kg * 8 + 2 * jj + 1) * CH + col];
      ua0.u[jj] = pack2(wa, wb);
      float wc = Wn[(kg * 8 + 2 * jj) * CH + 16 + col];
      float wd = Wn[(kg * 8 + 2 * jj + 1) * CH + 16 + col];
      ua1.u[jj] = pack2(wc, wd);
    }
  } else {
#pragma unroll
    for (int j = 0; j < 8; ++j) w4r[j] = Wn[kg * 8 + j];
  }
  float bias8[8];
#pragma unroll
  for (int j = 0; j < 8; ++j) bias8[j] = bias[kg * 8 + j];
  __syncthreads();

  const int* __restrict__ rows = csr_rows + (size_t)b * EE;
  const int base0 = chunk * 357;
  const int nend = base0 + 357;

#pragma unroll 1
  for (int p = 0; p < 3; ++p) {
    const int node = base0 + (p * 8 + wv) * 16 + col;
    const bool valid = node < nend;
    float zx[8];
#pragma unroll
    for (int j = 0; j < 8; ++j) zx[j] = 0.f;
    if (valid) {
      uint4 u = sy4[node * 4 + kg];
      zx[0] += bf_lo(u.x); zx[1] += bf_hi(u.x);
      zx[2] += bf_lo(u.y); zx[3] += bf_hi(u.y);
      zx[4] += bf_lo(u.z); zx[5] += bf_hi(u.z);
      zx[6] += bf_lo(u.w); zx[7] += bf_hi(u.w);
      const int o0 = s_off[node], o1 = s_off[node + 1];
      for (int k = o0; k < o1; ++k) {
        uint4 n = sy4[rows[k] * 4 + kg];
        zx[0] += bf_lo(n.x); zx[1] += bf_hi(n.x);
        zx[2] += bf_lo(n.y); zx[3] += bf_hi(n.y);
        zx[4] += bf_lo(n.z); zx[5] += bf_hi(n.z);
        zx[6] += bf_lo(n.w); zx[7] += bf_hi(n.w);
      }
    }
    const float dv = valid ? s_dv[node] : 0.f;
    float h[8];
#pragma unroll
    for (int j = 0; j < 8; ++j) {
      float t = fmaf(dv, zx[j], bias8[j]);
      float l = (t > 0.f) ? t : 0.01f * t;
      h[j] = (ACT == 0) ? l : (l + t);
    }
    if (OUTC == CH) {
      union { u32 u[4]; short8 v; } ub;
#pragma unroll
      for (int jj = 0; jj < 4; ++jj) ub.u[jj] = pack2(h[2 * jj], h[2 * jj + 1]);
      float4v z4 = {0.f, 0.f, 0.f, 0.f};
      float4v d0 = __builtin_amdgcn_mfma_f32_16x16x32_bf16(ua0.v, ub.v, z4, 0, 0, 0);
      float4v d1 = __builtin_amdgcn_mfma_f32_16x16x32_bf16(ua1.v, ub.v, z4, 0, 0, 0);
      if (valid) {
        u32* op = yout_b + ((size_t)b * NN + node) * 16;
        uint2 s0 = { pack2(d0[0] * dv, d0[1] * dv), pack2(d0[2] * dv, d0[3] * dv) };
        uint2 s1 = { pack2(d1[0] * dv, d1[1] * dv), pack2(d1[2] * dv, d1[3] * dv) };
        *(uint2*)(op + 2 * kg) = s0;
        *(uint2*)(op + 8 + 2 * kg) = s1;
      }
    } else {
      float part = 0.f;
#pragma unroll
      for (int j = 0; j < 8; ++j) part = fmaf(h[j], w4r[j], part);
      part += __shfl_xor(part, 16, 64);
      part += __shfl_xor(part, 32, 64);
      if (valid && kg == 0) yout_f[(size_t)b * NN + node] = part * dv;
    }
  }
}

// ---------------- Kernel F: 1-ch aggregate + lrelu, then FC1+relu, FC2+relu ----------------
__global__ __launch_bounds__(256) void k_tail(
    const float* __restrict__ y4, const float* __restrict__ dinv,
    const int* __restrict__ csr_off, const int* __restrict__ csr_rows,
    const float* __restrict__ b4, const float* __restrict__ Wf1,
    const float* __restrict__ bf1, const float* __restrict__ Wf2,
    const float* __restrict__ bf2, float* __restrict__ out)
{
  const int b = blockIdx.x, tid = threadIdx.x;
  __shared__ float s_y[NN];
  __shared__ float s_h[NN];
  __shared__ int s_off[NN + 1];
  __shared__ float s_red[256];
  __shared__ float s_u[128];
  for (int i = tid; i < NN; i += 256) s_y[i] = y4[(size_t)b * NN + i];
  for (int i = tid; i <= NN; i += 256) s_off[i] = csr_off[(size_t)b * (NN + 1) + i];
  __syncthreads();
  const int* __restrict__ rows = csr_rows + (size_t)b * EE;
  const float bb4 = b4[0];
  for (int i = tid; i < NN; i += 256) {
    float z = s_y[i];
    int o0 = s_off[i], o1 = s_off[i + 1];
    for (int k = o0; k < o1; ++k) z += s_y[rows[k]];
    float t = fmaf(dinv[(size_t)b * NN + i], z, bb4);
    s_h[i] = (t > 0.f) ? t : 0.01f * t;
  }
  __syncthreads();
  // FC1: 714 -> 128
  const int j = tid & 127, half = tid >> 7;
  float a = 0.f;
  const int n0 = half * 357, n1 = n0 + 357;
  for (int n = n0; n < n1; ++n) a = fmaf(s_h[n], Wf1[n * 128 + j], a);
  s_red[tid] = a;
  __syncthreads();
  if (tid < 128) {
    float v = s_red[tid] + s_red[tid + 128] + bf1[tid];
    s_u[tid] = fmaxf(v, 0.f);
  }
  __syncthreads();
  if (tid < 128) {
    float a2 = bf2[tid];
#pragma unroll 4
    for (int k = 0; k < 128; ++k) a2 = fmaf(s_u[k], Wf2[k * 128 + tid], a2);
    out[(size_t)b * 128 + tid] = fmaxf(a2, 0.f);
  }
}

extern "C" void kernel_launch(void* const* d_in, const int* in_sizes, int n_in,
                              void* d_out, int out_size, void* d_ws, size_t ws_size,
                              hipStream_t stream)
{
  (void)in_sizes; (void)n_in; (void)out_size; (void)ws_size;
  const int*   ids  = (const int*)d_in[0];
  const float* cont = (const float*)d_in[1];
  const int*   edges= (const int*)d_in[2];
  const float* emb  = (const float*)d_in[3];
  const float* W1   = (const float*)d_in[4];
  const float* b1   = (const float*)d_in[5];
  const float* W2   = (const float*)d_in[6];
  const float* b2   = (const float*)d_in[7];
  const float* W3   = (const float*)d_in[8];
  const float* b3   = (const float*)d_in[9];
  const float* W4   = (const float*)d_in[10];
  const float* b4   = (const float*)d_in[11];
  const float* Wf1  = (const float*)d_in[12];
  const float* bf1  = (const float*)d_in[13];
  const float* Wf2  = (const float*)d_in[14];
  const float* bf2  = (const float*)d_in[15];
  float* out = (float*)d_out;

  char* ws = (char*)d_ws;
  size_t off = 0;
  auto alloc = [&](size_t bytes) -> void* {
    void* p = ws + off;
    off = (off + bytes + 255) & ~(size_t)255;
    return p;
  };
  float* dinv     = (float*)alloc((size_t)BB * NN * 4);
  int*   csr_off  = (int*)  alloc((size_t)BB * (NN + 1) * 4);
  int*   csr_rows = (int*)  alloc((size_t)BB * EE * 4);
  u32*   yA       = (u32*)  alloc((size_t)BB * NN * 16 * 4);
  u32*   yB       = (u32*)  alloc((size_t)BB * NN * 16 * 4);
  float* y4       = (float*)alloc((size_t)BB * NN * 4);

  hipLaunchKernelGGL(k_prep, dim3(BB), dim3(256), 0, stream, edges, dinv, csr_off, csr_rows);
  hipLaunchKernelGGL(k_gcn1m, dim3(BB * 6), dim3(256), 0, stream,
                     ids, cont, emb, W1, dinv, yA);
  hipLaunchKernelGGL((k_layer2<0, 32>), dim3(BB * 2), dim3(512), 0, stream,
                     yA, dinv, csr_off, csr_rows, b1, W2, yB, (float*)nullptr);
  hipLaunchKernelGGL((k_layer2<1, 32>), dim3(BB * 2), dim3(512), 0, stream,
                     yB, dinv, csr_off, csr_rows, b2, W3, yA, (float*)nullptr);
  hipLaunchKernelGGL((k_layer2<1, 1>),  dim3(BB * 2), dim3(512), 0, stream,
                     yA, dinv, csr_off, csr_rows, b3, W4, (u32*)nullptr, y4);
  hipLaunchKernelGGL(k_tail, dim3(BB), dim3(256), 0, stream,
                     y4, dinv, csr_off, csr_rows, b4, Wf1, bf1, Wf2, bf2, out);
}

// Round 5
// 175.956 us; speedup vs baseline: 1.9934x; 1.0928x over previous
//
#include <hip/hip_runtime.h>
#include <hip/hip_bf16.h>

#define BB 512
#define NN 714
#define EE 4096
#define ED2 62
#define CH 32

typedef unsigned int u32;
typedef short short8 __attribute__((ext_vector_type(8)));
typedef float float4v __attribute__((ext_vector_type(4)));

__device__ __forceinline__ u32 f2bf(float f) {
  u32 u = __float_as_uint(f);
  return (u + 0x7fffu + ((u >> 16) & 1u)) >> 16;
}
__device__ __forceinline__ u32 pack2(float a, float b) {
  return f2bf(a) | (f2bf(b) << 16);
}
__device__ __forceinline__ float bf_lo(u32 u) { return __uint_as_float(u << 16); }
__device__ __forceinline__ float bf_hi(u32 u) { return __uint_as_float(u & 0xffff0000u); }

// ---------------- Kernel A: degree, dinv, CSR (sorted-by-col row list) ----------------
__global__ __launch_bounds__(256) void k_prep(const int* __restrict__ edges,
    float* __restrict__ dinv, int* __restrict__ csr_off, int* __restrict__ csr_rows)
{
  const int b = blockIdx.x;
  const int tid = threadIdx.x;
  const int* __restrict__ er = edges + (size_t)b * 2 * EE;       // e[0] = source (row)
  const int* __restrict__ ec = er + EE;                          // e[1] = target (col)
  __shared__ int s_cnt[NN];
  __shared__ int s_a[1024];
  __shared__ int s_b[1024];
  for (int i = tid; i < NN; i += 256) s_cnt[i] = 0;
  __syncthreads();
  for (int e = tid; e < EE; e += 256) atomicAdd(&s_cnt[ec[e]], 1);
  __syncthreads();
  for (int i = tid; i < 1024; i += 256) s_a[i] = (i < NN) ? s_cnt[i] : 0;
  for (int i = tid; i < NN; i += 256)
    dinv[(size_t)b * NN + i] = rsqrtf((float)(s_cnt[i] + 1));    // +1 self loop
  __syncthreads();
  int* src = s_a; int* dst = s_b;
  for (int d = 1; d < 1024; d <<= 1) {
    for (int i = tid; i < 1024; i += 256) {
      int v = src[i];
      if (i >= d) v += src[i - d];
      dst[i] = v;
    }
    __syncthreads();
    int* t = src; src = dst; dst = t;
  }
  // src = inclusive scan of counts
  int* og = csr_off + (size_t)b * (NN + 1);
  for (int i = tid; i <= NN; i += 256) og[i] = (i == 0) ? 0 : src[i - 1];
  for (int i = tid; i < NN; i += 256) s_cnt[i] = 0;  // reuse as fill cursors
  __syncthreads();
  int* rg = csr_rows + (size_t)b * EE;
  for (int e = tid; e < EE; e += 256) {
    int c = ec[e];
    int p = atomicAdd(&s_cnt[c], 1);
    int base = (c == 0) ? 0 : src[c - 1];
    rg[base + p] = er[e];
  }
}

// ---------------- Kernel B: cooperative-staged MFMA GCN1 ----------------
__global__ __launch_bounds__(256) void k_gcn1m(
    const int* __restrict__ ids, const float* __restrict__ cont,
    const float* __restrict__ emb, const float* __restrict__ W1,
    const float* __restrict__ dinv, u32* __restrict__ y1)
{
  const int bid = blockIdx.x;
  const int b = bid / 6, blk = bid - b * 6;
  const int base = blk * 128;
  const int nnodes = (NN - base < 128) ? (NN - base) : 128;
  const int nrows = nnodes * 2;
  const int tid = threadIdx.x, lane = tid & 63, wv = tid >> 6;
  const int col = lane & 15, kg = lane >> 4;

  __shared__ __align__(16) unsigned short sX[128 * 128];
  __shared__ float sC[128][4];
  __shared__ int s_ids[256];

  for (int t = tid; t < nnodes * 3; t += 256)
    sC[t / 3][t % 3] = cont[((size_t)b * NN + base) * 3 + t];
  s_ids[tid] = (tid < nrows) ? ids[((size_t)b * NN + base) * 2 + tid] : -1;
  __syncthreads();

  const int ck = tid & 7;           // 8-float chunk within row
  const int rbase = tid >> 3;       // 0..31
#pragma unroll
  for (int half = 0; half < 2; ++half) {
    float2 vv[4][4];
    int ids4[4];
#pragma unroll
    for (int q = 0; q < 4; ++q) ids4[q] = s_ids[(half * 4 + q) * 32 + rbase];
#pragma unroll
    for (int q = 0; q < 4; ++q) {
      const int id = ids4[q];
      if (id >= 0) {
        const float2* __restrict__ p = (const float2*)(emb + (size_t)id * ED2 + ck * 8);
        vv[q][0] = p[0]; vv[q][1] = p[1]; vv[q][2] = p[2];
        if (ck != 7) vv[q][3] = p[3];
        else { vv[q][3].x = 0.f; vv[q][3].y = 0.f; }
      } else {
        vv[q][0].x = vv[q][0].y = vv[q][1].x = vv[q][1].y = 0.f;
        vv[q][2].x = vv[q][2].y = vv[q][3].x = vv[q][3].y = 0.f;
      }
    }
#pragma unroll
    for (int q = 0; q < 4; ++q) {
      const int r = (half * 4 + q) * 32 + rbase;
      const int node = r >> 1, slot = r & 1;
      const int c16 = (node * 16 + slot * 8 + ck) ^ (node & 7);
      uint4 w = { pack2(vv[q][0].x, vv[q][0].y), pack2(vv[q][1].x, vv[q][1].y),
                  pack2(vv[q][2].x, vv[q][2].y), pack2(vv[q][3].x, vv[q][3].y) };
      ((uint4*)sX)[c16] = w;
    }
  }

  // hoist W1 MFMA fragments (bf16, remapped k) and cont-channel weights (f32)
  union { u32 u[4]; short8 v; } A[4][2];
#pragma unroll
  for (int kc = 0; kc < 4; ++kc)
#pragma unroll
    for (int hh = 0; hh < 2; ++hh)
#pragma unroll
      for (int jj = 0; jj < 4; ++jj) {
        const int k0 = kc * 32 + kg * 8 + 2 * jj;
        const int k1 = k0 + 1;
        const int m0 = (k0 < 62) ? k0 : ((k0 >= 64 && k0 < 126) ? k0 - 2 : -1);
        const int m1 = (k1 < 62) ? k1 : ((k1 >= 64 && k1 < 126) ? k1 - 2 : -1);
        const float wa = (m0 >= 0) ? W1[m0 * CH + hh * 16 + col] : 0.f;
        const float wb = (m1 >= 0) ? W1[m1 * CH + hh * 16 + col] : 0.f;
        A[kc][hh].u[jj] = pack2(wa, wb);
      }
  float Wc0[3][4], Wc1[3][4];
#pragma unroll
  for (int j = 0; j < 3; ++j)
#pragma unroll
    for (int reg = 0; reg < 4; ++reg) {
      Wc0[j][reg] = W1[(124 + j) * CH + 4 * kg + reg];
      Wc1[j][reg] = W1[(124 + j) * CH + 16 + 4 * kg + reg];
    }
  __syncthreads();

  const int ntiles = (nnodes + 15) >> 4;
  for (int t = wv; t < ntiles; t += 4) {
    const int ln = t * 16 + col;
    float4v a0 = {0.f, 0.f, 0.f, 0.f}, a1 = {0.f, 0.f, 0.f, 0.f};
#pragma unroll
    for (int kc = 0; kc < 4; ++kc) {
      const int idx16 = (ln * 16 + kc * 4 + kg) ^ (ln & 7);
      short8 bf = *(const short8*)(sX + idx16 * 8);
      a0 = __builtin_amdgcn_mfma_f32_16x16x32_bf16(A[kc][0].v, bf, a0, 0, 0, 0);
      a1 = __builtin_amdgcn_mfma_f32_16x16x32_bf16(A[kc][1].v, bf, a1, 0, 0, 0);
    }
#pragma unroll
    for (int j = 0; j < 3; ++j) {
      const float cv = sC[ln][j];
#pragma unroll
      for (int reg = 0; reg < 4; ++reg) {
        a0[reg] = fmaf(cv, Wc0[j][reg], a0[reg]);
        a1[reg] = fmaf(cv, Wc1[j][reg], a1[reg]);
      }
    }
    if (ln < nnodes) {
      const int gnode = base + ln;
      const float dv = dinv[(size_t)b * NN + gnode];
      u32* op = y1 + ((size_t)b * NN + gnode) * 16;
      uint2 s0 = { pack2(a0[0] * dv, a0[1] * dv), pack2(a0[2] * dv, a0[3] * dv) };
      uint2 s1 = { pack2(a1[0] * dv, a1[1] * dv), pack2(a1[2] * dv, a1[3] * dv) };
      *(uint2*)(op + 2 * kg) = s0;
      *(uint2*)(op + 8 + 2 * kg) = s1;
    }
  }
}

// ---------------- Kernels C/D/E: 4-lane/node aggregate + act + MFMA next matmul ----------------
template<int ACT, int OUTC>
__global__ __launch_bounds__(512, 6) void k_layer2(
    const u32* __restrict__ yin, const float* __restrict__ dinv,
    const int* __restrict__ csr_off, const int* __restrict__ csr_rows,
    const float* __restrict__ bias, const float* __restrict__ Wn,
    u32* __restrict__ yout_b, float* __restrict__ yout_f)
{
  const int bid = blockIdx.x;
  const int b = bid >> 1, chunk = bid & 1;
  const int tid = threadIdx.x;
  const int lane = tid & 63;
  const int wv = tid >> 6;          // wave 0..7
  const int col = lane & 15;        // node-in-tile
  const int kg = lane >> 4;         // channel group 0..3

  __shared__ u32 s_y[NN * 16];
  __shared__ float s_dv[NN];
  __shared__ int s_off[NN + 1];

  const uint4* __restrict__ ysrc = (const uint4*)(yin + (size_t)b * NN * 16);
  uint4* sy4 = (uint4*)s_y;
  for (int s = tid; s < NN * 4; s += 512) sy4[s] = ysrc[s];
  for (int i = tid; i < NN; i += 512) s_dv[i] = dinv[(size_t)b * NN + i];
  for (int i = tid; i <= NN; i += 512) s_off[i] = csr_off[(size_t)b * (NN + 1) + i];

  // hoist per-lane W fragments / bias (loop-invariant)
  union { u32 u[4]; short8 v; } ua0, ua1;
  float w4r[8];
  if (OUTC == CH) {
#pragma unroll
    for (int jj = 0; jj < 4; ++jj) {
      float wa = Wn[(kg * 8 + 2 * jj) * CH + col];
      float wb = Wn[(kg * 8 + 2 * jj + 1) * CH + col];
      ua0.u[jj] = pack2(wa, wb);
      float wc = Wn[(kg * 8 + 2 * jj) * CH + 16 + col];
      float wd = Wn[(kg * 8 + 2 * jj + 1) * CH + 16 + col];
      ua1.u[jj] = pack2(wc, wd);
    }
  } else {
#pragma unroll
    for (int j = 0; j < 8; ++j) w4r[j] = Wn[kg * 8 + j];
  }
  float bias8[8];
#pragma unroll
  for (int j = 0; j < 8; ++j) bias8[j] = bias[kg * 8 + j];
  __syncthreads();

  const int* __restrict__ rows = csr_rows + (size_t)b * EE;
  const int base0 = chunk * 357;
  const int nend = base0 + 357;

#pragma unroll 1
  for (int p = 0; p < 3; ++p) {
    const int node = base0 + (p * 8 + wv) * 16 + col;
    const bool valid = node < nend;
    float zx[8];
#pragma unroll
    for (int j = 0; j < 8; ++j) zx[j] = 0.f;
    if (valid) {
      uint4 u = sy4[node * 4 + kg];
      zx[0] += bf_lo(u.x); zx[1] += bf_hi(u.x);
      zx[2] += bf_lo(u.y); zx[3] += bf_hi(u.y);
      zx[4] += bf_lo(u.z); zx[5] += bf_hi(u.z);
      zx[6] += bf_lo(u.w); zx[7] += bf_hi(u.w);
      const int o0 = s_off[node], o1 = s_off[node + 1];
      for (int k = o0; k < o1; ++k) {
        uint4 n = sy4[rows[k] * 4 + kg];
        zx[0] += bf_lo(n.x); zx[1] += bf_hi(n.x);
        zx[2] += bf_lo(n.y); zx[3] += bf_hi(n.y);
        zx[4] += bf_lo(n.z); zx[5] += bf_hi(n.z);
        zx[6] += bf_lo(n.w); zx[7] += bf_hi(n.w);
      }
    }
    const float dv = valid ? s_dv[node] : 0.f;
    float h[8];
#pragma unroll
    for (int j = 0; j < 8; ++j) {
      float t = fmaf(dv, zx[j], bias8[j]);
      float l = (t > 0.f) ? t : 0.01f * t;
      h[j] = (ACT == 0) ? l : (l + t);
    }
    if (OUTC == CH) {
      union { u32 u[4]; short8 v; } ub;
#pragma unroll
      for (int jj = 0; jj < 4; ++jj) ub.u[jj] = pack2(h[2 * jj], h[2 * jj + 1]);
      float4v z4 = {0.f, 0.f, 0.f, 0.f};
      float4v d0 = __builtin_amdgcn_mfma_f32_16x16x32_bf16(ua0.v, ub.v, z4, 0, 0, 0);
      float4v d1 = __builtin_amdgcn_mfma_f32_16x16x32_bf16(ua1.v, ub.v, z4, 0, 0, 0);
      if (valid) {
        u32* op = yout_b + ((size_t)b * NN + node) * 16;
        uint2 s0 = { pack2(d0[0] * dv, d0[1] * dv), pack2(d0[2] * dv, d0[3] * dv) };
        uint2 s1 = { pack2(d1[0] * dv, d1[1] * dv), pack2(d1[2] * dv, d1[3] * dv) };
        *(uint2*)(op + 2 * kg) = s0;
        *(uint2*)(op + 8 + 2 * kg) = s1;
      }
    } else {
      float part = 0.f;
#pragma unroll
      for (int j = 0; j < 8; ++j) part = fmaf(h[j], w4r[j], part);
      part += __shfl_xor(part, 16, 64);
      part += __shfl_xor(part, 32, 64);
      if (valid && kg == 0) yout_f[(size_t)b * NN + node] = part * dv;
    }
  }
}

// ---------------- Kernel F: 1-ch aggregate + lrelu, then FC1+relu, FC2+relu ----------------
// 512 threads, 4-way split-K on both FC layers (latency fix: unroll + multi-acc).
__global__ __launch_bounds__(512) void k_tail(
    const float* __restrict__ y4, const float* __restrict__ dinv,
    const int* __restrict__ csr_off, const int* __restrict__ csr_rows,
    const float* __restrict__ b4, const float* __restrict__ Wf1,
    const float* __restrict__ bf1, const float* __restrict__ Wf2,
    const float* __restrict__ bf2, float* __restrict__ out)
{
  const int b = blockIdx.x, tid = threadIdx.x;
  __shared__ float s_y[NN];
  __shared__ float s_h[NN];
  __shared__ int s_off[NN + 1];
  __shared__ float s_red[512];
  __shared__ float s_u[128];
  for (int i = tid; i < NN; i += 512) s_y[i] = y4[(size_t)b * NN + i];
  for (int i = tid; i <= NN; i += 512) s_off[i] = csr_off[(size_t)b * (NN + 1) + i];
  __syncthreads();
  const int* __restrict__ rows = csr_rows + (size_t)b * EE;
  const float bb4 = b4[0];
  for (int i = tid; i < NN; i += 512) {
    float z = s_y[i];
    int o0 = s_off[i], o1 = s_off[i + 1];
    for (int k = o0; k < o1; ++k) z += s_y[rows[k]];
    float t = fmaf(dinv[(size_t)b * NN + i], z, bb4);
    s_h[i] = (t > 0.f) ? t : 0.01f * t;
  }
  __syncthreads();
  // FC1: 714 -> 128; thread (j = tid&127, q = tid>>7) covers n in [q*714/4,(q+1)*714/4)
  const int j = tid & 127, q = tid >> 7;
  {
    const int n0 = (q * NN) >> 2, n1 = ((q + 1) * NN) >> 2;
    const float* __restrict__ w = Wf1 + j;
    float a0 = 0.f, a1 = 0.f;
    int n = n0;
#pragma unroll 4
    for (; n + 2 <= n1; n += 2) {
      a0 = fmaf(s_h[n], w[(size_t)n * 128], a0);
      a1 = fmaf(s_h[n + 1], w[(size_t)(n + 1) * 128], a1);
    }
    if (n < n1) a0 = fmaf(s_h[n], w[(size_t)n * 128], a0);
    s_red[tid] = a0 + a1;
  }
  __syncthreads();
  if (tid < 128) {
    float v = s_red[tid] + s_red[tid + 128] + s_red[tid + 256] + s_red[tid + 384] + bf1[tid];
    s_u[tid] = fmaxf(v, 0.f);
  }
  __syncthreads();
  // FC2: 128 -> 128; thread (j, q) covers k in [q*32, q*32+32)
  {
    const float* __restrict__ w = Wf2 + j;
    float a0 = 0.f, a1 = 0.f;
#pragma unroll 8
    for (int k = q * 32; k < q * 32 + 32; k += 2) {
      a0 = fmaf(s_u[k], w[(size_t)k * 128], a0);
      a1 = fmaf(s_u[k + 1], w[(size_t)(k + 1) * 128], a1);
    }
    s_red[tid] = a0 + a1;
  }
  __syncthreads();
  if (tid < 128) {
    float v = s_red[tid] + s_red[tid + 128] + s_red[tid + 256] + s_red[tid + 384] + bf2[tid];
    out[(size_t)b * 128 + tid] = fmaxf(v, 0.f);
  }
}

extern "C" void kernel_launch(void* const* d_in, const int* in_sizes, int n_in,
                              void* d_out, int out_size, void* d_ws, size_t ws_size,
                              hipStream_t stream)
{
  (void)in_sizes; (void)n_in; (void)out_size; (void)ws_size;
  const int*   ids  = (const int*)d_in[0];
  const float* cont = (const float*)d_in[1];
  const int*   edges= (const int*)d_in[2];
  const float* emb  = (const float*)d_in[3];
  const float* W1   = (const float*)d_in[4];
  const float* b1   = (const float*)d_in[5];
  const float* W2   = (const float*)d_in[6];
  const float* b2   = (const float*)d_in[7];
  const float* W3   = (const float*)d_in[8];
  const float* b3   = (const float*)d_in[9];
  const float* W4   = (const float*)d_in[10];
  const float* b4   = (const float*)d_in[11];
  const float* Wf1  = (const float*)d_in[12];
  const float* bf1  = (const float*)d_in[13];
  const float* Wf2  = (const float*)d_in[14];
  const float* bf2  = (const float*)d_in[15];
  float* out = (float*)d_out;

  char* ws = (char*)d_ws;
  size_t off = 0;
  auto alloc = [&](size_t bytes) -> void* {
    void* p = ws + off;
    off = (off + bytes + 255) & ~(size_t)255;
    return p;
  };
  float* dinv     = (float*)alloc((size_t)BB * NN * 4);
  int*   csr_off  = (int*)  alloc((size_t)BB * (NN + 1) * 4);
  int*   csr_rows = (int*)  alloc((size_t)BB * EE * 4);
  u32*   yA       = (u32*)  alloc((size_t)BB * NN * 16 * 4);
  u32*   yB       = (u32*)  alloc((size_t)BB * NN * 16 * 4);
  float* y4       = (float*)alloc((size_t)BB * NN * 4);

  hipLaunchKernelGGL(k_prep, dim3(BB), dim3(256), 0, stream, edges, dinv, csr_off, csr_rows);
  hipLaunchKernelGGL(k_gcn1m, dim3(BB * 6), dim3(256), 0, stream,
                     ids, cont, emb, W1, dinv, yA);
  hipLaunchKernelGGL((k_layer2<0, 32>), dim3(BB * 2), dim3(512), 0, stream,
                     yA, dinv, csr_off, csr_rows, b1, W2, yB, (float*)nullptr);
  hipLaunchKernelGGL((k_layer2<1, 32>), dim3(BB * 2), dim3(512), 0, stream,
                     yB, dinv, csr_off, csr_rows, b2, W3, yA, (float*)nullptr);
  hipLaunchKernelGGL((k_layer2<1, 1>),  dim3(BB * 2), dim3(512), 0, stream,
                     yA, dinv, csr_off, csr_rows, b3, W4, (u32*)nullptr, y4);
  hipLaunchKernelGGL(k_tail, dim3(BB), dim3(512), 0, stream,
                     y4, dinv, csr_off, csr_rows, b4, Wf1, bf1, Wf2, bf2, out);
}

// Round 6
// 131.359 us; speedup vs baseline: 2.6702x; 1.3395x over previous
//
#include <hip/hip_runtime.h>
#include <hip/hip_bf16.h>

#define BB 512
#define NN 714
#define EE 4096
#define ED2 62
#define CH 32
#define NT16 45   // ceil(NN/16)

typedef unsigned int u32;
typedef unsigned short u16;
typedef short short8 __attribute__((ext_vector_type(8)));
typedef float float4v __attribute__((ext_vector_type(4)));

__device__ __forceinline__ u32 f2bf(float f) {
  u32 u = __float_as_uint(f);
  return (u + 0x7fffu + ((u >> 16) & 1u)) >> 16;
}
__device__ __forceinline__ u32 pack2(float a, float b) {
  return f2bf(a) | (f2bf(b) << 16);
}
__device__ __forceinline__ float bf_lo(u32 u) { return __uint_as_float(u << 16); }
__device__ __forceinline__ float bf_hi(u32 u) { return __uint_as_float(u & 0xffff0000u); }

// ---------------- Kernel A: degree, dinv, CSR (sorted-by-col row list) ----------------
__global__ __launch_bounds__(256) void k_prep(const int* __restrict__ edges,
    float* __restrict__ dinv, int* __restrict__ csr_off, int* __restrict__ csr_rows)
{
  const int b = blockIdx.x;
  const int tid = threadIdx.x;
  const int* __restrict__ er = edges + (size_t)b * 2 * EE;       // e[0] = source (row)
  const int* __restrict__ ec = er + EE;                          // e[1] = target (col)
  __shared__ int s_cnt[NN];
  __shared__ int s_a[1024];
  __shared__ int s_b[1024];
  for (int i = tid; i < NN; i += 256) s_cnt[i] = 0;
  __syncthreads();
  for (int e = tid; e < EE; e += 256) atomicAdd(&s_cnt[ec[e]], 1);
  __syncthreads();
  for (int i = tid; i < 1024; i += 256) s_a[i] = (i < NN) ? s_cnt[i] : 0;
  for (int i = tid; i < NN; i += 256)
    dinv[(size_t)b * NN + i] = rsqrtf((float)(s_cnt[i] + 1));    // +1 self loop
  __syncthreads();
  int* src = s_a; int* dst = s_b;
  for (int d = 1; d < 1024; d <<= 1) {
    for (int i = tid; i < 1024; i += 256) {
      int v = src[i];
      if (i >= d) v += src[i - d];
      dst[i] = v;
    }
    __syncthreads();
    int* t = src; src = dst; dst = t;
  }
  // src = inclusive scan of counts
  int* og = csr_off + (size_t)b * (NN + 1);
  for (int i = tid; i <= NN; i += 256) og[i] = (i == 0) ? 0 : src[i - 1];
  for (int i = tid; i < NN; i += 256) s_cnt[i] = 0;  // reuse as fill cursors
  __syncthreads();
  int* rg = csr_rows + (size_t)b * EE;
  for (int e = tid; e < EE; e += 256) {
    int c = ec[e];
    int p = atomicAdd(&s_cnt[c], 1);
    int base = (c == 0) ? 0 : src[c - 1];
    rg[base + p] = er[e];
  }
}

// ---------------- Kernel B: cooperative-staged MFMA GCN1 (unchanged) ----------------
__global__ __launch_bounds__(256) void k_gcn1m(
    const int* __restrict__ ids, const float* __restrict__ cont,
    const float* __restrict__ emb, const float* __restrict__ W1,
    const float* __restrict__ dinv, u32* __restrict__ y1)
{
  const int bid = blockIdx.x;
  const int b = bid / 6, blk = bid - b * 6;
  const int base = blk * 128;
  const int nnodes = (NN - base < 128) ? (NN - base) : 128;
  const int nrows = nnodes * 2;
  const int tid = threadIdx.x, lane = tid & 63, wv = tid >> 6;
  const int col = lane & 15, kg = lane >> 4;

  __shared__ __align__(16) unsigned short sX[128 * 128];
  __shared__ float sC[128][4];
  __shared__ int s_ids[256];

  for (int t = tid; t < nnodes * 3; t += 256)
    sC[t / 3][t % 3] = cont[((size_t)b * NN + base) * 3 + t];
  s_ids[tid] = (tid < nrows) ? ids[((size_t)b * NN + base) * 2 + tid] : -1;
  __syncthreads();

  const int ck = tid & 7;           // 8-float chunk within row
  const int rbase = tid >> 3;       // 0..31
#pragma unroll
  for (int half = 0; half < 2; ++half) {
    float2 vv[4][4];
    int ids4[4];
#pragma unroll
    for (int q = 0; q < 4; ++q) ids4[q] = s_ids[(half * 4 + q) * 32 + rbase];
#pragma unroll
    for (int q = 0; q < 4; ++q) {
      const int id = ids4[q];
      if (id >= 0) {
        const float2* __restrict__ p = (const float2*)(emb + (size_t)id * ED2 + ck * 8);
        vv[q][0] = p[0]; vv[q][1] = p[1]; vv[q][2] = p[2];
        if (ck != 7) vv[q][3] = p[3];
        else { vv[q][3].x = 0.f; vv[q][3].y = 0.f; }
      } else {
        vv[q][0].x = vv[q][0].y = vv[q][1].x = vv[q][1].y = 0.f;
        vv[q][2].x = vv[q][2].y = vv[q][3].x = vv[q][3].y = 0.f;
      }
    }
#pragma unroll
    for (int q = 0; q < 4; ++q) {
      const int r = (half * 4 + q) * 32 + rbase;
      const int node = r >> 1, slot = r & 1;
      const int c16 = (node * 16 + slot * 8 + ck) ^ (node & 7);
      uint4 w = { pack2(vv[q][0].x, vv[q][0].y), pack2(vv[q][1].x, vv[q][1].y),
                  pack2(vv[q][2].x, vv[q][2].y), pack2(vv[q][3].x, vv[q][3].y) };
      ((uint4*)sX)[c16] = w;
    }
  }

  union { u32 u[4]; short8 v; } A[4][2];
#pragma unroll
  for (int kc = 0; kc < 4; ++kc)
#pragma unroll
    for (int hh = 0; hh < 2; ++hh)
#pragma unroll
      for (int jj = 0; jj < 4; ++jj) {
        const int k0 = kc * 32 + kg * 8 + 2 * jj;
        const int k1 = k0 + 1;
        const int m0 = (k0 < 62) ? k0 : ((k0 >= 64 && k0 < 126) ? k0 - 2 : -1);
        const int m1 = (k1 < 62) ? k1 : ((k1 >= 64 && k1 < 126) ? k1 - 2 : -1);
        const float wa = (m0 >= 0) ? W1[m0 * CH + hh * 16 + col] : 0.f;
        const float wb = (m1 >= 0) ? W1[m1 * CH + hh * 16 + col] : 0.f;
        A[kc][hh].u[jj] = pack2(wa, wb);
      }
  float Wc0[3][4], Wc1[3][4];
#pragma unroll
  for (int j = 0; j < 3; ++j)
#pragma unroll
    for (int reg = 0; reg < 4; ++reg) {
      Wc0[j][reg] = W1[(124 + j) * CH + 4 * kg + reg];
      Wc1[j][reg] = W1[(124 + j) * CH + 16 + 4 * kg + reg];
    }
  __syncthreads();

  const int ntiles = (nnodes + 15) >> 4;
  for (int t = wv; t < ntiles; t += 4) {
    const int ln = t * 16 + col;
    float4v a0 = {0.f, 0.f, 0.f, 0.f}, a1 = {0.f, 0.f, 0.f, 0.f};
#pragma unroll
    for (int kc = 0; kc < 4; ++kc) {
      const int idx16 = (ln * 16 + kc * 4 + kg) ^ (ln & 7);
      short8 bf = *(const short8*)(sX + idx16 * 8);
      a0 = __builtin_amdgcn_mfma_f32_16x16x32_bf16(A[kc][0].v, bf, a0, 0, 0, 0);
      a1 = __builtin_amdgcn_mfma_f32_16x16x32_bf16(A[kc][1].v, bf, a1, 0, 0, 0);
    }
#pragma unroll
    for (int j = 0; j < 3; ++j) {
      const float cv = sC[ln][j];
#pragma unroll
      for (int reg = 0; reg < 4; ++reg) {
        a0[reg] = fmaf(cv, Wc0[j][reg], a0[reg]);
        a1[reg] = fmaf(cv, Wc1[j][reg], a1[reg]);
      }
    }
    if (ln < nnodes) {
      const int gnode = base + ln;
      const float dv = dinv[(size_t)b * NN + gnode];
      u32* op = y1 + ((size_t)b * NN + gnode) * 16;
      uint2 s0 = { pack2(a0[0] * dv, a0[1] * dv), pack2(a0[2] * dv, a0[3] * dv) };
      uint2 s1 = { pack2(a1[0] * dv, a1[1] * dv), pack2(a1[2] * dv, a1[3] * dv) };
      *(uint2*)(op + 2 * kg) = s0;
      *(uint2*)(op + 8 + 2 * kg) = s1;
    }
  }
}

// ---------------- Fused kernel: layers 2,3,4 + tail (one block per batch) ----------------
// LDS budget (61544 B): y 45696 | rows(u16) 8192 | off(u16) 1432 | dinv 2856 | h 2856 | u 512
// In-place layer update via register double-buffer (read all -> barrier -> write -> barrier).
template<int ACT>
__device__ __forceinline__ void gcn_pass32(
    u32* __restrict__ sy, const u16* __restrict__ s_rows,
    const u16* __restrict__ s_off, const float* __restrict__ s_dv,
    const int wv, const int col, const int kg,
    const short8 a0v, const short8 a1v, const float* __restrict__ bias8)
{
  const uint4* sy4 = (const uint4*)sy;
  u32 outs[3][4];
#pragma unroll
  for (int p = 0; p < 3; ++p) {
    const int t = p * 16 + wv;
    const int node = t * 16 + col;
    const bool valid = (t < NT16) && (node < NN);
    float zx[8];
#pragma unroll
    for (int j = 0; j < 8; ++j) zx[j] = 0.f;
    if (valid) {
      uint4 u = sy4[node * 4 + kg];
      zx[0] += bf_lo(u.x); zx[1] += bf_hi(u.x);
      zx[2] += bf_lo(u.y); zx[3] += bf_hi(u.y);
      zx[4] += bf_lo(u.z); zx[5] += bf_hi(u.z);
      zx[6] += bf_lo(u.w); zx[7] += bf_hi(u.w);
      const int o0 = s_off[node], o1 = s_off[node + 1];
      for (int k = o0; k < o1; ++k) {
        uint4 n = sy4[(int)s_rows[k] * 4 + kg];
        zx[0] += bf_lo(n.x); zx[1] += bf_hi(n.x);
        zx[2] += bf_lo(n.y); zx[3] += bf_hi(n.y);
        zx[4] += bf_lo(n.z); zx[5] += bf_hi(n.z);
        zx[6] += bf_lo(n.w); zx[7] += bf_hi(n.w);
      }
    }
    const float dv = valid ? s_dv[node] : 0.f;
    float h[8];
#pragma unroll
    for (int j = 0; j < 8; ++j) {
      float t2 = fmaf(dv, zx[j], bias8[j]);
      float l = (t2 > 0.f) ? t2 : 0.01f * t2;
      h[j] = (ACT == 0) ? l : (l + t2);
    }
    union { u32 u[4]; short8 v; } ub;
#pragma unroll
    for (int jj = 0; jj < 4; ++jj) ub.u[jj] = pack2(h[2 * jj], h[2 * jj + 1]);
    float4v z4 = {0.f, 0.f, 0.f, 0.f};
    float4v d0 = __builtin_amdgcn_mfma_f32_16x16x32_bf16(a0v, ub.v, z4, 0, 0, 0);
    float4v d1 = __builtin_amdgcn_mfma_f32_16x16x32_bf16(a1v, ub.v, z4, 0, 0, 0);
    outs[p][0] = pack2(d0[0] * dv, d0[1] * dv);
    outs[p][1] = pack2(d0[2] * dv, d0[3] * dv);
    outs[p][2] = pack2(d1[0] * dv, d1[1] * dv);
    outs[p][3] = pack2(d1[2] * dv, d1[3] * dv);
  }
  __syncthreads();
#pragma unroll
  for (int p = 0; p < 3; ++p) {
    const int t = p * 16 + wv;
    const int node = t * 16 + col;
    if (t < NT16 && node < NN) {
      u32* op = sy + node * 16;
      uint2 s0 = { outs[p][0], outs[p][1] };
      uint2 s1 = { outs[p][2], outs[p][3] };
      *(uint2*)(op + 2 * kg) = s0;
      *(uint2*)(op + 8 + 2 * kg) = s1;
    }
  }
  __syncthreads();
}

__global__ __launch_bounds__(1024) void k_fused(
    const u32* __restrict__ yin, const float* __restrict__ dinv,
    const int* __restrict__ csr_off, const int* __restrict__ csr_rows,
    const float* __restrict__ b1, const float* __restrict__ W2,
    const float* __restrict__ b2, const float* __restrict__ W3,
    const float* __restrict__ b3, const float* __restrict__ W4,
    const float* __restrict__ b4, const float* __restrict__ Wf1,
    const float* __restrict__ bf1, const float* __restrict__ Wf2,
    const float* __restrict__ bf2, float* __restrict__ out)
{
  const int b = blockIdx.x;
  const int tid = threadIdx.x;
  const int lane = tid & 63;
  const int wv = tid >> 6;          // wave 0..15
  const int col = lane & 15;        // node-in-tile
  const int kg = lane >> 4;         // channel group 0..3

  __shared__ __align__(16) char smem[61552];
  u32*   s_y    = (u32*)smem;                     // 45696 B (dead after pass C; reused as s_red)
  u16*   s_rows = (u16*)(smem + 45696);           // 8192
  u16*   s_off  = (u16*)(smem + 53888);           // 1432
  float* s_dv   = (float*)(smem + 55320);         // 2856
  float* s_h    = (float*)(smem + 58176);         // 2856
  float* s_u    = (float*)(smem + 61032);         // 512
  float* s_red  = (float*)smem;                   // 4096 (aliases dead s_y)

  {
    const uint4* __restrict__ ysrc = (const uint4*)(yin + (size_t)b * NN * 16);
    uint4* sy4w = (uint4*)s_y;
    for (int s = tid; s < NN * 4; s += 1024) sy4w[s] = ysrc[s];
    for (int e = tid; e < EE; e += 1024) s_rows[e] = (u16)csr_rows[(size_t)b * EE + e];
    for (int i = tid; i <= NN; i += 1024) s_off[i] = (u16)csr_off[(size_t)b * (NN + 1) + i];
    for (int i = tid; i < NN; i += 1024) s_dv[i] = dinv[(size_t)b * NN + i];
  }

  // hoist per-lane weight fragments / biases
  union { u32 u[4]; short8 v; } uaA0, uaA1, uaB0, uaB1;
#pragma unroll
  for (int jj = 0; jj < 4; ++jj) {
    uaA0.u[jj] = pack2(W2[(kg * 8 + 2 * jj) * CH + col],      W2[(kg * 8 + 2 * jj + 1) * CH + col]);
    uaA1.u[jj] = pack2(W2[(kg * 8 + 2 * jj) * CH + 16 + col], W2[(kg * 8 + 2 * jj + 1) * CH + 16 + col]);
    uaB0.u[jj] = pack2(W3[(kg * 8 + 2 * jj) * CH + col],      W3[(kg * 8 + 2 * jj + 1) * CH + col]);
    uaB1.u[jj] = pack2(W3[(kg * 8 + 2 * jj) * CH + 16 + col], W3[(kg * 8 + 2 * jj + 1) * CH + 16 + col]);
  }
  float b1r[8], b2r[8], b3r[8], w4r[8];
#pragma unroll
  for (int j = 0; j < 8; ++j) {
    b1r[j] = b1[kg * 8 + j];
    b2r[j] = b2[kg * 8 + j];
    b3r[j] = b3[kg * 8 + j];
    w4r[j] = W4[kg * 8 + j];
  }
  const float bb4 = b4[0];
  __syncthreads();

  // layer 2: agg(y1) + b1, lrelu, @W2, *dinv  (in-place into s_y)
  gcn_pass32<0>(s_y, s_rows, s_off, s_dv, wv, col, kg, uaA0.v, uaA1.v, b1r);
  // layer 3: agg + b2, lrelu+t, @W3, *dinv
  gcn_pass32<1>(s_y, s_rows, s_off, s_dv, wv, col, kg, uaB0.v, uaB1.v, b2r);

  // layer 4: agg + b3, lrelu+t, dot W4 (32->1), *dinv -> s_h
  {
    const uint4* sy4 = (const uint4*)s_y;
#pragma unroll
    for (int p = 0; p < 3; ++p) {
      const int t = p * 16 + wv;
      const int node = t * 16 + col;
      const bool valid = (t < NT16) && (node < NN);
      float zx[8];
#pragma unroll
      for (int j = 0; j < 8; ++j) zx[j] = 0.f;
      if (valid) {
        uint4 u = sy4[node * 4 + kg];
        zx[0] += bf_lo(u.x); zx[1] += bf_hi(u.x);
        zx[2] += bf_lo(u.y); zx[3] += bf_hi(u.y);
        zx[4] += bf_lo(u.z); zx[5] += bf_hi(u.z);
        zx[6] += bf_lo(u.w); zx[7] += bf_hi(u.w);
        const int o0 = s_off[node], o1 = s_off[node + 1];
        for (int k = o0; k < o1; ++k) {
          uint4 n = sy4[(int)s_rows[k] * 4 + kg];
          zx[0] += bf_lo(n.x); zx[1] += bf_hi(n.x);
          zx[2] += bf_lo(n.y); zx[3] += bf_hi(n.y);
          zx[4] += bf_lo(n.z); zx[5] += bf_hi(n.z);
          zx[6] += bf_lo(n.w); zx[7] += bf_hi(n.w);
        }
      }
      const float dv = valid ? s_dv[node] : 0.f;
      float part = 0.f;
#pragma unroll
      for (int j = 0; j < 8; ++j) {
        float t2 = fmaf(dv, zx[j], b3r[j]);
        float l = (t2 > 0.f) ? t2 : 0.01f * t2;
        part = fmaf(l + t2, w4r[j], part);
      }
      part += __shfl_xor(part, 16, 64);
      part += __shfl_xor(part, 32, 64);
      if (valid && kg == 0) s_h[node] = part * dv;
    }
  }
  __syncthreads();

  // tail aggregation: z = h + sum(h[rows]); lrelu(dinv*z + b4)
  {
    float hval = 0.f;
    const bool v = tid < NN;
    if (v) {
      float z = s_h[tid];
      const int o0 = s_off[tid], o1 = s_off[tid + 1];
      for (int k = o0; k < o1; ++k) z += s_h[(int)s_rows[k]];
      float t2 = fmaf(s_dv[tid], z, bb4);
      hval = (t2 > 0.f) ? t2 : 0.01f * t2;
    }
    __syncthreads();
    if (v) s_h[tid] = hval;
  }
  __syncthreads();

  // FC1: 714 -> 128, 8-way split-K
  const int j = tid & 127, q = tid >> 7;
  {
    const int n0 = (q * NN) >> 3, n1 = ((q + 1) * NN) >> 3;
    const float* __restrict__ w = Wf1 + j;
    float a0 = 0.f, a1 = 0.f;
    int n = n0;
#pragma unroll 4
    for (; n + 2 <= n1; n += 2) {
      a0 = fmaf(s_h[n], w[(size_t)n * 128], a0);
      a1 = fmaf(s_h[n + 1], w[(size_t)(n + 1) * 128], a1);
    }
    if (n < n1) a0 = fmaf(s_h[n], w[(size_t)n * 128], a0);
    s_red[tid] = a0 + a1;
  }
  __syncthreads();
  if (tid < 128) {
    float v = bf1[tid];
#pragma unroll
    for (int m = 0; m < 8; ++m) v += s_red[tid + 128 * m];
    s_u[tid] = fmaxf(v, 0.f);
  }
  __syncthreads();
  // FC2: 128 -> 128, 8-way split-K (16 k's each)
  {
    const float* __restrict__ w = Wf2 + j;
    float a0 = 0.f, a1 = 0.f;
#pragma unroll
    for (int k = q * 16; k < q * 16 + 16; k += 2) {
      a0 = fmaf(s_u[k], w[(size_t)k * 128], a0);
      a1 = fmaf(s_u[k + 1], w[(size_t)(k + 1) * 128], a1);
    }
    s_red[tid] = a0 + a1;
  }
  __syncthreads();
  if (tid < 128) {
    float v = bf2[tid];
#pragma unroll
    for (int m = 0; m < 8; ++m) v += s_red[tid + 128 * m];
    out[(size_t)b * 128 + tid] = fmaxf(v, 0.f);
  }
}

extern "C" void kernel_launch(void* const* d_in, const int* in_sizes, int n_in,
                              void* d_out, int out_size, void* d_ws, size_t ws_size,
                              hipStream_t stream)
{
  (void)in_sizes; (void)n_in; (void)out_size; (void)ws_size;
  const int*   ids  = (const int*)d_in[0];
  const float* cont = (const float*)d_in[1];
  const int*   edges= (const int*)d_in[2];
  const float* emb  = (const float*)d_in[3];
  const float* W1   = (const float*)d_in[4];
  const float* b1   = (const float*)d_in[5];
  const float* W2   = (const float*)d_in[6];
  const float* b2   = (const float*)d_in[7];
  const float* W3   = (const float*)d_in[8];
  const float* b3   = (const float*)d_in[9];
  const float* W4   = (const float*)d_in[10];
  const float* b4   = (const float*)d_in[11];
  const float* Wf1  = (const float*)d_in[12];
  const float* bf1  = (const float*)d_in[13];
  const float* Wf2  = (const float*)d_in[14];
  const float* bf2  = (const float*)d_in[15];
  float* out = (float*)d_out;

  char* ws = (char*)d_ws;
  size_t off = 0;
  auto alloc = [&](size_t bytes) -> void* {
    void* p = ws + off;
    off = (off + bytes + 255) & ~(size_t)255;
    return p;
  };
  float* dinv     = (float*)alloc((size_t)BB * NN * 4);
  int*   csr_off  = (int*)  alloc((size_t)BB * (NN + 1) * 4);
  int*   csr_rows = (int*)  alloc((size_t)BB * EE * 4);
  u32*   yA       = (u32*)  alloc((size_t)BB * NN * 16 * 4);

  hipLaunchKernelGGL(k_prep, dim3(BB), dim3(256), 0, stream, edges, dinv, csr_off, csr_rows);
  hipLaunchKernelGGL(k_gcn1m, dim3(BB * 6), dim3(256), 0, stream,
                     ids, cont, emb, W1, dinv, yA);
  hipLaunchKernelGGL(k_fused, dim3(BB), dim3(1024), 0, stream,
                     yA, dinv, csr_off, csr_rows,
                     b1, W2, b2, W3, b3, W4, b4, Wf1, bf1, Wf2, bf2, out);
}

// Round 7
// 122.891 us; speedup vs baseline: 2.8542x; 1.0689x over previous
//
#include <hip/hip_runtime.h>
#include <hip/hip_bf16.h>

#define BB 512
#define NN 714
#define EE 4096
#define ED2 62
#define CH 32
#define NT16 45   // ceil(NN/16)
#define VOCAB 38733

typedef unsigned int u32;
typedef unsigned short u16;
typedef short short8 __attribute__((ext_vector_type(8)));
typedef float float4v __attribute__((ext_vector_type(4)));

__device__ __forceinline__ u32 f2bf(float f) {
  u32 u = __float_as_uint(f);
  return (u + 0x7fffu + ((u >> 16) & 1u)) >> 16;
}
__device__ __forceinline__ u32 pack2(float a, float b) {
  return f2bf(a) | (f2bf(b) << 16);
}
__device__ __forceinline__ float bf_lo(u32 u) { return __uint_as_float(u << 16); }
__device__ __forceinline__ float bf_hi(u32 u) { return __uint_as_float(u & 0xffff0000u); }

// y-in-LDS swizzle: uint4 slot q of node -> q ^ ((node>>1)&3).
// 16 consecutive nodes then span 8 distinct bank-groups (2 lanes each = conflict-free).
__device__ __forceinline__ int yslot(int node, int q) {
  return (node << 2) | (q ^ ((node >> 1) & 3));
}

// ---------------- Kernel 0: f32 emb table -> bf16 [VOCAB][64] zero-padded ----------------
__global__ __launch_bounds__(256) void k_conv(const float* __restrict__ emb,
                                              uint2* __restrict__ embh)
{
  const int t = blockIdx.x * 256 + threadIdx.x;      // one thread = 4 cols of one row
  if (t >= VOCAB * 16) return;
  const int row = t >> 4, c = (t & 15) * 4;
  const float* __restrict__ p = emb + (size_t)row * ED2;
  float v0 = (c + 0 < ED2) ? p[c + 0] : 0.f;
  float v1 = (c + 1 < ED2) ? p[c + 1] : 0.f;
  float v2 = (c + 2 < ED2) ? p[c + 2] : 0.f;
  float v3 = (c + 3 < ED2) ? p[c + 3] : 0.f;
  uint2 o = { pack2(v0, v1), pack2(v2, v3) };
  embh[t] = o;
}

// ---------------- Kernel A: degree, dinv, CSR (sorted-by-col row list) ----------------
__global__ __launch_bounds__(256) void k_prep(const int* __restrict__ edges,
    float* __restrict__ dinv, int* __restrict__ csr_off, int* __restrict__ csr_rows)
{
  const int b = blockIdx.x;
  const int tid = threadIdx.x;
  const int* __restrict__ er = edges + (size_t)b * 2 * EE;       // e[0] = source (row)
  const int* __restrict__ ec = er + EE;                          // e[1] = target (col)
  __shared__ int s_cnt[NN];
  __shared__ int s_a[1024];
  __shared__ int s_b[1024];
  for (int i = tid; i < NN; i += 256) s_cnt[i] = 0;
  __syncthreads();
  for (int e = tid; e < EE; e += 256) atomicAdd(&s_cnt[ec[e]], 1);
  __syncthreads();
  for (int i = tid; i < 1024; i += 256) s_a[i] = (i < NN) ? s_cnt[i] : 0;
  for (int i = tid; i < NN; i += 256)
    dinv[(size_t)b * NN + i] = rsqrtf((float)(s_cnt[i] + 1));    // +1 self loop
  __syncthreads();
  int* src = s_a; int* dst = s_b;
  for (int d = 1; d < 1024; d <<= 1) {
    for (int i = tid; i < 1024; i += 256) {
      int v = src[i];
      if (i >= d) v += src[i - d];
      dst[i] = v;
    }
    __syncthreads();
    int* t = src; src = dst; dst = t;
  }
  int* og = csr_off + (size_t)b * (NN + 1);
  for (int i = tid; i <= NN; i += 256) og[i] = (i == 0) ? 0 : src[i - 1];
  for (int i = tid; i < NN; i += 256) s_cnt[i] = 0;  // reuse as fill cursors
  __syncthreads();
  int* rg = csr_rows + (size_t)b * EE;
  for (int e = tid; e < EE; e += 256) {
    int c = ec[e];
    int p = atomicAdd(&s_cnt[c], 1);
    int base = (c == 0) ? 0 : src[c - 1];
    rg[base + p] = er[e];
  }
}

// ---------------- Kernel B: MFMA GCN1, bf16-table gather (1 aligned uint4/row-chunk) ----------------
__global__ __launch_bounds__(256) void k_gcn1m(
    const int* __restrict__ ids, const float* __restrict__ cont,
    const uint4* __restrict__ embh, const float* __restrict__ W1,
    const float* __restrict__ dinv, u32* __restrict__ y1)
{
  const int bid = blockIdx.x;
  const int b = bid / 6, blk = bid - b * 6;
  const int base = blk * 128;
  const int nnodes = (NN - base < 128) ? (NN - base) : 128;
  const int nrows = nnodes * 2;
  const int tid = threadIdx.x, lane = tid & 63, wv = tid >> 6;
  const int col = lane & 15, kg = lane >> 4;

  __shared__ __align__(16) unsigned short sX[128 * 128];
  __shared__ float sC[128][4];
  __shared__ int s_ids[256];

  for (int t = tid; t < nnodes * 3; t += 256)
    sC[t / 3][t % 3] = cont[((size_t)b * NN + base) * 3 + t];
  s_ids[tid] = (tid < nrows) ? ids[((size_t)b * NN + base) * 2 + tid] : -1;
  __syncthreads();

  // staging: thread (rbase, ck) handles chunk ck (16B = 8 bf16) of rows q*32+rbase, q=0..7
  const int ck = tid & 7;           // chunk within row
  const int rbase = tid >> 3;       // 0..31
  {
    uint4 w4[8];
#pragma unroll
    for (int q = 0; q < 8; ++q) {
      const int id = s_ids[q * 32 + rbase];
      if (id >= 0) w4[q] = embh[(size_t)id * 8 + ck];
      else { w4[q].x = 0; w4[q].y = 0; w4[q].z = 0; w4[q].w = 0; }
    }
#pragma unroll
    for (int q = 0; q < 8; ++q) {
      const int r = q * 32 + rbase;
      const int node = r >> 1, slot = r & 1;
      const int c16 = (node * 16 + slot * 8 + ck) ^ (node & 7);
      ((uint4*)sX)[c16] = w4[q];
    }
  }

  // W1 MFMA fragments (bf16, remapped k: <62->k; 62,63->0; 64..125->k-2; 126,127->0)
  union { u32 u[4]; short8 v; } A[4][2];
#pragma unroll
  for (int kc = 0; kc < 4; ++kc)
#pragma unroll
    for (int hh = 0; hh < 2; ++hh)
#pragma unroll
      for (int jj = 0; jj < 4; ++jj) {
        const int k0 = kc * 32 + kg * 8 + 2 * jj;
        const int k1 = k0 + 1;
        const int m0 = (k0 < 62) ? k0 : ((k0 >= 64 && k0 < 126) ? k0 - 2 : -1);
        const int m1 = (k1 < 62) ? k1 : ((k1 >= 64 && k1 < 126) ? k1 - 2 : -1);
        const float wa = (m0 >= 0) ? W1[m0 * CH + hh * 16 + col] : 0.f;
        const float wb = (m1 >= 0) ? W1[m1 * CH + hh * 16 + col] : 0.f;
        A[kc][hh].u[jj] = pack2(wa, wb);
      }
  float Wc0[3][4], Wc1[3][4];
#pragma unroll
  for (int j = 0; j < 3; ++j)
#pragma unroll
    for (int reg = 0; reg < 4; ++reg) {
      Wc0[j][reg] = W1[(124 + j) * CH + 4 * kg + reg];
      Wc1[j][reg] = W1[(124 + j) * CH + 16 + 4 * kg + reg];
    }
  __syncthreads();

  const int ntiles = (nnodes + 15) >> 4;
  for (int t = wv; t < ntiles; t += 4) {
    const int ln = t * 16 + col;
    float4v a0 = {0.f, 0.f, 0.f, 0.f}, a1 = {0.f, 0.f, 0.f, 0.f};
#pragma unroll
    for (int kc = 0; kc < 4; ++kc) {
      const int idx16 = (ln * 16 + kc * 4 + kg) ^ (ln & 7);
      short8 bf = *(const short8*)(sX + idx16 * 8);
      a0 = __builtin_amdgcn_mfma_f32_16x16x32_bf16(A[kc][0].v, bf, a0, 0, 0, 0);
      a1 = __builtin_amdgcn_mfma_f32_16x16x32_bf16(A[kc][1].v, bf, a1, 0, 0, 0);
    }
#pragma unroll
    for (int j = 0; j < 3; ++j) {
      const float cv = sC[ln][j];
#pragma unroll
      for (int reg = 0; reg < 4; ++reg) {
        a0[reg] = fmaf(cv, Wc0[j][reg], a0[reg]);
        a1[reg] = fmaf(cv, Wc1[j][reg], a1[reg]);
      }
    }
    if (ln < nnodes) {
      const int gnode = base + ln;
      const float dv = dinv[(size_t)b * NN + gnode];
      u32* op = y1 + ((size_t)b * NN + gnode) * 16;
      uint2 s0 = { pack2(a0[0] * dv, a0[1] * dv), pack2(a0[2] * dv, a0[3] * dv) };
      uint2 s1 = { pack2(a1[0] * dv, a1[1] * dv), pack2(a1[2] * dv, a1[3] * dv) };
      *(uint2*)(op + 2 * kg) = s0;
      *(uint2*)(op + 8 + 2 * kg) = s1;
    }
  }
}

// ---------------- Fused kernel: layers 2,3,4 + tail (one block per batch) ----------------
template<int ACT>
__device__ __forceinline__ void gcn_pass32(
    u32* __restrict__ sy, const u16* __restrict__ s_rows,
    const u16* __restrict__ s_off, const float* __restrict__ s_dv,
    const int wv, const int col, const int kg,
    const short8 a0v, const short8 a1v, const float* __restrict__ bias8)
{
  const uint4* sy4 = (const uint4*)sy;
  u32 outs[3][4];
#pragma unroll
  for (int p = 0; p < 3; ++p) {
    const int t = p * 16 + wv;
    const int node = t * 16 + col;
    const bool valid = (t < NT16) && (node < NN);
    float zx[8];
#pragma unroll
    for (int j = 0; j < 8; ++j) zx[j] = 0.f;
    if (valid) {
      uint4 u = sy4[yslot(node, kg)];
      zx[0] += bf_lo(u.x); zx[1] += bf_hi(u.x);
      zx[2] += bf_lo(u.y); zx[3] += bf_hi(u.y);
      zx[4] += bf_lo(u.z); zx[5] += bf_hi(u.z);
      zx[6] += bf_lo(u.w); zx[7] += bf_hi(u.w);
      const int o0 = s_off[node], o1 = s_off[node + 1];
      for (int k = o0; k < o1; ++k) {
        const int r = (int)s_rows[k];
        uint4 n = sy4[yslot(r, kg)];
        zx[0] += bf_lo(n.x); zx[1] += bf_hi(n.x);
        zx[2] += bf_lo(n.y); zx[3] += bf_hi(n.y);
        zx[4] += bf_lo(n.z); zx[5] += bf_hi(n.z);
        zx[6] += bf_lo(n.w); zx[7] += bf_hi(n.w);
      }
    }
    const float dv = valid ? s_dv[node] : 0.f;
    float h[8];
#pragma unroll
    for (int j = 0; j < 8; ++j) {
      float t2 = fmaf(dv, zx[j], bias8[j]);
      float l = (t2 > 0.f) ? t2 : 0.01f * t2;
      h[j] = (ACT == 0) ? l : (l + t2);
    }
    union { u32 u[4]; short8 v; } ub;
#pragma unroll
    for (int jj = 0; jj < 4; ++jj) ub.u[jj] = pack2(h[2 * jj], h[2 * jj + 1]);
    float4v z4 = {0.f, 0.f, 0.f, 0.f};
    float4v d0 = __builtin_amdgcn_mfma_f32_16x16x32_bf16(a0v, ub.v, z4, 0, 0, 0);
    float4v d1 = __builtin_amdgcn_mfma_f32_16x16x32_bf16(a1v, ub.v, z4, 0, 0, 0);
    outs[p][0] = pack2(d0[0] * dv, d0[1] * dv);
    outs[p][1] = pack2(d0[2] * dv, d0[3] * dv);
    outs[p][2] = pack2(d1[0] * dv, d1[1] * dv);
    outs[p][3] = pack2(d1[2] * dv, d1[3] * dv);
  }
  __syncthreads();
#pragma unroll
  for (int p = 0; p < 3; ++p) {
    const int t = p * 16 + wv;
    const int node = t * 16 + col;
    if (t < NT16 && node < NN) {
      const int sw = (node >> 1) & 3;
      u32* op = sy + node * 16;
      uint2 s0 = { outs[p][0], outs[p][1] };
      uint2 s1 = { outs[p][2], outs[p][3] };
      // d0 -> linear slot kg>>1, d1 -> slot 2+(kg>>1); within-slot offset (2*kg)&3
      *(uint2*)(op + (((kg >> 1) ^ sw) << 2) + ((2 * kg) & 3)) = s0;
      *(uint2*)(op + (((2 + (kg >> 1)) ^ sw) << 2) + ((2 * kg) & 3)) = s1;
    }
  }
  __syncthreads();
}

__global__ __launch_bounds__(1024) void k_fused(
    const u32* __restrict__ yin, const float* __restrict__ dinv,
    const int* __restrict__ csr_off, const int* __restrict__ csr_rows,
    const float* __restrict__ b1, const float* __restrict__ W2,
    const float* __restrict__ b2, const float* __restrict__ W3,
    const float* __restrict__ b3, const float* __restrict__ W4,
    const float* __restrict__ b4, const float* __restrict__ Wf1,
    const float* __restrict__ bf1, const float* __restrict__ Wf2,
    const float* __restrict__ bf2, float* __restrict__ out)
{
  const int b = blockIdx.x;
  const int tid = threadIdx.x;
  const int lane = tid & 63;
  const int wv = tid >> 6;          // wave 0..15
  const int col = lane & 15;        // node-in-tile
  const int kg = lane >> 4;         // channel group 0..3

  __shared__ __align__(16) char smem[61552];
  u32*   s_y    = (u32*)smem;                     // 45696 B (dead after layer 4; reused as s_red)
  u16*   s_rows = (u16*)(smem + 45696);           // 8192
  u16*   s_off  = (u16*)(smem + 53888);           // 1432
  float* s_dv   = (float*)(smem + 55320);         // 2856
  float* s_h    = (float*)(smem + 58176);         // 2856
  float* s_u    = (float*)(smem + 61032);         // 512
  float* s_red  = (float*)smem;                   // 4096 (aliases dead s_y)

  {
    const uint4* __restrict__ ysrc = (const uint4*)(yin + (size_t)b * NN * 16);
    uint4* sy4w = (uint4*)s_y;
    for (int s = tid; s < NN * 4; s += 1024) sy4w[yslot(s >> 2, s & 3)] = ysrc[s];
    for (int e = tid; e < EE; e += 1024) s_rows[e] = (u16)csr_rows[(size_t)b * EE + e];
    for (int i = tid; i <= NN; i += 1024) s_off[i] = (u16)csr_off[(size_t)b * (NN + 1) + i];
    for (int i = tid; i < NN; i += 1024) s_dv[i] = dinv[(size_t)b * NN + i];
  }

  union { u32 u[4]; short8 v; } uaA0, uaA1, uaB0, uaB1;
#pragma unroll
  for (int jj = 0; jj < 4; ++jj) {
    uaA0.u[jj] = pack2(W2[(kg * 8 + 2 * jj) * CH + col],      W2[(kg * 8 + 2 * jj + 1) * CH + col]);
    uaA1.u[jj] = pack2(W2[(kg * 8 + 2 * jj) * CH + 16 + col], W2[(kg * 8 + 2 * jj + 1) * CH + 16 + col]);
    uaB0.u[jj] = pack2(W3[(kg * 8 + 2 * jj) * CH + col],      W3[(kg * 8 + 2 * jj + 1) * CH + col]);
    uaB1.u[jj] = pack2(W3[(kg * 8 + 2 * jj) * CH + 16 + col], W3[(kg * 8 + 2 * jj + 1) * CH + 16 + col]);
  }
  float b1r[8], b2r[8], b3r[8], w4r[8];
#pragma unroll
  for (int j = 0; j < 8; ++j) {
    b1r[j] = b1[kg * 8 + j];
    b2r[j] = b2[kg * 8 + j];
    b3r[j] = b3[kg * 8 + j];
    w4r[j] = W4[kg * 8 + j];
  }
  const float bb4 = b4[0];
  __syncthreads();

  gcn_pass32<0>(s_y, s_rows, s_off, s_dv, wv, col, kg, uaA0.v, uaA1.v, b1r);
  gcn_pass32<1>(s_y, s_rows, s_off, s_dv, wv, col, kg, uaB0.v, uaB1.v, b2r);

  // layer 4: agg + b3, lrelu+t, dot W4 (32->1), *dinv -> s_h
  {
    const uint4* sy4 = (const uint4*)s_y;
#pragma unroll
    for (int p = 0; p < 3; ++p) {
      const int t = p * 16 + wv;
      const int node = t * 16 + col;
      const bool valid = (t < NT16) && (node < NN);
      float zx[8];
#pragma unroll
      for (int j = 0; j < 8; ++j) zx[j] = 0.f;
      if (valid) {
        uint4 u = sy4[yslot(node, kg)];
        zx[0] += bf_lo(u.x); zx[1] += bf_hi(u.x);
        zx[2] += bf_lo(u.y); zx[3] += bf_hi(u.y);
        zx[4] += bf_lo(u.z); zx[5] += bf_hi(u.z);
        zx[6] += bf_lo(u.w); zx[7] += bf_hi(u.w);
        const int o0 = s_off[node], o1 = s_off[node + 1];
        for (int k = o0; k < o1; ++k) {
          const int r = (int)s_rows[k];
          uint4 n = sy4[yslot(r, kg)];
          zx[0] += bf_lo(n.x); zx[1] += bf_hi(n.x);
          zx[2] += bf_lo(n.y); zx[3] += bf_hi(n.y);
          zx[4] += bf_lo(n.z); zx[5] += bf_hi(n.z);
          zx[6] += bf_lo(n.w); zx[7] += bf_hi(n.w);
        }
      }
      const float dv = valid ? s_dv[node] : 0.f;
      float part = 0.f;
#pragma unroll
      for (int j = 0; j < 8; ++j) {
        float t2 = fmaf(dv, zx[j], b3r[j]);
        float l = (t2 > 0.f) ? t2 : 0.01f * t2;
        part = fmaf(l + t2, w4r[j], part);
      }
      part += __shfl_xor(part, 16, 64);
      part += __shfl_xor(part, 32, 64);
      if (valid && kg == 0) s_h[node] = part * dv;
    }
  }
  __syncthreads();

  // tail aggregation: z = h + sum(h[rows]); lrelu(dinv*z + b4)
  {
    float hval = 0.f;
    const bool v = tid < NN;
    if (v) {
      float z = s_h[tid];
      const int o0 = s_off[tid], o1 = s_off[tid + 1];
      for (int k = o0; k < o1; ++k) z += s_h[(int)s_rows[k]];
      float t2 = fmaf(s_dv[tid], z, bb4);
      hval = (t2 > 0.f) ? t2 : 0.01f * t2;
    }
    __syncthreads();
    if (v) s_h[tid] = hval;
  }
  __syncthreads();

  // FC1: 714 -> 128, 8-way split-K
  const int j = tid & 127, q = tid >> 7;
  {
    const int n0 = (q * NN) >> 3, n1 = ((q + 1) * NN) >> 3;
    const float* __restrict__ w = Wf1 + j;
    float a0 = 0.f, a1 = 0.f;
    int n = n0;
#pragma unroll 4
    for (; n + 2 <= n1; n += 2) {
      a0 = fmaf(s_h[n], w[(size_t)n * 128], a0);
      a1 = fmaf(s_h[n + 1], w[(size_t)(n + 1) * 128], a1);
    }
    if (n < n1) a0 = fmaf(s_h[n], w[(size_t)n * 128], a0);
    s_red[tid] = a0 + a1;
  }
  __syncthreads();
  if (tid < 128) {
    float v = bf1[tid];
#pragma unroll
    for (int m = 0; m < 8; ++m) v += s_red[tid + 128 * m];
    s_u[tid] = fmaxf(v, 0.f);
  }
  __syncthreads();
  // FC2: 128 -> 128, 8-way split-K
  {
    const float* __restrict__ w = Wf2 + j;
    float a0 = 0.f, a1 = 0.f;
#pragma unroll
    for (int k = q * 16; k < q * 16 + 16; k += 2) {
      a0 = fmaf(s_u[k], w[(size_t)k * 128], a0);
      a1 = fmaf(s_u[k + 1], w[(size_t)(k + 1) * 128], a1);
    }
    s_red[tid] = a0 + a1;
  }
  __syncthreads();
  if (tid < 128) {
    float v = bf2[tid];
#pragma unroll
    for (int m = 0; m < 8; ++m) v += s_red[tid + 128 * m];
    out[(size_t)b * 128 + tid] = fmaxf(v, 0.f);
  }
}

extern "C" void kernel_launch(void* const* d_in, const int* in_sizes, int n_in,
                              void* d_out, int out_size, void* d_ws, size_t ws_size,
                              hipStream_t stream)
{
  (void)in_sizes; (void)n_in; (void)out_size; (void)ws_size;
  const int*   ids  = (const int*)d_in[0];
  const float* cont = (const float*)d_in[1];
  const int*   edges= (const int*)d_in[2];
  const float* emb  = (const float*)d_in[3];
  const float* W1   = (const float*)d_in[4];
  const float* b1   = (const float*)d_in[5];
  const float* W2   = (const float*)d_in[6];
  const float* b2   = (const float*)d_in[7];
  const float* W3   = (const float*)d_in[8];
  const float* b3   = (const float*)d_in[9];
  const float* W4   = (const float*)d_in[10];
  const float* b4   = (const float*)d_in[11];
  const float* Wf1  = (const float*)d_in[12];
  const float* bf1  = (const float*)d_in[13];
  const float* Wf2  = (const float*)d_in[14];
  const float* bf2  = (const float*)d_in[15];
  float* out = (float*)d_out;

  char* ws = (char*)d_ws;
  size_t off = 0;
  auto alloc = [&](size_t bytes) -> void* {
    void* p = ws + off;
    off = (off + bytes + 255) & ~(size_t)255;
    return p;
  };
  float* dinv     = (float*)alloc((size_t)BB * NN * 4);
  int*   csr_off  = (int*)  alloc((size_t)BB * (NN + 1) * 4);
  int*   csr_rows = (int*)  alloc((size_t)BB * EE * 4);
  uint2* embh     = (uint2*)alloc((size_t)VOCAB * 64 * 2);   // bf16 [VOCAB][64] padded
  u32*   yA       = (u32*)  alloc((size_t)BB * NN * 16 * 4);

  hipLaunchKernelGGL(k_conv, dim3((VOCAB * 16 + 255) / 256), dim3(256), 0, stream, emb, embh);
  hipLaunchKernelGGL(k_prep, dim3(BB), dim3(256), 0, stream, edges, dinv, csr_off, csr_rows);
  hipLaunchKernelGGL(k_gcn1m, dim3(BB * 6), dim3(256), 0, stream,
                     ids, cont, (const uint4*)embh, W1, dinv, yA);
  hipLaunchKernelGGL(k_fused, dim3(BB), dim3(1024), 0, stream,
                     yA, dinv, csr_off, csr_rows,
                     b1, W2, b2, W3, b3, W4, b4, Wf1, bf1, Wf2, bf2, out);
}

// Round 8
// 117.225 us; speedup vs baseline: 2.9922x; 1.0483x over previous
//
#include <hip/hip_runtime.h>
#include <hip/hip_bf16.h>

#define BB 512
#define NN 714
#define EE 4096
#define ED2 62
#define CH 32
#define NT16 45   // ceil(NN/16)
#define VOCAB 38733

typedef unsigned int u32;
typedef unsigned short u16;
typedef short short8 __attribute__((ext_vector_type(8)));
typedef float float4v __attribute__((ext_vector_type(4)));

__device__ __forceinline__ u32 f2bf(float f) {
  u32 u = __float_as_uint(f);
  return (u + 0x7fffu + ((u >> 16) & 1u)) >> 16;
}
__device__ __forceinline__ u32 pack2(float a, float b) {
  return f2bf(a) | (f2bf(b) << 16);
}
__device__ __forceinline__ float bf_lo(u32 u) { return __uint_as_float(u << 16); }
__device__ __forceinline__ float bf_hi(u32 u) { return __uint_as_float(u & 0xffff0000u); }

// y-in-LDS swizzle: uint4 slot q of node -> q ^ ((node>>1)&3).
__device__ __forceinline__ int yslot(int node, int q) {
  return (node << 2) | (q ^ ((node >> 1) & 3));
}

// ---------------- Kernel 0: f32 emb table -> bf16 [VOCAB][64] zero-padded ----------------
__global__ __launch_bounds__(256) void k_conv(const float* __restrict__ emb,
                                              uint2* __restrict__ embh)
{
  const int t = blockIdx.x * 256 + threadIdx.x;
  if (t >= VOCAB * 16) return;
  const int row = t >> 4, c = (t & 15) * 4;
  const float* __restrict__ p = emb + (size_t)row * ED2;
  float v0 = (c + 0 < ED2) ? p[c + 0] : 0.f;
  float v1 = (c + 1 < ED2) ? p[c + 1] : 0.f;
  float v2 = (c + 2 < ED2) ? p[c + 2] : 0.f;
  float v3 = (c + 3 < ED2) ? p[c + 3] : 0.f;
  uint2 o = { pack2(v0, v1), pack2(v2, v3) };
  embh[t] = o;
}

// ---------------- Kernel A: degree, dinv, CSR + degree-sorted perm ----------------
__global__ __launch_bounds__(256) void k_prep(const int* __restrict__ edges,
    float* __restrict__ dinv, int* __restrict__ csr_off, int* __restrict__ csr_rows,
    u16* __restrict__ perm_g)
{
  const int b = blockIdx.x;
  const int tid = threadIdx.x;
  const int* __restrict__ er = edges + (size_t)b * 2 * EE;       // e[0] = source (row)
  const int* __restrict__ ec = er + EE;                          // e[1] = target (col)
  __shared__ int s_cnt[NN];
  __shared__ int s_a[1024];
  __shared__ int s_b[1024];
  for (int i = tid; i < NN; i += 256) s_cnt[i] = 0;
  __syncthreads();
  for (int e = tid; e < EE; e += 256) atomicAdd(&s_cnt[ec[e]], 1);
  __syncthreads();
  for (int i = tid; i < 1024; i += 256) s_a[i] = (i < NN) ? s_cnt[i] : 0;
  for (int i = tid; i < NN; i += 256)
    dinv[(size_t)b * NN + i] = rsqrtf((float)(s_cnt[i] + 1));    // +1 self loop
  __syncthreads();
  int* src = s_a; int* dst = s_b;
  for (int d = 1; d < 1024; d <<= 1) {
    for (int i = tid; i < 1024; i += 256) {
      int v = src[i];
      if (i >= d) v += src[i - d];
      dst[i] = v;
    }
    __syncthreads();
    int* t = src; src = dst; dst = t;
  }
  // src (= s_a after 10 swaps) holds inclusive scan of counts
  int* og = csr_off + (size_t)b * (NN + 1);
  for (int i = tid; i <= NN; i += 256) og[i] = (i == 0) ? 0 : src[i - 1];
  for (int i = tid; i < NN; i += 256) s_cnt[i] = 0;  // reuse as fill cursors
  __syncthreads();
  int* rg = csr_rows + (size_t)b * EE;
  for (int e = tid; e < EE; e += 256) {
    int c = ec[e];
    int p = atomicAdd(&s_cnt[c], 1);
    int base = (c == 0) ? 0 : src[c - 1];
    rg[base + p] = er[e];
  }
  // ---- degree-sorted permutation (64-bin counting sort; order within bin arbitrary:
  // per-node results are independent of tile grouping, so output is unchanged) ----
  int* hist = s_b;   // free now
  for (int i = tid; i < 64; i += 256) hist[i] = 0;
  if (tid < NT16 * 16 - NN) perm_g[(size_t)b * (NT16 * 16) + NN + tid] = 0xFFFFu;
  __syncthreads();
  for (int i = tid; i < NN; i += 256) {
    int deg = src[i] - (i ? src[i - 1] : 0);
    atomicAdd(&hist[deg < 63 ? deg : 63], 1);
  }
  __syncthreads();
  if (tid == 0) {
    int run = 0;
    for (int j = 0; j < 64; ++j) { int c = hist[j]; hist[j] = run; run += c; }
  }
  __syncthreads();
  for (int i = tid; i < NN; i += 256) {
    int deg = src[i] - (i ? src[i - 1] : 0);
    int pos = atomicAdd(&hist[deg < 63 ? deg : 63], 1);
    perm_g[(size_t)b * (NT16 * 16) + pos] = (u16)i;
  }
}

// ---------------- Kernel B: MFMA GCN1, bf16-table gather (unchanged) ----------------
__global__ __launch_bounds__(256) void k_gcn1m(
    const int* __restrict__ ids, const float* __restrict__ cont,
    const uint4* __restrict__ embh, const float* __restrict__ W1,
    const float* __restrict__ dinv, u32* __restrict__ y1)
{
  const int bid = blockIdx.x;
  const int b = bid / 6, blk = bid - b * 6;
  const int base = blk * 128;
  const int nnodes = (NN - base < 128) ? (NN - base) : 128;
  const int nrows = nnodes * 2;
  const int tid = threadIdx.x, lane = tid & 63, wv = tid >> 6;
  const int col = lane & 15, kg = lane >> 4;

  __shared__ __align__(16) unsigned short sX[128 * 128];
  __shared__ float sC[128][4];
  __shared__ int s_ids[256];

  for (int t = tid; t < nnodes * 3; t += 256)
    sC[t / 3][t % 3] = cont[((size_t)b * NN + base) * 3 + t];
  s_ids[tid] = (tid < nrows) ? ids[((size_t)b * NN + base) * 2 + tid] : -1;
  __syncthreads();

  const int ck = tid & 7;
  const int rbase = tid >> 3;
  {
    uint4 w4[8];
#pragma unroll
    for (int q = 0; q < 8; ++q) {
      const int id = s_ids[q * 32 + rbase];
      if (id >= 0) w4[q] = embh[(size_t)id * 8 + ck];
      else { w4[q].x = 0; w4[q].y = 0; w4[q].z = 0; w4[q].w = 0; }
    }
#pragma unroll
    for (int q = 0; q < 8; ++q) {
      const int r = q * 32 + rbase;
      const int node = r >> 1, slot = r & 1;
      const int c16 = (node * 16 + slot * 8 + ck) ^ (node & 7);
      ((uint4*)sX)[c16] = w4[q];
    }
  }

  union { u32 u[4]; short8 v; } A[4][2];
#pragma unroll
  for (int kc = 0; kc < 4; ++kc)
#pragma unroll
    for (int hh = 0; hh < 2; ++hh)
#pragma unroll
      for (int jj = 0; jj < 4; ++jj) {
        const int k0 = kc * 32 + kg * 8 + 2 * jj;
        const int k1 = k0 + 1;
        const int m0 = (k0 < 62) ? k0 : ((k0 >= 64 && k0 < 126) ? k0 - 2 : -1);
        const int m1 = (k1 < 62) ? k1 : ((k1 >= 64 && k1 < 126) ? k1 - 2 : -1);
        const float wa = (m0 >= 0) ? W1[m0 * CH + hh * 16 + col] : 0.f;
        const float wb = (m1 >= 0) ? W1[m1 * CH + hh * 16 + col] : 0.f;
        A[kc][hh].u[jj] = pack2(wa, wb);
      }
  float Wc0[3][4], Wc1[3][4];
#pragma unroll
  for (int j = 0; j < 3; ++j)
#pragma unroll
    for (int reg = 0; reg < 4; ++reg) {
      Wc0[j][reg] = W1[(124 + j) * CH + 4 * kg + reg];
      Wc1[j][reg] = W1[(124 + j) * CH + 16 + 4 * kg + reg];
    }
  __syncthreads();

  const int ntiles = (nnodes + 15) >> 4;
  for (int t = wv; t < ntiles; t += 4) {
    const int ln = t * 16 + col;
    float4v a0 = {0.f, 0.f, 0.f, 0.f}, a1 = {0.f, 0.f, 0.f, 0.f};
#pragma unroll
    for (int kc = 0; kc < 4; ++kc) {
      const int idx16 = (ln * 16 + kc * 4 + kg) ^ (ln & 7);
      short8 bf = *(const short8*)(sX + idx16 * 8);
      a0 = __builtin_amdgcn_mfma_f32_16x16x32_bf16(A[kc][0].v, bf, a0, 0, 0, 0);
      a1 = __builtin_amdgcn_mfma_f32_16x16x32_bf16(A[kc][1].v, bf, a1, 0, 0, 0);
    }
#pragma unroll
    for (int j = 0; j < 3; ++j) {
      const float cv = sC[ln][j];
#pragma unroll
      for (int reg = 0; reg < 4; ++reg) {
        a0[reg] = fmaf(cv, Wc0[j][reg], a0[reg]);
        a1[reg] = fmaf(cv, Wc1[j][reg], a1[reg]);
      }
    }
    if (ln < nnodes) {
      const int gnode = base + ln;
      const float dv = dinv[(size_t)b * NN + gnode];
      u32* op = y1 + ((size_t)b * NN + gnode) * 16;
      uint2 s0 = { pack2(a0[0] * dv, a0[1] * dv), pack2(a0[2] * dv, a0[3] * dv) };
      uint2 s1 = { pack2(a1[0] * dv, a1[1] * dv), pack2(a1[2] * dv, a1[3] * dv) };
      *(uint2*)(op + 2 * kg) = s0;
      *(uint2*)(op + 8 + 2 * kg) = s1;
    }
  }
}

// ---------------- Fused kernel: layers 2,3,4 + tail (one block per batch) ----------------
template<int ACT>
__device__ __forceinline__ void gcn_pass32(
    u32* __restrict__ sy, const u16* __restrict__ s_rows,
    const u16* __restrict__ s_off, const float* __restrict__ s_dv,
    const u16* __restrict__ s_perm,
    const int wv, const int col, const int kg,
    const short8 a0v, const short8 a1v, const float* __restrict__ bias8)
{
  const uint4* sy4 = (const uint4*)sy;
  u32 outs[3][4];
  int nodes[3];
#pragma unroll
  for (int p = 0; p < 3; ++p) {
    const int t = p * 16 + wv;
    int node = -1;
    if (t < NT16) { const int pv = s_perm[t * 16 + col]; node = (pv == 0xFFFF) ? -1 : pv; }
    nodes[p] = node;
    const bool valid = node >= 0;
    float zx[8];
#pragma unroll
    for (int j = 0; j < 8; ++j) zx[j] = 0.f;
    if (valid) {
      uint4 u = sy4[yslot(node, kg)];
      zx[0] += bf_lo(u.x); zx[1] += bf_hi(u.x);
      zx[2] += bf_lo(u.y); zx[3] += bf_hi(u.y);
      zx[4] += bf_lo(u.z); zx[5] += bf_hi(u.z);
      zx[6] += bf_lo(u.w); zx[7] += bf_hi(u.w);
      const int o0 = s_off[node], o1 = s_off[node + 1];
      for (int k = o0; k < o1; ++k) {
        const int r = (int)s_rows[k];
        uint4 n = sy4[yslot(r, kg)];
        zx[0] += bf_lo(n.x); zx[1] += bf_hi(n.x);
        zx[2] += bf_lo(n.y); zx[3] += bf_hi(n.y);
        zx[4] += bf_lo(n.z); zx[5] += bf_hi(n.z);
        zx[6] += bf_lo(n.w); zx[7] += bf_hi(n.w);
      }
    }
    const float dv = valid ? s_dv[node] : 0.f;
    float h[8];
#pragma unroll
    for (int j = 0; j < 8; ++j) {
      float t2 = fmaf(dv, zx[j], bias8[j]);
      float l = (t2 > 0.f) ? t2 : 0.01f * t2;
      h[j] = (ACT == 0) ? l : (l + t2);
    }
    union { u32 u[4]; short8 v; } ub;
#pragma unroll
    for (int jj = 0; jj < 4; ++jj) ub.u[jj] = pack2(h[2 * jj], h[2 * jj + 1]);
    float4v z4 = {0.f, 0.f, 0.f, 0.f};
    float4v d0 = __builtin_amdgcn_mfma_f32_16x16x32_bf16(a0v, ub.v, z4, 0, 0, 0);
    float4v d1 = __builtin_amdgcn_mfma_f32_16x16x32_bf16(a1v, ub.v, z4, 0, 0, 0);
    outs[p][0] = pack2(d0[0] * dv, d0[1] * dv);
    outs[p][1] = pack2(d0[2] * dv, d0[3] * dv);
    outs[p][2] = pack2(d1[0] * dv, d1[1] * dv);
    outs[p][3] = pack2(d1[2] * dv, d1[3] * dv);
  }
  __syncthreads();
#pragma unroll
  for (int p = 0; p < 3; ++p) {
    const int node = nodes[p];
    if (node >= 0) {
      const int sw = (node >> 1) & 3;
      u32* op = sy + node * 16;
      uint2 s0 = { outs[p][0], outs[p][1] };
      uint2 s1 = { outs[p][2], outs[p][3] };
      *(uint2*)(op + (((kg >> 1) ^ sw) << 2) + ((2 * kg) & 3)) = s0;
      *(uint2*)(op + (((2 + (kg >> 1)) ^ sw) << 2) + ((2 * kg) & 3)) = s1;
    }
  }
  __syncthreads();
}

__global__ __launch_bounds__(1024) void k_fused(
    const u32* __restrict__ yin, const float* __restrict__ dinv,
    const int* __restrict__ csr_off, const int* __restrict__ csr_rows,
    const u16* __restrict__ perm_g,
    const float* __restrict__ b1, const float* __restrict__ W2,
    const float* __restrict__ b2, const float* __restrict__ W3,
    const float* __restrict__ b3, const float* __restrict__ W4,
    const float* __restrict__ b4, const float* __restrict__ Wf1,
    const float* __restrict__ bf1, const float* __restrict__ Wf2,
    const float* __restrict__ bf2, float* __restrict__ out)
{
  const int b = blockIdx.x;
  const int tid = threadIdx.x;
  const int lane = tid & 63;
  const int wv = tid >> 6;          // wave 0..15
  const int col = lane & 15;        // node-in-tile
  const int kg = lane >> 4;         // channel group 0..3

  __shared__ __align__(16) char smem[62992];
  u32*   s_y    = (u32*)smem;                     // 45696 B (dead after layer 4; reused as s_red)
  u16*   s_rows = (u16*)(smem + 45696);           // 8192
  u16*   s_off  = (u16*)(smem + 53888);           // 1432
  float* s_dv   = (float*)(smem + 55320);         // 2856
  float* s_h    = (float*)(smem + 58176);         // 2856
  float* s_u    = (float*)(smem + 61032);         // 512
  u16*   s_perm = (u16*)(smem + 61544);           // 1440
  float* s_red  = (float*)smem;                   // 4096 (aliases dead s_y)

  {
    const uint4* __restrict__ ysrc = (const uint4*)(yin + (size_t)b * NN * 16);
    uint4* sy4w = (uint4*)s_y;
    for (int s = tid; s < NN * 4; s += 1024) sy4w[yslot(s >> 2, s & 3)] = ysrc[s];
    for (int e = tid; e < EE; e += 1024) s_rows[e] = (u16)csr_rows[(size_t)b * EE + e];
    for (int i = tid; i <= NN; i += 1024) s_off[i] = (u16)csr_off[(size_t)b * (NN + 1) + i];
    for (int i = tid; i < NN; i += 1024) s_dv[i] = dinv[(size_t)b * NN + i];
    for (int i = tid; i < NT16 * 16; i += 1024) s_perm[i] = perm_g[(size_t)b * (NT16 * 16) + i];
  }

  union { u32 u[4]; short8 v; } uaA0, uaA1, uaB0, uaB1;
#pragma unroll
  for (int jj = 0; jj < 4; ++jj) {
    uaA0.u[jj] = pack2(W2[(kg * 8 + 2 * jj) * CH + col],      W2[(kg * 8 + 2 * jj + 1) * CH + col]);
    uaA1.u[jj] = pack2(W2[(kg * 8 + 2 * jj) * CH + 16 + col], W2[(kg * 8 + 2 * jj + 1) * CH + 16 + col]);
    uaB0.u[jj] = pack2(W3[(kg * 8 + 2 * jj) * CH + col],      W3[(kg * 8 + 2 * jj + 1) * CH + col]);
    uaB1.u[jj] = pack2(W3[(kg * 8 + 2 * jj) * CH + 16 + col], W3[(kg * 8 + 2 * jj + 1) * CH + 16 + col]);
  }
  float b1r[8], b2r[8], b3r[8], w4r[8];
#pragma unroll
  for (int j = 0; j < 8; ++j) {
    b1r[j] = b1[kg * 8 + j];
    b2r[j] = b2[kg * 8 + j];
    b3r[j] = b3[kg * 8 + j];
    w4r[j] = W4[kg * 8 + j];
  }
  const float bb4 = b4[0];
  __syncthreads();

  gcn_pass32<0>(s_y, s_rows, s_off, s_dv, s_perm, wv, col, kg, uaA0.v, uaA1.v, b1r);
  gcn_pass32<1>(s_y, s_rows, s_off, s_dv, s_perm, wv, col, kg, uaB0.v, uaB1.v, b2r);

  // layer 4: agg + b3, lrelu+t, dot W4 (32->1), *dinv -> s_h
  {
    const uint4* sy4 = (const uint4*)s_y;
#pragma unroll
    for (int p = 0; p < 3; ++p) {
      const int t = p * 16 + wv;
      int node = -1;
      if (t < NT16) { const int pv = s_perm[t * 16 + col]; node = (pv == 0xFFFF) ? -1 : pv; }
      const bool valid = node >= 0;
      float zx[8];
#pragma unroll
      for (int j = 0; j < 8; ++j) zx[j] = 0.f;
      if (valid) {
        uint4 u = sy4[yslot(node, kg)];
        zx[0] += bf_lo(u.x); zx[1] += bf_hi(u.x);
        zx[2] += bf_lo(u.y); zx[3] += bf_hi(u.y);
        zx[4] += bf_lo(u.z); zx[5] += bf_hi(u.z);
        zx[6] += bf_lo(u.w); zx[7] += bf_hi(u.w);
        const int o0 = s_off[node], o1 = s_off[node + 1];
        for (int k = o0; k < o1; ++k) {
          const int r = (int)s_rows[k];
          uint4 n = sy4[yslot(r, kg)];
          zx[0] += bf_lo(n.x); zx[1] += bf_hi(n.x);
          zx[2] += bf_lo(n.y); zx[3] += bf_hi(n.y);
          zx[4] += bf_lo(n.z); zx[5] += bf_hi(n.z);
          zx[6] += bf_lo(n.w); zx[7] += bf_hi(n.w);
        }
      }
      const float dv = valid ? s_dv[node] : 0.f;
      float part = 0.f;
#pragma unroll
      for (int j = 0; j < 8; ++j) {
        float t2 = fmaf(dv, zx[j], b3r[j]);
        float l = (t2 > 0.f) ? t2 : 0.01f * t2;
        part = fmaf(l + t2, w4r[j], part);
      }
      part += __shfl_xor(part, 16, 64);
      part += __shfl_xor(part, 32, 64);
      if (valid && kg == 0) s_h[node] = part * dv;
    }
  }
  __syncthreads();

  // tail aggregation: z = h + sum(h[rows]); lrelu(dinv*z + b4)
  {
    float hval = 0.f;
    const bool v = tid < NN;
    if (v) {
      float z = s_h[tid];
      const int o0 = s_off[tid], o1 = s_off[tid + 1];
      for (int k = o0; k < o1; ++k) z += s_h[(int)s_rows[k]];
      float t2 = fmaf(s_dv[tid], z, bb4);
      hval = (t2 > 0.f) ? t2 : 0.01f * t2;
    }
    __syncthreads();
    if (v) s_h[tid] = hval;
  }
  __syncthreads();

  // FC1: 714 -> 128, 8-way split-K
  const int j = tid & 127, q = tid >> 7;
  {
    const int n0 = (q * NN) >> 3, n1 = ((q + 1) * NN) >> 3;
    const float* __restrict__ w = Wf1 + j;
    float a0 = 0.f, a1 = 0.f;
    int n = n0;
#pragma unroll 4
    for (; n + 2 <= n1; n += 2) {
      a0 = fmaf(s_h[n], w[(size_t)n * 128], a0);
      a1 = fmaf(s_h[n + 1], w[(size_t)(n + 1) * 128], a1);
    }
    if (n < n1) a0 = fmaf(s_h[n], w[(size_t)n * 128], a0);
    s_red[tid] = a0 + a1;
  }
  __syncthreads();
  if (tid < 128) {
    float v = bf1[tid];
#pragma unroll
    for (int m = 0; m < 8; ++m) v += s_red[tid + 128 * m];
    s_u[tid] = fmaxf(v, 0.f);
  }
  __syncthreads();
  // FC2: 128 -> 128, 8-way split-K
  {
    const float* __restrict__ w = Wf2 + j;
    float a0 = 0.f, a1 = 0.f;
#pragma unroll
    for (int k = q * 16; k < q * 16 + 16; k += 2) {
      a0 = fmaf(s_u[k], w[(size_t)k * 128], a0);
      a1 = fmaf(s_u[k + 1], w[(size_t)(k + 1) * 128], a1);
    }
    s_red[tid] = a0 + a1;
  }
  __syncthreads();
  if (tid < 128) {
    float v = bf2[tid];
#pragma unroll
    for (int m = 0; m < 8; ++m) v += s_red[tid + 128 * m];
    out[(size_t)b * 128 + tid] = fmaxf(v, 0.f);
  }
}

extern "C" void kernel_launch(void* const* d_in, const int* in_sizes, int n_in,
                              void* d_out, int out_size, void* d_ws, size_t ws_size,
                              hipStream_t stream)
{
  (void)in_sizes; (void)n_in; (void)out_size; (void)ws_size;
  const int*   ids  = (const int*)d_in[0];
  const float* cont = (const float*)d_in[1];
  const int*   edges= (const int*)d_in[2];
  const float* emb  = (const float*)d_in[3];
  const float* W1   = (const float*)d_in[4];
  const float* b1   = (const float*)d_in[5];
  const float* W2   = (const float*)d_in[6];
  const float* b2   = (const float*)d_in[7];
  const float* W3   = (const float*)d_in[8];
  const float* b3   = (const float*)d_in[9];
  const float* W4   = (const float*)d_in[10];
  const float* b4   = (const float*)d_in[11];
  const float* Wf1  = (const float*)d_in[12];
  const float* bf1  = (const float*)d_in[13];
  const float* Wf2  = (const float*)d_in[14];
  const float* bf2  = (const float*)d_in[15];
  float* out = (float*)d_out;

  char* ws = (char*)d_ws;
  size_t off = 0;
  auto alloc = [&](size_t bytes) -> void* {
    void* p = ws + off;
    off = (off + bytes + 255) & ~(size_t)255;
    return p;
  };
  float* dinv     = (float*)alloc((size_t)BB * NN * 4);
  int*   csr_off  = (int*)  alloc((size_t)BB * (NN + 1) * 4);
  int*   csr_rows = (int*)  alloc((size_t)BB * EE * 4);
  uint2* embh     = (uint2*)alloc((size_t)VOCAB * 64 * 2);   // bf16 [VOCAB][64] padded
  u32*   yA       = (u32*)  alloc((size_t)BB * NN * 16 * 4);
  u16*   perm     = (u16*)  alloc((size_t)BB * (NT16 * 16) * 2);

  hipLaunchKernelGGL(k_conv, dim3((VOCAB * 16 + 255) / 256), dim3(256), 0, stream, emb, embh);
  hipLaunchKernelGGL(k_prep, dim3(BB), dim3(256), 0, stream, edges, dinv, csr_off, csr_rows, perm);
  hipLaunchKernelGGL(k_gcn1m, dim3(BB * 6), dim3(256), 0, stream,
                     ids, cont, (const uint4*)embh, W1, dinv, yA);
  hipLaunchKernelGGL(k_fused, dim3(BB), dim3(1024), 0, stream,
                     yA, dinv, csr_off, csr_rows, perm,
                     b1, W2, b2, W3, b3, W4, b4, Wf1, bf1, Wf2, bf2, out);
}

// Round 9
// 116.219 us; speedup vs baseline: 3.0181x; 1.0087x over previous
//
#include <hip/hip_runtime.h>
#include <hip/hip_bf16.h>

#define BB 512
#define NN 714
#define EE 4096
#define ED2 62
#define CH 32
#define NT16 45    // ceil(NN/16)
#define NPAD 720   // NT16*16
#define VOCAB 38733
#define ELLR 404   // ELL row capacity (rows of 16 u16); expected usage ~300-345
#define ELLB (ELLR*16)

typedef unsigned int u32;
typedef unsigned short u16;
typedef short short8 __attribute__((ext_vector_type(8)));
typedef float float4v __attribute__((ext_vector_type(4)));

__device__ __forceinline__ u32 f2bf(float f) {
  u32 u = __float_as_uint(f);
  return (u + 0x7fffu + ((u >> 16) & 1u)) >> 16;
}
__device__ __forceinline__ u32 pack2(float a, float b) {
  return f2bf(a) | (f2bf(b) << 16);
}
__device__ __forceinline__ float bf_lo(u32 u) { return __uint_as_float(u << 16); }
__device__ __forceinline__ float bf_hi(u32 u) { return __uint_as_float(u & 0xffff0000u); }

// y-in-LDS swizzle: uint4 slot q of node -> q ^ ((node>>1)&3).
__device__ __forceinline__ int yslot(int node, int q) {
  return (node << 2) | (q ^ ((node >> 1) & 3));
}

// ---------------- Kernel 0: f32 emb table -> bf16 [VOCAB][64] zero-padded ----------------
__global__ __launch_bounds__(256) void k_conv(const float* __restrict__ emb,
                                              uint2* __restrict__ embh)
{
  const int t = blockIdx.x * 256 + threadIdx.x;
  if (t >= VOCAB * 16) return;
  const int row = t >> 4, c = (t & 15) * 4;
  const float* __restrict__ p = emb + (size_t)row * ED2;
  float v0 = (c + 0 < ED2) ? p[c + 0] : 0.f;
  float v1 = (c + 1 < ED2) ? p[c + 1] : 0.f;
  float v2 = (c + 2 < ED2) ? p[c + 2] : 0.f;
  float v3 = (c + 3 < ED2) ? p[c + 3] : 0.f;
  uint2 o = { pack2(v0, v1), pack2(v2, v3) };
  embh[t] = o;
}

// ---------------- Kernel A: degree, dinv, degree-sorted perm, tile-ELL ----------------
__global__ __launch_bounds__(256) void k_prep(const int* __restrict__ edges,
    float* __restrict__ dinv, u16* __restrict__ perm_g,
    u16* __restrict__ ell_g, u16* __restrict__ elloff_g)
{
  const int b = blockIdx.x;
  const int tid = threadIdx.x;
  const int* __restrict__ er = edges + (size_t)b * 2 * EE;       // e[0] = source (row)
  const int* __restrict__ ec = er + EE;                          // e[1] = target (col)
  __shared__ int s_cnt[NN];
  __shared__ int s_a[1024];
  __shared__ int s_b[1024];
  __shared__ u16 s_rows16[EE];
  __shared__ u16 s_perm[NPAD];
  __shared__ u16 s_degP[NPAD];
  __shared__ int s_hist[64];
  __shared__ int s_md[NT16 + 1];

  for (int i = tid; i < NN; i += 256) s_cnt[i] = 0;
  __syncthreads();
  for (int e = tid; e < EE; e += 256) atomicAdd(&s_cnt[ec[e]], 1);
  __syncthreads();
  for (int i = tid; i < 1024; i += 256) s_a[i] = (i < NN) ? s_cnt[i] : 0;
  for (int i = tid; i < NN; i += 256)
    dinv[(size_t)b * NN + i] = rsqrtf((float)(s_cnt[i] + 1));    // +1 self loop
  __syncthreads();
  int* src = s_a; int* dst = s_b;
  for (int d = 1; d < 1024; d <<= 1) {
    for (int i = tid; i < 1024; i += 256) {
      int v = src[i];
      if (i >= d) v += src[i - d];
      dst[i] = v;
    }
    __syncthreads();
    int* t = src; src = dst; dst = t;
  }
  // src (= s_a, 10 swaps) = inclusive scan of degree counts
  for (int i = tid; i < NN; i += 256) s_cnt[i] = 0;  // fill cursors
  __syncthreads();
  for (int e = tid; e < EE; e += 256) {
    int c = ec[e];
    int p = atomicAdd(&s_cnt[c], 1);
    int base = (c == 0) ? 0 : src[c - 1];
    s_rows16[base + p] = (u16)er[e];
  }
  // degree-sorted perm (counting sort, 64 bins)
  for (int i = tid; i < 64; i += 256) s_hist[i] = 0;
  for (int i = tid; i < NPAD; i += 256) { s_perm[i] = 0xFFFFu; s_degP[i] = 0; }
  __syncthreads();
  for (int i = tid; i < NN; i += 256) {
    int deg = src[i] - (i ? src[i - 1] : 0);
    atomicAdd(&s_hist[deg < 63 ? deg : 63], 1);
  }
  __syncthreads();
  if (tid == 0) {
    int run = 0;
    for (int j = 0; j < 64; ++j) { int c = s_hist[j]; s_hist[j] = run; run += c; }
  }
  __syncthreads();
  for (int i = tid; i < NN; i += 256) {
    int deg = src[i] - (i ? src[i - 1] : 0);
    int pos = atomicAdd(&s_hist[deg < 63 ? deg : 63], 1);
    s_perm[pos] = (u16)i;
    s_degP[pos] = (u16)deg;
  }
  __syncthreads();
  for (int i = tid; i < NPAD; i += 256) perm_g[(size_t)b * NPAD + i] = s_perm[i];
  // per-tile max degree
  if (tid < NT16) {
    int md = 0;
#pragma unroll
    for (int c = 0; c < 16; ++c) { int d = s_degP[tid * 16 + c]; md = d > md ? d : md; }
    s_md[tid] = md;
  }
  __syncthreads();
  if (tid == 0) {
    int run = 0;
    for (int t = 0; t < NT16; ++t) {
      int m = s_md[t];
      if (run + m > ELLR) m = ELLR - run;       // capacity clamp (never expected)
      s_md[t] = run; run += m;
    }
    s_md[NT16] = run;
  }
  __syncthreads();
  if (tid <= NT16) elloff_g[(size_t)b * (NT16 + 1) + tid] = (u16)s_md[tid];
  // fill ELL (pad -> dummy node NN)
  u16* eg = ell_g + (size_t)b * ELLB;
  for (int t = 0; t < NT16; ++t) {
    const int base = s_md[t], md = s_md[t + 1] - base;
    for (int s = tid; s < md * 16; s += 256) {
      const int kk = s >> 4, col = s & 15;
      const int pv = s_perm[t * 16 + col];
      u16 entry = (u16)NN;
      if (pv != 0xFFFF) {
        const int deg = s_degP[t * 16 + col];
        if (kk < deg) {
          const int off = pv ? src[pv - 1] : 0;
          entry = s_rows16[off + kk];
        }
      }
      eg[base * 16 + s] = entry;
    }
  }
}

// ---------------- Kernel B: MFMA GCN1, bf16-table gather (unchanged) ----------------
__global__ __launch_bounds__(256) void k_gcn1m(
    const int* __restrict__ ids, const float* __restrict__ cont,
    const uint4* __restrict__ embh, const float* __restrict__ W1,
    const float* __restrict__ dinv, u32* __restrict__ y1)
{
  const int bid = blockIdx.x;
  const int b = bid / 6, blk = bid - b * 6;
  const int base = blk * 128;
  const int nnodes = (NN - base < 128) ? (NN - base) : 128;
  const int nrows = nnodes * 2;
  const int tid = threadIdx.x, lane = tid & 63, wv = tid >> 6;
  const int col = lane & 15, kg = lane >> 4;

  __shared__ __align__(16) unsigned short sX[128 * 128];
  __shared__ float sC[128][4];
  __shared__ int s_ids[256];

  for (int t = tid; t < nnodes * 3; t += 256)
    sC[t / 3][t % 3] = cont[((size_t)b * NN + base) * 3 + t];
  s_ids[tid] = (tid < nrows) ? ids[((size_t)b * NN + base) * 2 + tid] : -1;
  __syncthreads();

  const int ck = tid & 7;
  const int rbase = tid >> 3;
  {
    uint4 w4[8];
#pragma unroll
    for (int q = 0; q < 8; ++q) {
      const int id = s_ids[q * 32 + rbase];
      if (id >= 0) w4[q] = embh[(size_t)id * 8 + ck];
      else { w4[q].x = 0; w4[q].y = 0; w4[q].z = 0; w4[q].w = 0; }
    }
#pragma unroll
    for (int q = 0; q < 8; ++q) {
      const int r = q * 32 + rbase;
      const int node = r >> 1, slot = r & 1;
      const int c16 = (node * 16 + slot * 8 + ck) ^ (node & 7);
      ((uint4*)sX)[c16] = w4[q];
    }
  }

  union { u32 u[4]; short8 v; } A[4][2];
#pragma unroll
  for (int kc = 0; kc < 4; ++kc)
#pragma unroll
    for (int hh = 0; hh < 2; ++hh)
#pragma unroll
      for (int jj = 0; jj < 4; ++jj) {
        const int k0 = kc * 32 + kg * 8 + 2 * jj;
        const int k1 = k0 + 1;
        const int m0 = (k0 < 62) ? k0 : ((k0 >= 64 && k0 < 126) ? k0 - 2 : -1);
        const int m1 = (k1 < 62) ? k1 : ((k1 >= 64 && k1 < 126) ? k1 - 2 : -1);
        const float wa = (m0 >= 0) ? W1[m0 * CH + hh * 16 + col] : 0.f;
        const float wb = (m1 >= 0) ? W1[m1 * CH + hh * 16 + col] : 0.f;
        A[kc][hh].u[jj] = pack2(wa, wb);
      }
  float Wc0[3][4], Wc1[3][4];
#pragma unroll
  for (int j = 0; j < 3; ++j)
#pragma unroll
    for (int reg = 0; reg < 4; ++reg) {
      Wc0[j][reg] = W1[(124 + j) * CH + 4 * kg + reg];
      Wc1[j][reg] = W1[(124 + j) * CH + 16 + 4 * kg + reg];
    }
  __syncthreads();

  const int ntiles = (nnodes + 15) >> 4;
  for (int t = wv; t < ntiles; t += 4) {
    const int ln = t * 16 + col;
    float4v a0 = {0.f, 0.f, 0.f, 0.f}, a1 = {0.f, 0.f, 0.f, 0.f};
#pragma unroll
    for (int kc = 0; kc < 4; ++kc) {
      const int idx16 = (ln * 16 + kc * 4 + kg) ^ (ln & 7);
      short8 bf = *(const short8*)(sX + idx16 * 8);
      a0 = __builtin_amdgcn_mfma_f32_16x16x32_bf16(A[kc][0].v, bf, a0, 0, 0, 0);
      a1 = __builtin_amdgcn_mfma_f32_16x16x32_bf16(A[kc][1].v, bf, a1, 0, 0, 0);
    }
#pragma unroll
    for (int j = 0; j < 3; ++j) {
      const float cv = sC[ln][j];
#pragma unroll
      for (int reg = 0; reg < 4; ++reg) {
        a0[reg] = fmaf(cv, Wc0[j][reg], a0[reg]);
        a1[reg] = fmaf(cv, Wc1[j][reg], a1[reg]);
      }
    }
    if (ln < nnodes) {
      const int gnode = base + ln;
      const float dv = dinv[(size_t)b * NN + gnode];
      u32* op = y1 + ((size_t)b * NN + gnode) * 16;
      uint2 s0 = { pack2(a0[0] * dv, a0[1] * dv), pack2(a0[2] * dv, a0[3] * dv) };
      uint2 s1 = { pack2(a1[0] * dv, a1[1] * dv), pack2(a1[2] * dv, a1[3] * dv) };
      *(uint2*)(op + 2 * kg) = s0;
      *(uint2*)(op + 8 + 2 * kg) = s1;
    }
  }
}

// ---------------- Fused kernel: layers 2,3,4 + tail ----------------
// ELL-uniform aggregation: wave-uniform (SGPR) trip count, zero predication
// (pad entries point to dummy node NN whose y == 0).
template<int ACT>
__device__ __forceinline__ void gcn_pass32(
    u32* __restrict__ sy, const u16* __restrict__ s_ell,
    const u16* __restrict__ s_elloff, const float* __restrict__ s_dv,
    const u16* __restrict__ pvs,
    const int wv, const int col, const int kg,
    const short8 a0v, const short8 a1v, const float* __restrict__ bias8)
{
  const uint4* sy4 = (const uint4*)sy;
  u32 outs[3][4];
  int nodes[3];
#pragma unroll
  for (int p = 0; p < 3; ++p) {
    const int t = p * 16 + wv;
    const int pv = (t < NT16) ? (int)pvs[p] : 0xFFFF;
    const int node = (pv == 0xFFFF) ? NN : pv;
    nodes[p] = (pv == 0xFFFF) ? -1 : pv;
    int base = 0, md = 0;
    if (t < NT16) { base = s_elloff[t]; md = s_elloff[t + 1] - base; }
    base = __builtin_amdgcn_readfirstlane(base);
    md = __builtin_amdgcn_readfirstlane(md);
    float zx[8];
    {
      uint4 u = sy4[yslot(node, kg)];          // dummy row = zeros
      zx[0] = bf_lo(u.x); zx[1] = bf_hi(u.x);
      zx[2] = bf_lo(u.y); zx[3] = bf_hi(u.y);
      zx[4] = bf_lo(u.z); zx[5] = bf_hi(u.z);
      zx[6] = bf_lo(u.w); zx[7] = bf_hi(u.w);
    }
    const u16* ep = s_ell + base * 16 + col;
#pragma unroll 2
    for (int kk = 0; kk < md; ++kk) {
      const int r = (int)ep[kk * 16];
      uint4 n = sy4[yslot(r, kg)];
      zx[0] += bf_lo(n.x); zx[1] += bf_hi(n.x);
      zx[2] += bf_lo(n.y); zx[3] += bf_hi(n.y);
      zx[4] += bf_lo(n.z); zx[5] += bf_hi(n.z);
      zx[6] += bf_lo(n.w); zx[7] += bf_hi(n.w);
    }
    const float dv = s_dv[node];               // dummy dv = 0
    float h[8];
#pragma unroll
    for (int j = 0; j < 8; ++j) {
      float t2 = fmaf(dv, zx[j], bias8[j]);
      float l = (t2 > 0.f) ? t2 : 0.01f * t2;
      h[j] = (ACT == 0) ? l : (l + t2);
    }
    union { u32 u[4]; short8 v; } ub;
#pragma unroll
    for (int jj = 0; jj < 4; ++jj) ub.u[jj] = pack2(h[2 * jj], h[2 * jj + 1]);
    float4v z4 = {0.f, 0.f, 0.f, 0.f};
    float4v d0 = __builtin_amdgcn_mfma_f32_16x16x32_bf16(a0v, ub.v, z4, 0, 0, 0);
    float4v d1 = __builtin_amdgcn_mfma_f32_16x16x32_bf16(a1v, ub.v, z4, 0, 0, 0);
    outs[p][0] = pack2(d0[0] * dv, d0[1] * dv);
    outs[p][1] = pack2(d0[2] * dv, d0[3] * dv);
    outs[p][2] = pack2(d1[0] * dv, d1[1] * dv);
    outs[p][3] = pack2(d1[2] * dv, d1[3] * dv);
  }
  __syncthreads();
#pragma unroll
  for (int p = 0; p < 3; ++p) {
    const int node = nodes[p];
    if (node >= 0) {
      const int sw = (node >> 1) & 3;
      u32* op = sy + node * 16;
      uint2 s0 = { outs[p][0], outs[p][1] };
      uint2 s1 = { outs[p][2], outs[p][3] };
      *(uint2*)(op + (((kg >> 1) ^ sw) << 2) + ((2 * kg) & 3)) = s0;
      *(uint2*)(op + (((2 + (kg >> 1)) ^ sw) << 2) + ((2 * kg) & 3)) = s1;
    }
  }
  __syncthreads();
}

__global__ __launch_bounds__(1024) void k_fused(
    const u32* __restrict__ yin, const float* __restrict__ dinv,
    const u16* __restrict__ perm_g, const u16* __restrict__ ell_g,
    const u16* __restrict__ elloff_g,
    const float* __restrict__ b1, const float* __restrict__ W2,
    const float* __restrict__ b2, const float* __restrict__ W3,
    const float* __restrict__ b3, const float* __restrict__ W4,
    const float* __restrict__ b4, const float* __restrict__ Wf1,
    const float* __restrict__ bf1, const float* __restrict__ Wf2,
    const float* __restrict__ bf2, float* __restrict__ out)
{
  const int b = blockIdx.x;
  const int tid = threadIdx.x;
  const int lane = tid & 63;
  const int wv = tid >> 6;          // wave 0..15
  const int col = lane & 15;
  const int kg = lane >> 4;

  __shared__ __align__(16) char smem[64504];
  u32*   s_y      = (u32*)smem;                     // 45760 B (715 rows; dead later)
  u16*   s_ell    = (u16*)(smem + 45760);           // 12928
  u16*   s_elloff = (u16*)(smem + 58688);           // 96
  float* s_dv     = (float*)(smem + 58784);         // 2860 (incl dummy)
  float* s_h      = (float*)(smem + 61644);         // 2860 (incl dummy)
  float* s_red    = (float*)smem;                   // aliases dead s_y
  float* s_u      = (float*)(smem + 8192);          // aliases dead s_y

  {
    const uint4* __restrict__ ysrc = (const uint4*)(yin + (size_t)b * NN * 16);
    uint4* sy4w = (uint4*)s_y;
    const uint4 z4 = {0, 0, 0, 0};
    for (int s = tid; s < (NN + 1) * 4; s += 1024) {
      const int node = s >> 2;
      sy4w[yslot(node, s & 3)] = (node < NN) ? ysrc[s] : z4;
    }
    const uint4* __restrict__ esrc = (const uint4*)(ell_g + (size_t)b * ELLB);
    uint4* ed = (uint4*)s_ell;
    for (int s = tid; s < ELLB / 8; s += 1024) ed[s] = esrc[s];
    for (int i = tid; i <= NT16; i += 1024) s_elloff[i] = elloff_g[(size_t)b * (NT16 + 1) + i];
    for (int i = tid; i < NN; i += 1024) s_dv[i] = dinv[(size_t)b * NN + i];
    if (tid == 1023) s_dv[NN] = 0.f;
  }
  // per-thread perm entries (registers, no LDS)
  u16 pvs[3];
#pragma unroll
  for (int p = 0; p < 3; ++p) {
    const int t = p * 16 + wv;
    pvs[p] = (t < NT16) ? perm_g[(size_t)b * NPAD + t * 16 + col] : (u16)0xFFFF;
  }
  const u16 pvt = (tid < NPAD) ? perm_g[(size_t)b * NPAD + tid] : (u16)0xFFFF;

  union { u32 u[4]; short8 v; } uaA0, uaA1, uaB0, uaB1;
#pragma unroll
  for (int jj = 0; jj < 4; ++jj) {
    uaA0.u[jj] = pack2(W2[(kg * 8 + 2 * jj) * CH + col],      W2[(kg * 8 + 2 * jj + 1) * CH + col]);
    uaA1.u[jj] = pack2(W2[(kg * 8 + 2 * jj) * CH + 16 + col], W2[(kg * 8 + 2 * jj + 1) * CH + 16 + col]);
    uaB0.u[jj] = pack2(W3[(kg * 8 + 2 * jj) * CH + col],      W3[(kg * 8 + 2 * jj + 1) * CH + col]);
    uaB1.u[jj] = pack2(W3[(kg * 8 + 2 * jj) * CH + 16 + col], W3[(kg * 8 + 2 * jj + 1) * CH + 16 + col]);
  }
  float b1r[8], b2r[8], b3r[8], w4r[8];
#pragma unroll
  for (int j = 0; j < 8; ++j) {
    b1r[j] = b1[kg * 8 + j];
    b2r[j] = b2[kg * 8 + j];
    b3r[j] = b3[kg * 8 + j];
    w4r[j] = W4[kg * 8 + j];
  }
  const float bb4 = b4[0];
  __syncthreads();

  gcn_pass32<0>(s_y, s_ell, s_elloff, s_dv, pvs, wv, col, kg, uaA0.v, uaA1.v, b1r);
  gcn_pass32<1>(s_y, s_ell, s_elloff, s_dv, pvs, wv, col, kg, uaB0.v, uaB1.v, b2r);

  // layer 4: agg + b3, lrelu+t, dot W4 (32->1), *dinv -> s_h
  {
    const uint4* sy4 = (const uint4*)s_y;
#pragma unroll
    for (int p = 0; p < 3; ++p) {
      const int t = p * 16 + wv;
      const int pv = (t < NT16) ? (int)pvs[p] : 0xFFFF;
      const int node = (pv == 0xFFFF) ? NN : pv;
      int base = 0, md = 0;
      if (t < NT16) { base = s_elloff[t]; md = s_elloff[t + 1] - base; }
      base = __builtin_amdgcn_readfirstlane(base);
      md = __builtin_amdgcn_readfirstlane(md);
      float zx[8];
      {
        uint4 u = sy4[yslot(node, kg)];
        zx[0] = bf_lo(u.x); zx[1] = bf_hi(u.x);
        zx[2] = bf_lo(u.y); zx[3] = bf_hi(u.y);
        zx[4] = bf_lo(u.z); zx[5] = bf_hi(u.z);
        zx[6] = bf_lo(u.w); zx[7] = bf_hi(u.w);
      }
      const u16* ep = s_ell + base * 16 + col;
#pragma unroll 2
      for (int kk = 0; kk < md; ++kk) {
        const int r = (int)ep[kk * 16];
        uint4 n = sy4[yslot(r, kg)];
        zx[0] += bf_lo(n.x); zx[1] += bf_hi(n.x);
        zx[2] += bf_lo(n.y); zx[3] += bf_hi(n.y);
        zx[4] += bf_lo(n.z); zx[5] += bf_hi(n.z);
        zx[6] += bf_lo(n.w); zx[7] += bf_hi(n.w);
      }
      const float dv = s_dv[node];
      float part = 0.f;
#pragma unroll
      for (int j = 0; j < 8; ++j) {
        float t2 = fmaf(dv, zx[j], b3r[j]);
        float l = (t2 > 0.f) ? t2 : 0.01f * t2;
        part = fmaf(l + t2, w4r[j], part);
      }
      part += __shfl_xor(part, 16, 64);
      part += __shfl_xor(part, 32, 64);
      if (pv != 0xFFFF && kg == 0) s_h[node] = part * dv;
    }
  }
  __syncthreads();
  if (tid == 1023) s_h[NN] = 0.f;
  __syncthreads();

  // tail aggregation via ELL: z = h[node] + sum h[ell]; lrelu(dinv*z + b4)
  {
    float hval = 0.f;
    int node = -1;
    if (tid < NPAD && pvt != 0xFFFF) {
      node = (int)pvt;
      const int t = tid >> 4, c = tid & 15;
      const int base = s_elloff[t], md = s_elloff[t + 1] - base;
      float z = s_h[node];
      const u16* ep = s_ell + base * 16 + c;
      for (int kk = 0; kk < md; ++kk) z += s_h[(int)ep[kk * 16]];
      float t2 = fmaf(s_dv[node], z, bb4);
      hval = (t2 > 0.f) ? t2 : 0.01f * t2;
    }
    __syncthreads();
    if (node >= 0) s_h[node] = hval;
  }
  __syncthreads();

  // FC1: 714 -> 128, 8-way split-K
  const int j = tid & 127, q = tid >> 7;
  {
    const int n0 = (q * NN) >> 3, n1 = ((q + 1) * NN) >> 3;
    const float* __restrict__ w = Wf1 + j;
    float a0 = 0.f, a1 = 0.f;
    int n = n0;
#pragma unroll 4
    for (; n + 2 <= n1; n += 2) {
      a0 = fmaf(s_h[n], w[(size_t)n * 128], a0);
      a1 = fmaf(s_h[n + 1], w[(size_t)(n + 1) * 128], a1);
    }
    if (n < n1) a0 = fmaf(s_h[n], w[(size_t)n * 128], a0);
    s_red[tid] = a0 + a1;
  }
  __syncthreads();
  if (tid < 128) {
    float v = bf1[tid];
#pragma unroll
    for (int m = 0; m < 8; ++m) v += s_red[tid + 128 * m];
    s_u[tid] = fmaxf(v, 0.f);
  }
  __syncthreads();
  // FC2: 128 -> 128, 8-way split-K
  {
    const float* __restrict__ w = Wf2 + j;
    float a0 = 0.f, a1 = 0.f;
#pragma unroll
    for (int k = q * 16; k < q * 16 + 16; k += 2) {
      a0 = fmaf(s_u[k], w[(size_t)k * 128], a0);
      a1 = fmaf(s_u[k + 1], w[(size_t)(k + 1) * 128], a1);
    }
    s_red[tid] = a0 + a1;
  }
  __syncthreads();
  if (tid < 128) {
    float v = bf2[tid];
#pragma unroll
    for (int m = 0; m < 8; ++m) v += s_red[tid + 128 * m];
    out[(size_t)b * 128 + tid] = fmaxf(v, 0.f);
  }
}

extern "C" void kernel_launch(void* const* d_in, const int* in_sizes, int n_in,
                              void* d_out, int out_size, void* d_ws, size_t ws_size,
                              hipStream_t stream)
{
  (void)in_sizes; (void)n_in; (void)out_size; (void)ws_size;
  const int*   ids  = (const int*)d_in[0];
  const float* cont = (const float*)d_in[1];
  const int*   edges= (const int*)d_in[2];
  const float* emb  = (const float*)d_in[3];
  const float* W1   = (const float*)d_in[4];
  const float* b1   = (const float*)d_in[5];
  const float* W2   = (const float*)d_in[6];
  const float* b2   = (const float*)d_in[7];
  const float* W3   = (const float*)d_in[8];
  const float* b3   = (const float*)d_in[9];
  const float* W4   = (const float*)d_in[10];
  const float* b4   = (const float*)d_in[11];
  const float* Wf1  = (const float*)d_in[12];
  const float* bf1  = (const float*)d_in[13];
  const float* Wf2  = (const float*)d_in[14];
  const float* bf2  = (const float*)d_in[15];
  float* out = (float*)d_out;

  char* ws = (char*)d_ws;
  size_t off = 0;
  auto alloc = [&](size_t bytes) -> void* {
    void* p = ws + off;
    off = (off + bytes + 255) & ~(size_t)255;
    return p;
  };
  float* dinv     = (float*)alloc((size_t)BB * NN * 4);
  u16*   perm     = (u16*)  alloc((size_t)BB * NPAD * 2);
  u16*   ell      = (u16*)  alloc((size_t)BB * ELLB * 2);
  u16*   elloff   = (u16*)  alloc((size_t)BB * (NT16 + 1) * 2);
  uint2* embh     = (uint2*)alloc((size_t)VOCAB * 64 * 2);
  u32*   yA       = (u32*)  alloc((size_t)BB * NN * 16 * 4);

  hipLaunchKernelGGL(k_conv, dim3((VOCAB * 16 + 255) / 256), dim3(256), 0, stream, emb, embh);
  hipLaunchKernelGGL(k_prep, dim3(BB), dim3(256), 0, stream, edges, dinv, perm, ell, elloff);
  hipLaunchKernelGGL(k_gcn1m, dim3(BB * 6), dim3(256), 0, stream,
                     ids, cont, (const uint4*)embh, W1, dinv, yA);
  hipLaunchKernelGGL(k_fused, dim3(BB), dim3(1024), 0, stream,
                     yA, dinv, perm, ell, elloff,
                     b1, W2, b2, W3, b3, W4, b4, Wf1, bf1, Wf2, bf2, out);
}

// Round 11
// 112.243 us; speedup vs baseline: 3.1250x; 1.0354x over previous
//
#include <hip/hip_runtime.h>
#include <hip/hip_bf16.h>

#define BB 512
#define NN 714
#define EE 4096
#define ED2 62
#define CH 32
#define NT16 45    // ceil(NN/16)
#define NPAD 720   // NT16*16
#define VOCAB 38733
#define ELLR 432   // ELL row capacity (rows of 16 u16), rows per tile padded to x4
#define ELLB (ELLR*16)

typedef unsigned int u32;
typedef unsigned short u16;
typedef short short8 __attribute__((ext_vector_type(8)));
typedef float float4v __attribute__((ext_vector_type(4)));
typedef _Float16 f16x2 __attribute__((ext_vector_type(2)));
typedef __fp16 fp16x2 __attribute__((ext_vector_type(2)));

__device__ __forceinline__ u32 f2bf(float f) {
  u32 u = __float_as_uint(f);
  return (u + 0x7fffu + ((u >> 16) & 1u)) >> 16;
}
__device__ __forceinline__ u32 pack2(float a, float b) {
  return f2bf(a) | (f2bf(b) << 16);
}
__device__ __forceinline__ f16x2 u2h(u32 x) { union { u32 u; f16x2 h; } c; c.u = x; return c.h; }
__device__ __forceinline__ u32 packh(float a, float b) {
  union { fp16x2 h; u32 u; } c;
  c.h = __builtin_amdgcn_cvt_pkrtz(a, b);
  return c.u;
}

// y-in-LDS swizzle: uint4 slot q of node -> q ^ ((node>>1)&3).
__device__ __forceinline__ int yslot(int node, int q) {
  return (node << 2) | (q ^ ((node >> 1) & 3));
}

// ---------------- Kernel 0: f32 emb table -> bf16 [VOCAB][64] zero-padded ----------------
__global__ __launch_bounds__(256) void k_conv(const float* __restrict__ emb,
                                              uint2* __restrict__ embh)
{
  const int t = blockIdx.x * 256 + threadIdx.x;
  if (t >= VOCAB * 16) return;
  const int row = t >> 4, c = (t & 15) * 4;
  const float* __restrict__ p = emb + (size_t)row * ED2;
  float v0 = (c + 0 < ED2) ? p[c + 0] : 0.f;
  float v1 = (c + 1 < ED2) ? p[c + 1] : 0.f;
  float v2 = (c + 2 < ED2) ? p[c + 2] : 0.f;
  float v3 = (c + 3 < ED2) ? p[c + 3] : 0.f;
  uint2 o = { pack2(v0, v1), pack2(v2, v3) };
  embh[t] = o;
}

// ---------------- Kernel A: degree, dinv, degree-sorted perm, tile-ELL (rows pad4) ----------------
__global__ __launch_bounds__(256) void k_prep(const int* __restrict__ edges,
    float* __restrict__ dinv, u16* __restrict__ perm_g,
    u16* __restrict__ ell_g, u16* __restrict__ elloff_g)
{
  const int b = blockIdx.x;
  const int tid = threadIdx.x;
  const int* __restrict__ er = edges + (size_t)b * 2 * EE;       // e[0] = source (row)
  const int* __restrict__ ec = er + EE;                          // e[1] = target (col)
  __shared__ int s_cnt[NN];
  __shared__ int s_a[1024];
  __shared__ int s_b[1024];
  __shared__ u16 s_rows16[EE];
  __shared__ u16 s_perm[NPAD];
  __shared__ u16 s_degP[NPAD];
  __shared__ int s_hist[64];
  __shared__ int s_md[NT16 + 1];

  for (int i = tid; i < NN; i += 256) s_cnt[i] = 0;
  __syncthreads();
  for (int e = tid; e < EE; e += 256) atomicAdd(&s_cnt[ec[e]], 1);
  __syncthreads();
  for (int i = tid; i < 1024; i += 256) s_a[i] = (i < NN) ? s_cnt[i] : 0;
  for (int i = tid; i < NN; i += 256)
    dinv[(size_t)b * NN + i] = rsqrtf((float)(s_cnt[i] + 1));    // +1 self loop
  __syncthreads();
  int* src = s_a; int* dst = s_b;
  for (int d = 1; d < 1024; d <<= 1) {
    for (int i = tid; i < 1024; i += 256) {
      int v = src[i];
      if (i >= d) v += src[i - d];
      dst[i] = v;
    }
    __syncthreads();
    int* t = src; src = dst; dst = t;
  }
  // src (= s_a, 10 swaps) = inclusive scan of degree counts
  for (int i = tid; i < NN; i += 256) s_cnt[i] = 0;  // fill cursors
  __syncthreads();
  for (int e = tid; e < EE; e += 256) {
    int c = ec[e];
    int p = atomicAdd(&s_cnt[c], 1);
    int base = (c == 0) ? 0 : src[c - 1];
    s_rows16[base + p] = (u16)er[e];
  }
  // degree-sorted perm (counting sort, 64 bins)
  for (int i = tid; i < 64; i += 256) s_hist[i] = 0;
  for (int i = tid; i < NPAD; i += 256) { s_perm[i] = 0xFFFFu; s_degP[i] = 0; }
  __syncthreads();
  for (int i = tid; i < NN; i += 256) {
    int deg = src[i] - (i ? src[i - 1] : 0);
    atomicAdd(&s_hist[deg < 63 ? deg : 63], 1);
  }
  __syncthreads();
  if (tid == 0) {
    int run = 0;
    for (int j = 0; j < 64; ++j) { int c = s_hist[j]; s_hist[j] = run; run += c; }
  }
  __syncthreads();
  for (int i = tid; i < NN; i += 256) {
    int deg = src[i] - (i ? src[i - 1] : 0);
    int pos = atomicAdd(&s_hist[deg < 63 ? deg : 63], 1);
    s_perm[pos] = (u16)i;
    s_degP[pos] = (u16)deg;
  }
  __syncthreads();
  for (int i = tid; i < NPAD; i += 256) perm_g[(size_t)b * NPAD + i] = s_perm[i];
  // per-tile max degree, padded to multiple of 4
  if (tid < NT16) {
    int md = 0;
#pragma unroll
    for (int c = 0; c < 16; ++c) { int d = s_degP[tid * 16 + c]; md = d > md ? d : md; }
    s_md[tid] = (md + 3) & ~3;
  }
  __syncthreads();
  if (tid == 0) {
    int run = 0;
    for (int t = 0; t < NT16; ++t) {
      int m = s_md[t];
      if (run + m > ELLR) m = (ELLR - run) & ~3;   // capacity clamp (never expected)
      s_md[t] = run; run += m;
    }
    s_md[NT16] = run;
  }
  __syncthreads();
  if (tid <= NT16) elloff_g[(size_t)b * (NT16 + 1) + tid] = (u16)s_md[tid];
  // fill ELL (pad entries -> dummy node NN)
  u16* eg = ell_g + (size_t)b * ELLB;
  for (int t = 0; t < NT16; ++t) {
    const int base = s_md[t], md4 = s_md[t + 1] - base;
    for (int s = tid; s < md4 * 16; s += 256) {
      const int kk = s >> 4, col = s & 15;
      const int pv = s_perm[t * 16 + col];
      u16 entry = (u16)NN;
      if (pv != 0xFFFF) {
        const int deg = s_degP[t * 16 + col];
        if (kk < deg) {
          const int off = pv ? src[pv - 1] : 0;
          entry = s_rows16[off + kk];
        }
      }
      eg[base * 16 + s] = entry;
    }
  }
}

// ---------------- Kernel B: MFMA GCN1 (bf16 compute), y1 output packed fp16 ----------------
__global__ __launch_bounds__(256) void k_gcn1m(
    const int* __restrict__ ids, const float* __restrict__ cont,
    const uint4* __restrict__ embh, const float* __restrict__ W1,
    const float* __restrict__ dinv, u32* __restrict__ y1)
{
  const int bid = blockIdx.x;
  const int b = bid / 6, blk = bid - b * 6;
  const int base = blk * 128;
  const int nnodes = (NN - base < 128) ? (NN - base) : 128;
  const int nrows = nnodes * 2;
  const int tid = threadIdx.x, lane = tid & 63, wv = tid >> 6;
  const int col = lane & 15, kg = lane >> 4;

  __shared__ __align__(16) unsigned short sX[128 * 128];
  __shared__ float sC[128][4];
  __shared__ int s_ids[256];

  for (int t = tid; t < nnodes * 3; t += 256)
    sC[t / 3][t % 3] = cont[((size_t)b * NN + base) * 3 + t];
  s_ids[tid] = (tid < nrows) ? ids[((size_t)b * NN + base) * 2 + tid] : -1;
  __syncthreads();

  const int ck = tid & 7;
  const int rbase = tid >> 3;
  {
    uint4 w4[8];
#pragma unroll
    for (int q = 0; q < 8; ++q) {
      const int id = s_ids[q * 32 + rbase];
      if (id >= 0) w4[q] = embh[(size_t)id * 8 + ck];
      else { w4[q].x = 0; w4[q].y = 0; w4[q].z = 0; w4[q].w = 0; }
    }
#pragma unroll
    for (int q = 0; q < 8; ++q) {
      const int r = q * 32 + rbase;
      const int node = r >> 1, slot = r & 1;
      const int c16 = (node * 16 + slot * 8 + ck) ^ (node & 7);
      ((uint4*)sX)[c16] = w4[q];
    }
  }

  union { u32 u[4]; short8 v; } A[4][2];
#pragma unroll
  for (int kc = 0; kc < 4; ++kc)
#pragma unroll
    for (int hh = 0; hh < 2; ++hh)
#pragma unroll
      for (int jj = 0; jj < 4; ++jj) {
        const int k0 = kc * 32 + kg * 8 + 2 * jj;
        const int k1 = k0 + 1;
        const int m0 = (k0 < 62) ? k0 : ((k0 >= 64 && k0 < 126) ? k0 - 2 : -1);
        const int m1 = (k1 < 62) ? k1 : ((k1 >= 64 && k1 < 126) ? k1 - 2 : -1);
        const float wa = (m0 >= 0) ? W1[m0 * CH + hh * 16 + col] : 0.f;
        const float wb = (m1 >= 0) ? W1[m1 * CH + hh * 16 + col] : 0.f;
        A[kc][hh].u[jj] = pack2(wa, wb);
      }
  float Wc0[3][4], Wc1[3][4];
#pragma unroll
  for (int j = 0; j < 3; ++j)
#pragma unroll
    for (int reg = 0; reg < 4; ++reg) {
      Wc0[j][reg] = W1[(124 + j) * CH + 4 * kg + reg];
      Wc1[j][reg] = W1[(124 + j) * CH + 16 + 4 * kg + reg];
    }
  __syncthreads();

  const int ntiles = (nnodes + 15) >> 4;
  for (int t = wv; t < ntiles; t += 4) {
    const int ln = t * 16 + col;
    float4v a0 = {0.f, 0.f, 0.f, 0.f}, a1 = {0.f, 0.f, 0.f, 0.f};
#pragma unroll
    for (int kc = 0; kc < 4; ++kc) {
      const int idx16 = (ln * 16 + kc * 4 + kg) ^ (ln & 7);
      short8 bf = *(const short8*)(sX + idx16 * 8);
      a0 = __builtin_amdgcn_mfma_f32_16x16x32_bf16(A[kc][0].v, bf, a0, 0, 0, 0);
      a1 = __builtin_amdgcn_mfma_f32_16x16x32_bf16(A[kc][1].v, bf, a1, 0, 0, 0);
    }
#pragma unroll
    for (int j = 0; j < 3; ++j) {
      const float cv = sC[ln][j];
#pragma unroll
      for (int reg = 0; reg < 4; ++reg) {
        a0[reg] = fmaf(cv, Wc0[j][reg], a0[reg]);
        a1[reg] = fmaf(cv, Wc1[j][reg], a1[reg]);
      }
    }
    if (ln < nnodes) {
      const int gnode = base + ln;
      const float dv = dinv[(size_t)b * NN + gnode];
      u32* op = y1 + ((size_t)b * NN + gnode) * 16;
      uint2 s0 = { packh(a0[0] * dv, a0[1] * dv), packh(a0[2] * dv, a0[3] * dv) };
      uint2 s1 = { packh(a1[0] * dv, a1[1] * dv), packh(a1[2] * dv, a1[3] * dv) };
      *(uint2*)(op + 2 * kg) = s0;
      *(uint2*)(op + 8 + 2 * kg) = s1;
    }
  }
}

// ---------------- Fused kernel: layers 2,3,4 + tail ----------------
// y in LDS is fp16; aggregation via v_pk_add_f16 with f32 flush every 8 edges.
#define EDGE(EP, K) { const int r = (int)(EP)[(K) * 16]; \
  uint4 n = sy4[yslot(r, kg)]; \
  a0h += u2h(n.x); a1h += u2h(n.y); a2h += u2h(n.z); a3h += u2h(n.w); }
#define FLUSH { zx[0] += (float)a0h.x; zx[1] += (float)a0h.y; \
  zx[2] += (float)a1h.x; zx[3] += (float)a1h.y; \
  zx[4] += (float)a2h.x; zx[5] += (float)a2h.y; \
  zx[6] += (float)a3h.x; zx[7] += (float)a3h.y; \
  a0h = hz; a1h = hz; a2h = hz; a3h = hz; }

template<int ACT>
__device__ __forceinline__ void gcn_pass32(
    u32* __restrict__ sy, const u16* __restrict__ s_ell,
    const u16* __restrict__ s_elloff, const float* __restrict__ s_dv,
    const u16* __restrict__ pvs,
    const int wv, const int col, const int kg,
    const short8 a0v, const short8 a1v, const float* __restrict__ bias8)
{
  const uint4* sy4 = (const uint4*)sy;
  const f16x2 hz = {(_Float16)0, (_Float16)0};
  u32 outs[3][4];
  int nodes[3];
#pragma unroll
  for (int p = 0; p < 3; ++p) {
    const int t = p * 16 + wv;
    const int pv = (t < NT16) ? (int)pvs[p] : 0xFFFF;
    const int node = (pv == 0xFFFF) ? NN : pv;
    nodes[p] = (pv == 0xFFFF) ? -1 : pv;
    int base = 0, md4 = 0;
    if (t < NT16) { base = s_elloff[t]; md4 = s_elloff[t + 1] - base; }
    base = __builtin_amdgcn_readfirstlane(base);
    md4 = __builtin_amdgcn_readfirstlane(md4);
    f16x2 a0h, a1h, a2h, a3h;
    {
      uint4 u = sy4[yslot(node, kg)];          // self (dummy row = zeros)
      a0h = u2h(u.x); a1h = u2h(u.y); a2h = u2h(u.z); a3h = u2h(u.w);
    }
    float zx[8];
#pragma unroll
    for (int j = 0; j < 8; ++j) zx[j] = 0.f;
    const u16* ep = s_ell + base * 16 + col;
    int kk = 0;
    while (kk + 8 <= md4) {
#pragma unroll
      for (int e = 0; e < 8; ++e) EDGE(ep, kk + e)
      FLUSH
      kk += 8;
    }
    if (kk < md4) {
#pragma unroll
      for (int e = 0; e < 4; ++e) EDGE(ep, kk + e)
      FLUSH
    }
    const float dv = s_dv[node];               // dummy dv = 0
    float h[8];
#pragma unroll
    for (int j = 0; j < 8; ++j) {
      float t2 = fmaf(dv, zx[j], bias8[j]);
      float l = (t2 > 0.f) ? t2 : 0.01f * t2;
      h[j] = (ACT == 0) ? l : (l + t2);
    }
    union { u32 u[4]; short8 v; } ub;
#pragma unroll
    for (int jj = 0; jj < 4; ++jj) ub.u[jj] = pack2(h[2 * jj], h[2 * jj + 1]);
    float4v z4 = {0.f, 0.f, 0.f, 0.f};
    float4v d0 = __builtin_amdgcn_mfma_f32_16x16x32_bf16(a0v, ub.v, z4, 0, 0, 0);
    float4v d1 = __builtin_amdgcn_mfma_f32_16x16x32_bf16(a1v, ub.v, z4, 0, 0, 0);
    outs[p][0] = packh(d0[0] * dv, d0[1] * dv);
    outs[p][1] = packh(d0[2] * dv, d0[3] * dv);
    outs[p][2] = packh(d1[0] * dv, d1[1] * dv);
    outs[p][3] = packh(d1[2] * dv, d1[3] * dv);
  }
  __syncthreads();
#pragma unroll
  for (int p = 0; p < 3; ++p) {
    const int node = nodes[p];
    if (node >= 0) {
      const int sw = (node >> 1) & 3;
      u32* op = sy + node * 16;
      uint2 s0 = { outs[p][0], outs[p][1] };
      uint2 s1 = { outs[p][2], outs[p][3] };
      *(uint2*)(op + (((kg >> 1) ^ sw) << 2) + ((2 * kg) & 3)) = s0;
      *(uint2*)(op + (((2 + (kg >> 1)) ^ sw) << 2) + ((2 * kg) & 3)) = s1;
    }
  }
  __syncthreads();
}

__global__ __launch_bounds__(1024) void k_fused(
    const u32* __restrict__ yin, const float* __restrict__ dinv,
    const u16* __restrict__ perm_g, const u16* __restrict__ ell_g,
    const u16* __restrict__ elloff_g,
    const float* __restrict__ b1, const float* __restrict__ W2,
    const float* __restrict__ b2, const float* __restrict__ W3,
    const float* __restrict__ b3, const float* __restrict__ W4,
    const float* __restrict__ b4, const float* __restrict__ Wf1,
    const float* __restrict__ bf1, const float* __restrict__ Wf2,
    const float* __restrict__ bf2, float* __restrict__ out)
{
  const int b = blockIdx.x;
  const int tid = threadIdx.x;
  const int lane = tid & 63;
  const int wv = tid >> 6;          // wave 0..15
  const int col = lane & 15;
  const int kg = lane >> 4;

  __shared__ __align__(16) char smem[65408];
  u32*   s_y      = (u32*)smem;                     // 45760 B (715 rows; dead later)
  u16*   s_ell    = (u16*)(smem + 45760);           // 13824
  u16*   s_elloff = (u16*)(smem + 59584);           // 96
  float* s_dv     = (float*)(smem + 59680);         // 2864 (incl dummy)
  float* s_h      = (float*)(smem + 62544);         // 2864 (incl dummy)
  float* s_red    = (float*)smem;                   // aliases dead s_y
  float* s_u      = (float*)(smem + 8192);          // aliases dead s_y

  {
    const uint4* __restrict__ ysrc = (const uint4*)(yin + (size_t)b * NN * 16);
    uint4* sy4w = (uint4*)s_y;
    const uint4 z4 = {0, 0, 0, 0};
    for (int s = tid; s < (NN + 1) * 4; s += 1024) {
      const int node = s >> 2;
      sy4w[yslot(node, s & 3)] = (node < NN) ? ysrc[s] : z4;
    }
    const uint4* __restrict__ esrc = (const uint4*)(ell_g + (size_t)b * ELLB);
    uint4* ed = (uint4*)s_ell;
    for (int s = tid; s < ELLB / 8; s += 1024) ed[s] = esrc[s];
    for (int i = tid; i <= NT16; i += 1024) s_elloff[i] = elloff_g[(size_t)b * (NT16 + 1) + i];
    for (int i = tid; i < NN; i += 1024) s_dv[i] = dinv[(size_t)b * NN + i];
    if (tid == 1023) s_dv[NN] = 0.f;
  }
  u16 pvs[3];
#pragma unroll
  for (int p = 0; p < 3; ++p) {
    const int t = p * 16 + wv;
    pvs[p] = (t < NT16) ? perm_g[(size_t)b * NPAD + t * 16 + col] : (u16)0xFFFF;
  }
  const u16 pvt = (tid < NPAD) ? perm_g[(size_t)b * NPAD + tid] : (u16)0xFFFF;

  union { u32 u[4]; short8 v; } uaA0, uaA1, uaB0, uaB1;
#pragma unroll
  for (int jj = 0; jj < 4; ++jj) {
    uaA0.u[jj] = pack2(W2[(kg * 8 + 2 * jj) * CH + col],      W2[(kg * 8 + 2 * jj + 1) * CH + col]);
    uaA1.u[jj] = pack2(W2[(kg * 8 + 2 * jj) * CH + 16 + col], W2[(kg * 8 + 2 * jj + 1) * CH + 16 + col]);
    uaB0.u[jj] = pack2(W3[(kg * 8 + 2 * jj) * CH + col],      W3[(kg * 8 + 2 * jj + 1) * CH + col]);
    uaB1.u[jj] = pack2(W3[(kg * 8 + 2 * jj) * CH + 16 + col], W3[(kg * 8 + 2 * jj + 1) * CH + 16 + col]);
  }
  float b1r[8], b2r[8], b3r[8], w4r[8];
#pragma unroll
  for (int j = 0; j < 8; ++j) {
    b1r[j] = b1[kg * 8 + j];
    b2r[j] = b2[kg * 8 + j];
    b3r[j] = b3[kg * 8 + j];
    w4r[j] = W4[kg * 8 + j];
  }
  const float bb4 = b4[0];
  __syncthreads();

  gcn_pass32<0>(s_y, s_ell, s_elloff, s_dv, pvs, wv, col, kg, uaA0.v, uaA1.v, b1r);
  gcn_pass32<1>(s_y, s_ell, s_elloff, s_dv, pvs, wv, col, kg, uaB0.v, uaB1.v, b2r);

  // layer 4: agg + b3, lrelu+t, dot W4 (32->1), *dinv -> s_h
  {
    const uint4* sy4 = (const uint4*)s_y;
    const f16x2 hz = {(_Float16)0, (_Float16)0};
#pragma unroll
    for (int p = 0; p < 3; ++p) {
      const int t = p * 16 + wv;
      const int pv = (t < NT16) ? (int)pvs[p] : 0xFFFF;
      const int node = (pv == 0xFFFF) ? NN : pv;
      int base = 0, md4 = 0;
      if (t < NT16) { base = s_elloff[t]; md4 = s_elloff[t + 1] - base; }
      base = __builtin_amdgcn_readfirstlane(base);
      md4 = __builtin_amdgcn_readfirstlane(md4);
      f16x2 a0h, a1h, a2h, a3h;
      {
        uint4 u = sy4[yslot(node, kg)];
        a0h = u2h(u.x); a1h = u2h(u.y); a2h = u2h(u.z); a3h = u2h(u.w);
      }
      float zx[8];
#pragma unroll
      for (int j = 0; j < 8; ++j) zx[j] = 0.f;
      const u16* ep = s_ell + base * 16 + col;
      int kk = 0;
      while (kk + 8 <= md4) {
#pragma unroll
        for (int e = 0; e < 8; ++e) EDGE(ep, kk + e)
        FLUSH
        kk += 8;
      }
      if (kk < md4) {
#pragma unroll
        for (int e = 0; e < 4; ++e) EDGE(ep, kk + e)
        FLUSH
      }
      const float dv = s_dv[node];
      float part = 0.f;
#pragma unroll
      for (int j = 0; j < 8; ++j) {
        float t2 = fmaf(dv, zx[j], b3r[j]);
        float l = (t2 > 0.f) ? t2 : 0.01f * t2;
        part = fmaf(l + t2, w4r[j], part);
      }
      part += __shfl_xor(part, 16, 64);
      part += __shfl_xor(part, 32, 64);
      if (pv != 0xFFFF && kg == 0) s_h[node] = part * dv;
    }
  }
  __syncthreads();
  if (tid == 1023) s_h[NN] = 0.f;
  __syncthreads();

  // tail aggregation via ELL: z = h[node] + sum h[ell]; lrelu(dinv*z + b4)
  {
    float hval = 0.f;
    int node = -1;
    if (tid < NPAD && pvt != 0xFFFF) {
      node = (int)pvt;
      const int t = tid >> 4, c = tid & 15;
      const int base = s_elloff[t], md4 = s_elloff[t + 1] - base;
      float z = s_h[node];
      const u16* ep = s_ell + base * 16 + c;
      for (int kk = 0; kk < md4; ++kk) z += s_h[(int)ep[kk * 16]];
      float t2 = fmaf(s_dv[node], z, bb4);
      hval = (t2 > 0.f) ? t2 : 0.01f * t2;
    }
    __syncthreads();
    if (node >= 0) s_h[node] = hval;
  }
  __syncthreads();

  // FC1: 714 -> 128, 8-way split-K
  const int j = tid & 127, q = tid >> 7;
  {
    const int n0 = (q * NN) >> 3, n1 = ((q + 1) * NN) >> 3;
    const float* __restrict__ w = Wf1 + j;
    float a0 = 0.f, a1 = 0.f;
    int n = n0;
#pragma unroll 4
    for (; n + 2 <= n1; n += 2) {
      a0 = fmaf(s_h[n], w[(size_t)n * 128], a0);
      a1 = fmaf(s_h[n + 1], w[(size_t)(n + 1) * 128], a1);
    }
    if (n < n1) a0 = fmaf(s_h[n], w[(size_t)n * 128], a0);
    s_red[tid] = a0 + a1;
  }
  __syncthreads();
  if (tid < 128) {
    float v = bf1[tid];
#pragma unroll
    for (int m = 0; m < 8; ++m) v += s_red[tid + 128 * m];
    s_u[tid] = fmaxf(v, 0.f);
  }
  __syncthreads();
  // FC2: 128 -> 128, 8-way split-K
  {
    const float* __restrict__ w = Wf2 + j;
    float a0 = 0.f, a1 = 0.f;
#pragma unroll
    for (int k = q * 16; k < q * 16 + 16; k += 2) {
      a0 = fmaf(s_u[k], w[(size_t)k * 128], a0);
      a1 = fmaf(s_u[k + 1], w[(size_t)(k + 1) * 128], a1);
    }
    s_red[tid] = a0 + a1;
  }
  __syncthreads();
  if (tid < 128) {
    float v = bf2[tid];
#pragma unroll
    for (int m = 0; m < 8; ++m) v += s_red[tid + 128 * m];
    out[(size_t)b * 128 + tid] = fmaxf(v, 0.f);
  }
}

extern "C" void kernel_launch(void* const* d_in, const int* in_sizes, int n_in,
                              void* d_out, int out_size, void* d_ws, size_t ws_size,
                              hipStream_t stream)
{
  (void)in_sizes; (void)n_in; (void)out_size; (void)ws_size;
  const int*   ids  = (const int*)d_in[0];
  const float* cont = (const float*)d_in[1];
  const int*   edges= (const int*)d_in[2];
  const float* emb  = (const float*)d_in[3];
  const float* W1   = (const float*)d_in[4];
  const float* b1   = (const float*)d_in[5];
  const float* W2   = (const float*)d_in[6];
  const float* b2   = (const float*)d_in[7];
  const float* W3   = (const float*)d_in[8];
  const float* b3   = (const float*)d_in[9];
  const float* W4   = (const float*)d_in[10];
  const float* b4   = (const float*)d_in[11];
  const float* Wf1  = (const float*)d_in[12];
  const float* bf1  = (const float*)d_in[13];
  const float* Wf2  = (const float*)d_in[14];
  const float* bf2  = (const float*)d_in[15];
  float* out = (float*)d_out;

  char* ws = (char*)d_ws;
  size_t off = 0;
  auto alloc = [&](size_t bytes) -> void* {
    void* p = ws + off;
    off = (off + bytes + 255) & ~(size_t)255;
    return p;
  };
  float* dinv     = (float*)alloc((size_t)BB * NN * 4);
  u16*   perm     = (u16*)  alloc((size_t)BB * NPAD * 2);
  u16*   ell      = (u16*)  alloc((size_t)BB * ELLB * 2);
  u16*   elloff   = (u16*)  alloc((size_t)BB * (NT16 + 1) * 2);
  uint2* embh     = (uint2*)alloc((size_t)VOCAB * 64 * 2);
  u32*   yA       = (u32*)  alloc((size_t)BB * NN * 16 * 4);

  hipLaunchKernelGGL(k_conv, dim3((VOCAB * 16 + 255) / 256), dim3(256), 0, stream, emb, embh);
  hipLaunchKernelGGL(k_prep, dim3(BB), dim3(256), 0, stream, edges, dinv, perm, ell, elloff);
  hipLaunchKernelGGL(k_gcn1m, dim3(BB * 6), dim3(256), 0, stream,
                     ids, cont, (const uint4*)embh, W1, dinv, yA);
  hipLaunchKernelGGL(k_fused, dim3(BB), dim3(1024), 0, stream,
                     yA, dinv, perm, ell, elloff,
                     b1, W2, b2, W3, b3, W4, b4, Wf1, bf1, Wf2, bf2, out);
}